// Round 1
// baseline (2364.812 us; speedup 1.0000x reference)
//
#include <hip/hip_runtime.h>
#include <stdint.h>

#define DEV __device__ __forceinline__

constexpr int N0 = 50000;
constexpr int E0 = 800000;
constexpr int D  = 128;

// ---------------- CSR build ----------------
__global__ void k_count(const int* __restrict__ src, const int* __restrict__ dst,
                        unsigned* cnt_src, unsigned* cnt_dst) {
  int e = blockIdx.x * blockDim.x + threadIdx.x;
  if (e < E0) {
    atomicAdd(&cnt_src[src[e]], 1u);
    atomicAdd(&cnt_dst[dst[e]], 1u);
  }
}

// single-block exclusive scan; out has n+1 entries
__global__ void k_scan(const unsigned* __restrict__ in, unsigned* __restrict__ out, int n) {
  __shared__ unsigned wsum[16], woff[16];
  __shared__ unsigned carry;
  int t = threadIdx.x, lane = t & 63, w = t >> 6;
  if (t == 0) carry = 0;
  __syncthreads();
  for (int base = 0; base < n; base += 1024) {
    int i = base + t;
    unsigned v = (i < n) ? in[i] : 0u;
    unsigned s = v;
    #pragma unroll
    for (int off = 1; off < 64; off <<= 1) {
      unsigned u = __shfl_up(s, (unsigned)off);
      if (lane >= off) s += u;
    }
    if (lane == 63) wsum[w] = s;
    __syncthreads();
    if (t == 0) {
      unsigned run = carry;
      for (int j = 0; j < 16; ++j) { woff[j] = run; run += wsum[j]; }
      carry = run;
    }
    __syncthreads();
    if (i < n) out[i] = woff[w] + s - v;
    __syncthreads();
  }
  if (threadIdx.x == 0) out[n] = carry;
}

__global__ void k_fill(const int* __restrict__ key, unsigned* cursor, unsigned* __restrict__ eids) {
  int e = blockIdx.x * blockDim.x + threadIdx.x;
  if (e < E0) {
    unsigned pos = atomicAdd(&cursor[key[e]], 1u);
    eids[pos] = (unsigned)e;
  }
}

// ---------------- weight transpose: BT[c][k][o], k<128 -> Wl, else Wr ----------------
__global__ void k_wt(const float* __restrict__ Wl, const float* __restrict__ Wr, float* __restrict__ BT) {
  int idx = blockIdx.x * blockDim.x + threadIdx.x;
  if (idx < 10 * 256 * 128) {
    int o = idx & 127;
    int k = (idx >> 7) & 255;
    int c = idx >> 15;
    float v = (k < 128) ? Wl[(c * 128 + o) * 128 + k] : Wr[(c * 128 + o) * 128 + (k - 128)];
    BT[idx] = v;
  }
}

// ---------------- SAGE mean aggregation: wave per node ----------------
__global__ void k_sage_agg(const float* __restrict__ x, const int* __restrict__ csrc,
                           const float* __restrict__ valid, const int* __restrict__ orig,
                           const unsigned* __restrict__ indptr, const unsigned* __restrict__ eids,
                           int n, float* __restrict__ mean) {
  int wid = (blockIdx.x * blockDim.x + threadIdx.x) >> 6;
  int lane = threadIdx.x & 63;
  if (wid >= n) return;
  int o = orig ? orig[wid] : wid;
  unsigned s0 = indptr[o], s1 = indptr[o + 1];
  float a0 = 0.f, a1 = 0.f, cnt = 0.f;
  for (unsigned idx = s0; idx < s1; ++idx) {
    int e = (int)eids[idx];
    float v = valid ? valid[e] : 1.0f;
    if (v > 0.f) {
      const float2 xv = *(const float2*)(x + (size_t)csrc[e] * D + lane * 2);
      a0 += xv.x; a1 += xv.y; cnt += v;
    }
  }
  float inv = 1.0f / fmaxf(cnt, 1.0f);
  float2 outv; outv.x = a0 * inv; outv.y = a1 * inv;
  *(float2*)(mean + (size_t)wid * D + lane * 2) = outv;
}

// ---------------- weighted edge conv: wave per node, gather cidx[e] ----------------
__global__ void k_econv(const float* __restrict__ x, const int* __restrict__ cidx,
                        const float* __restrict__ ec, const int* __restrict__ orig,
                        const unsigned* __restrict__ indptr, const unsigned* __restrict__ eids,
                        int n, float* __restrict__ out) {
  int wid = (blockIdx.x * blockDim.x + threadIdx.x) >> 6;
  int lane = threadIdx.x & 63;
  if (wid >= n) return;
  int o = orig ? orig[wid] : wid;
  unsigned s0 = indptr[o], s1 = indptr[o + 1];
  float a0 = 0.f, a1 = 0.f;
  for (unsigned idx = s0; idx < s1; ++idx) {
    int e = (int)eids[idx];
    float wgt = ec[e];
    if (wgt != 0.f) {
      const float2 xv = *(const float2*)(x + (size_t)cidx[e] * D + lane * 2);
      a0 = fmaf(wgt, xv.x, a0); a1 = fmaf(wgt, xv.y, a1);
    }
  }
  float2 outv; outv.x = a0; outv.y = a1;
  *(float2*)(out + (size_t)wid * D + lane * 2) = outv;
}

// ---------------- fused conv GEMM: y = mean@Wl^T + bl + x@Wr^T ----------------
__launch_bounds__(256)
__global__ void k_conv_gemm(const float* __restrict__ mean, const float* __restrict__ xin,
                            const float* __restrict__ BT, const float* __restrict__ bias,
                            float* __restrict__ y, int n) {
  __shared__ float As[64][17];
  __shared__ float Bs[16][128];
  int tid = threadIdx.x;
  int tx = tid & 15, ty = tid >> 4;
  int row0 = blockIdx.x * 64;
  float acc[4][8];
  #pragma unroll
  for (int r = 0; r < 4; ++r)
    #pragma unroll
    for (int c = 0; c < 8; ++c) acc[r][c] = 0.f;

  int lm = tid >> 2;        // 0..63 A-row
  int lk = (tid & 3) * 4;   // 0,4,8,12
  int bk = tid >> 4;        // 0..15 B-k
  int bo = (tid & 15) * 8;  // 0..120

  for (int kc = 0; kc < 16; ++kc) {
    int k0 = kc * 16;
    const float* A = (k0 < 128) ? mean : xin;
    int kk = k0 & 127;
    int gr = row0 + lm;
    float4 av = make_float4(0.f, 0.f, 0.f, 0.f);
    if (gr < n) av = *(const float4*)(A + (size_t)gr * D + kk + lk);
    As[lm][lk + 0] = av.x; As[lm][lk + 1] = av.y; As[lm][lk + 2] = av.z; As[lm][lk + 3] = av.w;
    float4 bv0 = *(const float4*)(BT + (size_t)(k0 + bk) * 128 + bo);
    float4 bv1 = *(const float4*)(BT + (size_t)(k0 + bk) * 128 + bo + 4);
    *(float4*)&Bs[bk][bo] = bv0;
    *(float4*)&Bs[bk][bo + 4] = bv1;
    __syncthreads();
    #pragma unroll
    for (int k = 0; k < 16; ++k) {
      float a[4];
      #pragma unroll
      for (int r = 0; r < 4; ++r) a[r] = As[ty * 4 + r][k];
      float4 b0 = *(const float4*)&Bs[k][tx * 4];
      float4 b1 = *(const float4*)&Bs[k][64 + tx * 4];
      float bb[8] = {b0.x, b0.y, b0.z, b0.w, b1.x, b1.y, b1.z, b1.w};
      #pragma unroll
      for (int r = 0; r < 4; ++r)
        #pragma unroll
        for (int c = 0; c < 8; ++c)
          acc[r][c] = fmaf(a[r], bb[c], acc[r][c]);
    }
    __syncthreads();
  }
  float4 bs0 = *(const float4*)(bias + tx * 4);
  float4 bs1 = *(const float4*)(bias + 64 + tx * 4);
  #pragma unroll
  for (int r = 0; r < 4; ++r) {
    int gr = row0 + ty * 4 + r;
    if (gr < n) {
      float4 o0 = make_float4(acc[r][0] + bs0.x, acc[r][1] + bs0.y, acc[r][2] + bs0.z, acc[r][3] + bs0.w);
      float4 o1 = make_float4(acc[r][4] + bs1.x, acc[r][5] + bs1.y, acc[r][6] + bs1.z, acc[r][7] + bs1.w);
      *(float4*)(y + (size_t)gr * D + tx * 4) = o0;
      *(float4*)(y + (size_t)gr * D + 64 + tx * 4) = o1;
    }
  }
}

// ---------------- cal_ew ----------------
__global__ void k_deg(const float* __restrict__ valid, const int* __restrict__ orig,
                      const unsigned* __restrict__ indptr_src, const unsigned* __restrict__ eids_src,
                      int n, float* __restrict__ deg) {
  int j = blockIdx.x * blockDim.x + threadIdx.x;
  if (j >= n) return;
  int o = orig ? orig[j] : j;
  unsigned s0 = indptr_src[o], s1 = indptr_src[o + 1];
  float d = 0.f;
  for (unsigned i = s0; i < s1; ++i) {
    int e = (int)eids_src[i];
    d += valid ? valid[e] : 1.0f;
  }
  deg[j] = d;
}

__global__ void k_wsend(const int* __restrict__ csrc, const float* __restrict__ valid,
                        const float* __restrict__ w, const float* __restrict__ deg,
                        float* __restrict__ wsend) {
  int e = blockIdx.x * blockDim.x + threadIdx.x;
  if (e >= E0) return;
  float v = valid ? valid[e] : 1.0f;
  int s = csrc[e];
  float dd = deg[s];
  float nm = (w ? w[s] : 1.0f) / (dd > 0.f ? dd : 1.0f);
  wsend[e] = nm * v;
}

__global__ void k_aggrw(const float* __restrict__ wsend, const int* __restrict__ orig,
                        const unsigned* __restrict__ indptr_dst, const unsigned* __restrict__ eids_dst,
                        int n, float* __restrict__ aggrw) {
  int j = blockIdx.x * blockDim.x + threadIdx.x;
  if (j >= n) return;
  int o = orig ? orig[j] : j;
  unsigned s0 = indptr_dst[o], s1 = indptr_dst[o + 1];
  float s = 1e-12f;
  for (unsigned i = s0; i < s1; ++i) s += wsend[(int)eids_dst[i]];
  aggrw[j] = s;
}

__global__ void k_ec(const float* __restrict__ wsend, const int* __restrict__ cdst,
                     const float* __restrict__ aggrw, float* __restrict__ ec) {
  int e = blockIdx.x * blockDim.x + threadIdx.x;
  if (e >= E0) return;
  ec[e] = wsend[e] / aggrw[cdst[e]];
}

// ---------------- pooling ----------------
DEV unsigned mono_key(float f) {
  unsigned u = __float_as_uint(f);
  return (u & 0x80000000u) ? ~u : (u | 0x80000000u);
}

__global__ void k_pnorm(const float* __restrict__ p, float* __restrict__ pinv) {
  int lane = threadIdx.x;
  float v = p[lane] * p[lane] + p[lane + 64] * p[lane + 64];
  #pragma unroll
  for (int off = 32; off >= 1; off >>= 1) v += __shfl_xor(v, off);
  if (lane == 0) *pinv = 1.0f / sqrtf(v);
}

__global__ void k_score(const float* __restrict__ x, const float* __restrict__ p,
                        const float* __restrict__ pinv, int n,
                        float* __restrict__ score, unsigned* __restrict__ keys) {
  int wid = (blockIdx.x * blockDim.x + threadIdx.x) >> 6;
  int lane = threadIdx.x & 63;
  if (wid >= n) return;
  const float2 xv = *(const float2*)(x + (size_t)wid * D + lane * 2);
  float partial = xv.x * p[lane * 2] + xv.y * p[lane * 2 + 1];
  #pragma unroll
  for (int off = 32; off >= 1; off >>= 1) partial += __shfl_xor(partial, off);
  if (lane == 0) {
    float sc = partial * (*pinv);
    score[wid] = sc;
    keys[wid] = mono_key(sc);
  }
}

__global__ void k_sel_init(unsigned* bins, unsigned* state, int k) {
  int t = threadIdx.x;
  if (t < 256) bins[t] = 0u;
  if (t == 0) { state[0] = 0u; state[1] = (unsigned)k; }
}

__global__ void k_hist(const unsigned* __restrict__ keys, int n, const unsigned* __restrict__ state,
                       unsigned* __restrict__ bins, int byte) {
  __shared__ unsigned lb[256];
  for (int i = threadIdx.x; i < 256; i += blockDim.x) lb[i] = 0u;
  __syncthreads();
  unsigned prefix = state[0];
  unsigned mask = (byte == 3) ? 0u : (0xFFFFFFFFu << ((byte + 1) * 8));
  for (int i = blockIdx.x * blockDim.x + threadIdx.x; i < n; i += gridDim.x * blockDim.x) {
    unsigned key = keys[i];
    if ((key & mask) == (prefix & mask))
      atomicAdd(&lb[(key >> (byte * 8)) & 255], 1u);
  }
  __syncthreads();
  for (int i = threadIdx.x; i < 256; i += blockDim.x)
    if (lb[i]) atomicAdd(&bins[i], lb[i]);
}

__global__ void k_pick(unsigned* bins, unsigned* state, int byte) {
  if (threadIdx.x == 0) {
    unsigned r = state[1];
    int b;
    for (b = 255; b > 0; --b) {
      unsigned c = bins[b];
      if (c >= r) break;
      r -= c;
    }
    state[0] |= ((unsigned)b) << (byte * 8);
    state[1] = r;
  }
  __syncthreads();
  for (int i = threadIdx.x; i < 256; i += blockDim.x) bins[i] = 0u;
}

// single-block: select top-k set (ties -> lowest index), pack perm/new_id/w/orig
__global__ void k_pack(const unsigned* __restrict__ keys, const unsigned* __restrict__ state,
                       const float* __restrict__ aggrw, const int* __restrict__ orig,
                       int n, int* __restrict__ perm, int* __restrict__ new_id,
                       float* __restrict__ w_next, int* __restrict__ orig_next) {
  __shared__ unsigned wsA[16], offA[16], wsB[16], offB[16];
  __shared__ unsigned cEq, cSel;
  int t = threadIdx.x, lane = t & 63, w = t >> 6;
  unsigned T = state[0], r = state[1];
  if (t == 0) { cEq = 0; cSel = 0; }
  __syncthreads();
  for (int base = 0; base < n; base += 1024) {
    int i = base + t;
    unsigned key = (i < n) ? keys[i] : 0u;
    unsigned gt = (i < n && key > T) ? 1u : 0u;
    unsigned eq = (i < n && key == T) ? 1u : 0u;
    unsigned s = eq;
    #pragma unroll
    for (int off = 1; off < 64; off <<= 1) {
      unsigned u = __shfl_up(s, (unsigned)off);
      if (lane >= off) s += u;
    }
    if (lane == 63) wsA[w] = s;
    __syncthreads();
    if (t == 0) {
      unsigned run = cEq;
      for (int j = 0; j < 16; ++j) { offA[j] = run; run += wsA[j]; }
      cEq = run;
    }
    __syncthreads();
    unsigned eqrank = offA[w] + s - eq;
    unsigned sel = gt | (eq & ((eqrank < r) ? 1u : 0u));
    unsigned s2 = sel;
    #pragma unroll
    for (int off = 1; off < 64; off <<= 1) {
      unsigned u = __shfl_up(s2, (unsigned)off);
      if (lane >= off) s2 += u;
    }
    if (lane == 63) wsB[w] = s2;
    __syncthreads();
    if (t == 0) {
      unsigned run = cSel;
      for (int j = 0; j < 16; ++j) { offB[j] = run; run += wsB[j]; }
      cSel = run;
    }
    __syncthreads();
    if (i < n) {
      if (sel) {
        int pos = (int)(offB[w] + s2 - sel);
        perm[pos] = i;
        new_id[i] = pos;
        w_next[pos] = aggrw[i];
        orig_next[pos] = orig ? orig[i] : i;
      } else {
        new_id[i] = -1;
      }
    }
    __syncthreads();
  }
}

__global__ void k_gate(const float* __restrict__ xin, const int* __restrict__ perm,
                       const float* __restrict__ score, int k, float* __restrict__ xout) {
  int wid = (blockIdx.x * blockDim.x + threadIdx.x) >> 6;
  int lane = threadIdx.x & 63;
  if (wid >= k) return;
  int j = perm[wid];
  float g = tanhf(score[j]);
  float2 v = *(const float2*)(xin + (size_t)j * D + lane * 2);
  v.x *= g; v.y *= g;
  *(float2*)(xout + (size_t)wid * D + lane * 2) = v;
}

__global__ void k_relabel(const int* __restrict__ src_in, const int* __restrict__ dst_in,
                          const float* __restrict__ valid_in, const int* __restrict__ new_id,
                          int* __restrict__ src_out, int* __restrict__ dst_out,
                          float* __restrict__ valid_out) {
  int e = blockIdx.x * blockDim.x + threadIdx.x;
  if (e >= E0) return;
  int s2 = new_id[src_in[e]];
  int d2 = new_id[dst_in[e]];
  float v = (valid_in ? valid_in[e] : 1.0f) * ((s2 >= 0 && d2 >= 0) ? 1.0f : 0.0f);
  src_out[e] = s2 > 0 ? s2 : 0;
  dst_out[e] = d2 > 0 ? d2 : 0;
  valid_out[e] = v;
}

// ---------------- unpool scatter / skip add ----------------
__global__ void k_scatter(const float* __restrict__ xin, const int* __restrict__ perm,
                          int k, float* __restrict__ xout) {
  int wid = (blockIdx.x * blockDim.x + threadIdx.x) >> 6;
  int lane = threadIdx.x & 63;
  if (wid >= k) return;
  int p = perm[wid];
  float2 v = *(const float2*)(xin + (size_t)wid * D + lane * 2);
  *(float2*)(xout + (size_t)p * D + lane * 2) = v;
}

__global__ void k_add(const float* __restrict__ a, const float* __restrict__ b,
                      float* __restrict__ out, int total4) {
  int i = blockIdx.x * blockDim.x + threadIdx.x;
  if (i < total4) {
    float4 av = ((const float4*)a)[i];
    float4 bv = ((const float4*)b)[i];
    ((float4*)out)[i] = make_float4(av.x + bv.x, av.y + bv.y, av.z + bv.z, av.w + bv.w);
  }
}

// =============================================================================
extern "C" void kernel_launch(void* const* d_in, const int* in_sizes, int n_in,
                              void* d_out, int out_size, void* d_ws, size_t ws_size,
                              hipStream_t stream) {
  const float* x_in   = (const float*)d_in[0];
  const int*   ei     = (const int*)d_in[1];
  const int*   src0   = ei;
  const int*   dst0   = ei + E0;
  const float* Wl     = (const float*)d_in[2];
  const float* bl     = (const float*)d_in[3];
  const float* Wr     = (const float*)d_in[4];
  const float* pool_p = (const float*)d_in[5];
  float* out = (float*)d_out;

  const int n0 = N0, k0 = 25000, n1 = 25000, k1 = 12500, n2 = 12500;

  char* ws = (char*)d_ws;
  size_t off = 0;
  auto alloc = [&](size_t bytes) -> char* {
    char* p = ws + off;
    off += (bytes + 255) & ~(size_t)255;
    return p;
  };
  const size_t NB = (size_t)N0 * D * 4;
  float* B0    = (float*)alloc(NB);
  float* B1    = (float*)alloc(NB);
  float* B2    = (float*)alloc(NB);
  float* down0 = (float*)alloc(NB);
  float* down1 = (float*)alloc(NB / 2);
  float* ec0   = (float*)alloc(E0 * 4);
  float* ec1   = (float*)alloc(E0 * 4);
  float* valid1 = (float*)alloc(E0 * 4);
  float* valid2 = (float*)alloc(E0 * 4);
  float* tmp_e  = (float*)alloc(E0 * 4);   // wsend
  int* src1 = (int*)alloc(E0 * 4);
  int* dst1 = (int*)alloc(E0 * 4);
  int* src2 = (int*)alloc(E0 * 4);
  int* dst2 = (int*)alloc(E0 * 4);
  unsigned* eids_dst = (unsigned*)alloc(E0 * 4);
  unsigned* eids_src = (unsigned*)alloc(E0 * 4);
  unsigned* indptr_dst = (unsigned*)alloc((N0 + 1) * 4);
  unsigned* indptr_src = (unsigned*)alloc((N0 + 1) * 4);
  unsigned* cursor  = (unsigned*)alloc(N0 * 4);
  unsigned* cnt_src = (unsigned*)alloc(N0 * 4);
  unsigned* cnt_dst = (unsigned*)alloc(N0 * 4);
  float* deg   = (float*)alloc(N0 * 4);
  float* aggrw = (float*)alloc(N0 * 4);
  float* w1 = (float*)alloc(n1 * 4);
  float* w2 = (float*)alloc(n2 * 4);
  float* score = (float*)alloc(N0 * 4);
  unsigned* keys = (unsigned*)alloc(N0 * 4);
  int* perm0 = (int*)alloc(k0 * 4);
  int* perm1 = (int*)alloc(k1 * 4);
  int* orig1 = (int*)alloc(k0 * 4);
  int* orig2 = (int*)alloc(k1 * 4);
  int* new_id = (int*)alloc(N0 * 4);
  unsigned* bins  = (unsigned*)alloc(256 * 4);
  unsigned* state = (unsigned*)alloc(8);
  float* pinv = (float*)alloc(4);
  float* BT = (float*)alloc((size_t)10 * 256 * 128 * 4);

  const int EG = (E0 + 255) / 256;

  // ---- CSR build (once per call) ----
  hipMemsetAsync(cnt_src, 0, N0 * 4, stream);
  hipMemsetAsync(cnt_dst, 0, N0 * 4, stream);
  k_count<<<EG, 256, 0, stream>>>(src0, dst0, cnt_src, cnt_dst);
  k_scan<<<1, 1024, 0, stream>>>(cnt_src, indptr_src, N0);
  k_scan<<<1, 1024, 0, stream>>>(cnt_dst, indptr_dst, N0);
  hipMemcpyAsync(cursor, indptr_dst, N0 * 4, hipMemcpyDeviceToDevice, stream);
  k_fill<<<EG, 256, 0, stream>>>(dst0, cursor, eids_dst);
  hipMemcpyAsync(cursor, indptr_src, N0 * 4, hipMemcpyDeviceToDevice, stream);
  k_fill<<<EG, 256, 0, stream>>>(src0, cursor, eids_src);
  k_wt<<<(10 * 256 * 128 + 255) / 256, 256, 0, stream>>>(Wl, Wr, BT);

  auto conv = [&](const float* xin, float* meanbuf, float* yout, int n,
                  const int* csrc, const float* valid, const int* orig, int cidx) {
    k_sage_agg<<<(n + 3) / 4, 256, 0, stream>>>(xin, csrc, valid, orig, indptr_dst, eids_dst, n, meanbuf);
    k_conv_gemm<<<(n + 63) / 64, 256, 0, stream>>>(meanbuf, xin, BT + (size_t)cidx * 256 * 128,
                                                   bl + cidx * 128, yout, n);
  };

  auto cal_ew = [&](const int* csrc, const int* cdst, const float* valid, const float* w,
                    const int* orig, int n, float* ec) {
    k_deg<<<(n + 255) / 256, 256, 0, stream>>>(valid, orig, indptr_src, eids_src, n, deg);
    k_wsend<<<EG, 256, 0, stream>>>(csrc, valid, w, deg, tmp_e);
    k_aggrw<<<(n + 255) / 256, 256, 0, stream>>>(tmp_e, orig, indptr_dst, eids_dst, n, aggrw);
    k_ec<<<EG, 256, 0, stream>>>(tmp_e, cdst, aggrw, ec);
  };

  auto pool = [&](const float* xpool, int n, int kk, int level, const int* orig,
                  const int* csrc, const int* cdst, const float* valid,
                  float* xout, int* perm, float* w_next, int* orig_next,
                  int* src_next, int* dst_next, float* valid_next) {
    k_pnorm<<<1, 64, 0, stream>>>(pool_p + level * D, pinv);
    k_score<<<(n + 3) / 4, 256, 0, stream>>>(xpool, pool_p + level * D, pinv, n, score, keys);
    k_sel_init<<<1, 256, 0, stream>>>(bins, state, kk);
    for (int byte = 3; byte >= 0; --byte) {
      k_hist<<<256, 256, 0, stream>>>(keys, n, state, bins, byte);
      k_pick<<<1, 256, 0, stream>>>(bins, state, byte);
    }
    k_pack<<<1, 1024, 0, stream>>>(keys, state, aggrw, orig, n, perm, new_id, w_next, orig_next);
    k_gate<<<(kk + 3) / 4, 256, 0, stream>>>(xpool, perm, score, kk, xout);
    k_relabel<<<EG, 256, 0, stream>>>(csrc, cdst, valid, new_id, src_next, dst_next, valid_next);
  };

  // ---- down level 0 ----
  conv(x_in, B1, B2, n0, src0, nullptr, nullptr, 0);
  conv(B2, B1, down0, n0, src0, nullptr, nullptr, 1);
  cal_ew(src0, dst0, nullptr, nullptr, nullptr, n0, ec0);
  k_econv<<<(n0 + 3) / 4, 256, 0, stream>>>(down0, src0, ec0, nullptr, indptr_dst, eids_dst, n0, B1);
  pool(B1, n0, k0, 0, nullptr, src0, dst0, nullptr,
       B2, perm0, w1, orig1, src1, dst1, valid1);

  // ---- down level 1 ----
  conv(B2, B1, B0, n1, src1, valid1, orig1, 2);
  conv(B0, B1, down1, n1, src1, valid1, orig1, 3);
  cal_ew(src1, dst1, valid1, w1, orig1, n1, ec1);
  k_econv<<<(n1 + 3) / 4, 256, 0, stream>>>(down1, src1, ec1, orig1, indptr_dst, eids_dst, n1, B1);
  pool(B1, n1, k1, 1, orig1, src1, dst1, valid1,
       B2, perm1, w2, orig2, src2, dst2, valid2);

  // ---- bottom ----
  conv(B2, B1, B0, n2, src2, valid2, orig2, 4);
  conv(B0, B1, B2, n2, src2, valid2, orig2, 5);

  // ---- up u=1 ----
  hipMemsetAsync(B0, 0, (size_t)n1 * D * 4, stream);
  k_scatter<<<(n2 + 3) / 4, 256, 0, stream>>>(B2, perm1, n2, B0);
  k_econv<<<(n1 + 3) / 4, 256, 0, stream>>>(B0, dst1, ec1, orig1, indptr_src, eids_src, n1, B1);
  conv(B1, B0, B2, n1, src1, valid1, orig1, 6);
  conv(B2, B0, B1, n1, src1, valid1, orig1, 7);
  k_add<<<((n1 * D / 4) + 255) / 256, 256, 0, stream>>>(B1, down1, B1, n1 * D / 4);

  // ---- up u=0 ----
  hipMemsetAsync(B0, 0, (size_t)n0 * D * 4, stream);
  k_scatter<<<(n1 + 3) / 4, 256, 0, stream>>>(B1, perm0, n1, B0);
  k_econv<<<(n0 + 3) / 4, 256, 0, stream>>>(B0, dst0, ec0, nullptr, indptr_src, eids_src, n0, B2);
  conv(B2, B0, B1, n0, src0, nullptr, nullptr, 8);
  conv(B1, B0, B2, n0, src0, nullptr, nullptr, 9);
  k_add<<<((n0 * D / 4) + 255) / 256, 256, 0, stream>>>(B2, down0, out, n0 * D / 4);
}

// Round 2
// 1505.738 us; speedup vs baseline: 1.5705x; 1.5705x over previous
//
#include <hip/hip_runtime.h>
#include <stdint.h>

#define DEV __device__ __forceinline__

constexpr int N0 = 50000;
constexpr int E0 = 800000;
constexpr int D  = 128;

DEV float bf2f(unsigned u) { return __uint_as_float(u << 16); }
DEV unsigned short f2bf(float f) {
  unsigned u = __float_as_uint(f);
  unsigned r = u + 0x7fffu + ((u >> 16) & 1u);   // round-to-nearest-even
  return (unsigned short)(r >> 16);
}

// ---------------- CSR build ----------------
__global__ void k_count(const int* __restrict__ src, const int* __restrict__ dst,
                        unsigned* cnt_src, unsigned* cnt_dst) {
  int e = blockIdx.x * blockDim.x + threadIdx.x;
  if (e < E0) {
    atomicAdd(&cnt_src[src[e]], 1u);
    atomicAdd(&cnt_dst[dst[e]], 1u);
  }
}

// single-block exclusive scan; out has n+1 entries
__global__ void k_scan(const unsigned* __restrict__ in, unsigned* __restrict__ out, int n) {
  __shared__ unsigned wsum[16], woff[16];
  __shared__ unsigned carry;
  int t = threadIdx.x, lane = t & 63, w = t >> 6;
  if (t == 0) carry = 0;
  __syncthreads();
  for (int base = 0; base < n; base += 1024) {
    int i = base + t;
    unsigned v = (i < n) ? in[i] : 0u;
    unsigned s = v;
    #pragma unroll
    for (int off = 1; off < 64; off <<= 1) {
      unsigned u = __shfl_up(s, (unsigned)off);
      if (lane >= off) s += u;
    }
    if (lane == 63) wsum[w] = s;
    __syncthreads();
    if (t == 0) {
      unsigned run = carry;
      for (int j = 0; j < 16; ++j) { woff[j] = run; run += wsum[j]; }
      carry = run;
    }
    __syncthreads();
    if (i < n) out[i] = woff[w] + s - v;
    __syncthreads();
  }
  if (threadIdx.x == 0) out[n] = carry;
}

// fill packed adjacency: adj[pos] = other endpoint of edge, slot order by key's CSR
__global__ void k_filla(const int* __restrict__ key, const int* __restrict__ other,
                        unsigned* cursor, int* __restrict__ adj) {
  int e = blockIdx.x * blockDim.x + threadIdx.x;
  if (e < E0) {
    unsigned pos = atomicAdd(&cursor[key[e]], 1u);
    adj[pos] = other[e];
  }
}

// compose level mask/relabel: adj_out[pos] = adj_prev[pos]>=0 ? new_id[adj_prev[pos]] : -1
__global__ void k_adj_next(const int* __restrict__ adj_prev, const int* __restrict__ new_id,
                           int* __restrict__ adj_out) {
  int pos = blockIdx.x * blockDim.x + threadIdx.x;
  if (pos < E0) {
    int a = adj_prev[pos];
    adj_out[pos] = (a >= 0) ? new_id[a] : -1;
  }
}

// ---------------- weight transpose: BT[c][k][o], k<128 -> Wl, else Wr ----------------
__global__ void k_wt(const float* __restrict__ Wl, const float* __restrict__ Wr, float* __restrict__ BT) {
  int idx = blockIdx.x * blockDim.x + threadIdx.x;
  if (idx < 10 * 256 * 128) {
    int o = idx & 127;
    int k = (idx >> 7) & 255;
    int c = idx >> 15;
    float v = (k < 128) ? Wl[(c * 128 + o) * 128 + k] : Wr[(c * 128 + o) * 128 + (k - 128)];
    BT[idx] = v;
  }
}

// ---------------- SAGE mean aggregation: wave per node, strip-mined x4 ----------------
template<bool BF, bool MASKED>
__global__ void k_sage(const void* __restrict__ xv, const int* __restrict__ adj,
                       const unsigned* __restrict__ indptr, const int* __restrict__ orig,
                       int n, float* __restrict__ mean) {
  int wid = (blockIdx.x * blockDim.x + threadIdx.x) >> 6;
  int lane = threadIdx.x & 63;
  if (wid >= n) return;
  int o = orig ? orig[wid] : wid;
  unsigned s0 = indptr[o], s1 = indptr[o + 1];
  const float* xf = (const float*)xv;
  const unsigned* xb = (const unsigned*)xv;
  float a0 = 0.f, a1 = 0.f, cnt = 0.f;
  unsigned idx = s0;
  for (; idx + 4 <= s1; idx += 4) {
    int ad[4];
    #pragma unroll
    for (int j = 0; j < 4; ++j) ad[j] = adj[idx + j];
    #pragma unroll
    for (int j = 0; j < 4; ++j) {
      if (!MASKED || ad[j] >= 0) {
        float x0, x1;
        if (BF) { unsigned u = xb[(size_t)ad[j] * 64 + lane]; x0 = bf2f(u & 0xffffu); x1 = bf2f(u >> 16); }
        else    { float2 v = *(const float2*)(xf + (size_t)ad[j] * D + lane * 2); x0 = v.x; x1 = v.y; }
        a0 += x0; a1 += x1; cnt += 1.f;
      }
    }
  }
  for (; idx < s1; ++idx) {
    int a = adj[idx];
    if (!MASKED || a >= 0) {
      float x0, x1;
      if (BF) { unsigned u = xb[(size_t)a * 64 + lane]; x0 = bf2f(u & 0xffffu); x1 = bf2f(u >> 16); }
      else    { float2 v = *(const float2*)(xf + (size_t)a * D + lane * 2); x0 = v.x; x1 = v.y; }
      a0 += x0; a1 += x1; cnt += 1.f;
    }
  }
  if (!MASKED) cnt = (float)(s1 - s0);
  float inv = 1.0f / fmaxf(cnt, 1.0f);
  *(float2*)(mean + (size_t)wid * D + lane * 2) = make_float2(a0 * inv, a1 * inv);
}

// ---------------- weighted edge conv: wave per node, ec in slot order ----------------
template<bool BF, bool MASKED>
__global__ void k_econv2(const void* __restrict__ xv, const int* __restrict__ adj,
                         const float* __restrict__ ecs, const unsigned* __restrict__ indptr,
                         const int* __restrict__ orig, int n,
                         float* __restrict__ out, unsigned* __restrict__ outbf) {
  int wid = (blockIdx.x * blockDim.x + threadIdx.x) >> 6;
  int lane = threadIdx.x & 63;
  if (wid >= n) return;
  int o = orig ? orig[wid] : wid;
  unsigned s0 = indptr[o], s1 = indptr[o + 1];
  const float* xf = (const float*)xv;
  const unsigned* xb = (const unsigned*)xv;
  float a0 = 0.f, a1 = 0.f;
  unsigned idx = s0;
  for (; idx + 4 <= s1; idx += 4) {
    int ad[4]; float wv[4];
    #pragma unroll
    for (int j = 0; j < 4; ++j) { ad[j] = adj[idx + j]; wv[j] = ecs[idx + j]; }
    #pragma unroll
    for (int j = 0; j < 4; ++j) {
      if (!MASKED || ad[j] >= 0) {
        float x0, x1;
        if (BF) { unsigned u = xb[(size_t)ad[j] * 64 + lane]; x0 = bf2f(u & 0xffffu); x1 = bf2f(u >> 16); }
        else    { float2 v = *(const float2*)(xf + (size_t)ad[j] * D + lane * 2); x0 = v.x; x1 = v.y; }
        a0 = fmaf(wv[j], x0, a0); a1 = fmaf(wv[j], x1, a1);
      }
    }
  }
  for (; idx < s1; ++idx) {
    int a = adj[idx]; float wgt = ecs[idx];
    if (!MASKED || a >= 0) {
      float x0, x1;
      if (BF) { unsigned u = xb[(size_t)a * 64 + lane]; x0 = bf2f(u & 0xffffu); x1 = bf2f(u >> 16); }
      else    { float2 v = *(const float2*)(xf + (size_t)a * D + lane * 2); x0 = v.x; x1 = v.y; }
      a0 = fmaf(wgt, x0, a0); a1 = fmaf(wgt, x1, a1);
    }
  }
  *(float2*)(out + (size_t)wid * D + lane * 2) = make_float2(a0, a1);
  if (outbf) {
    unsigned p = (unsigned)f2bf(a0) | ((unsigned)f2bf(a1) << 16);
    outbf[(size_t)wid * 64 + lane] = p;
  }
}

// ---------------- fused conv GEMM: y = mean@Wl^T + bl + x@Wr^T (+ bf16 mirror) ----------------
__launch_bounds__(256)
__global__ void k_conv_gemm(const float* __restrict__ mean, const float* __restrict__ xin,
                            const float* __restrict__ BT, const float* __restrict__ bias,
                            float* __restrict__ y, unsigned short* __restrict__ ybf, int n) {
  __shared__ float As[64][17];
  __shared__ float Bs[16][128];
  int tid = threadIdx.x;
  int tx = tid & 15, ty = tid >> 4;
  int row0 = blockIdx.x * 64;
  float acc[4][8];
  #pragma unroll
  for (int r = 0; r < 4; ++r)
    #pragma unroll
    for (int c = 0; c < 8; ++c) acc[r][c] = 0.f;

  int lm = tid >> 2;
  int lk = (tid & 3) * 4;
  int bk = tid >> 4;
  int bo = (tid & 15) * 8;

  for (int kc = 0; kc < 16; ++kc) {
    int k0 = kc * 16;
    const float* A = (k0 < 128) ? mean : xin;
    int kk = k0 & 127;
    int gr = row0 + lm;
    float4 av = make_float4(0.f, 0.f, 0.f, 0.f);
    if (gr < n) av = *(const float4*)(A + (size_t)gr * D + kk + lk);
    As[lm][lk + 0] = av.x; As[lm][lk + 1] = av.y; As[lm][lk + 2] = av.z; As[lm][lk + 3] = av.w;
    float4 bv0 = *(const float4*)(BT + (size_t)(k0 + bk) * 128 + bo);
    float4 bv1 = *(const float4*)(BT + (size_t)(k0 + bk) * 128 + bo + 4);
    *(float4*)&Bs[bk][bo] = bv0;
    *(float4*)&Bs[bk][bo + 4] = bv1;
    __syncthreads();
    #pragma unroll
    for (int k = 0; k < 16; ++k) {
      float a[4];
      #pragma unroll
      for (int r = 0; r < 4; ++r) a[r] = As[ty * 4 + r][k];
      float4 b0 = *(const float4*)&Bs[k][tx * 4];
      float4 b1 = *(const float4*)&Bs[k][64 + tx * 4];
      float bb[8] = {b0.x, b0.y, b0.z, b0.w, b1.x, b1.y, b1.z, b1.w};
      #pragma unroll
      for (int r = 0; r < 4; ++r)
        #pragma unroll
        for (int c = 0; c < 8; ++c)
          acc[r][c] = fmaf(a[r], bb[c], acc[r][c]);
    }
    __syncthreads();
  }
  float4 bs0 = *(const float4*)(bias + tx * 4);
  float4 bs1 = *(const float4*)(bias + 64 + tx * 4);
  #pragma unroll
  for (int r = 0; r < 4; ++r) {
    int gr = row0 + ty * 4 + r;
    if (gr < n) {
      float4 o0 = make_float4(acc[r][0] + bs0.x, acc[r][1] + bs0.y, acc[r][2] + bs0.z, acc[r][3] + bs0.w);
      float4 o1 = make_float4(acc[r][4] + bs1.x, acc[r][5] + bs1.y, acc[r][6] + bs1.z, acc[r][7] + bs1.w);
      *(float4*)(y + (size_t)gr * D + tx * 4) = o0;
      *(float4*)(y + (size_t)gr * D + 64 + tx * 4) = o1;
      if (ybf) {
        ushort4 p0; p0.x = f2bf(o0.x); p0.y = f2bf(o0.y); p0.z = f2bf(o0.z); p0.w = f2bf(o0.w);
        ushort4 p1; p1.x = f2bf(o1.x); p1.y = f2bf(o1.y); p1.z = f2bf(o1.z); p1.w = f2bf(o1.w);
        *(ushort4*)(ybf + (size_t)gr * D + tx * 4) = p0;
        *(ushort4*)(ybf + (size_t)gr * D + 64 + tx * 4) = p1;
      }
    }
  }
}

// ---------------- cal_ew (all in CSR slot order) ----------------
__global__ void k_deg_len(const unsigned* __restrict__ indptr, int n, float* __restrict__ deg) {
  int j = blockIdx.x * blockDim.x + threadIdx.x;
  if (j < n) deg[j] = (float)(indptr[j + 1] - indptr[j]);
}

__global__ void k_deg_mask(const int* __restrict__ adj_src, const unsigned* __restrict__ indptr_src,
                           const int* __restrict__ orig, int n, float* __restrict__ deg) {
  int j = blockIdx.x * blockDim.x + threadIdx.x;
  if (j >= n) return;
  int o = orig ? orig[j] : j;
  unsigned s0 = indptr_src[o], s1 = indptr_src[o + 1];
  float d = 0.f;
  for (unsigned i = s0; i < s1; ++i) d += (adj_src[i] >= 0) ? 1.f : 0.f;
  deg[j] = d;
}

// per dst-node: ws_slot, aggrw (=sum+EPS), ec_dst_slot
template<bool MASKED>
__global__ void k_ew_dst(const int* __restrict__ adj, const unsigned* __restrict__ indptr,
                         const int* __restrict__ orig, const float* __restrict__ w,
                         const float* __restrict__ deg, int n,
                         float* __restrict__ ws_slot, float* __restrict__ aggrw,
                         float* __restrict__ ec_slot) {
  int j = blockIdx.x * blockDim.x + threadIdx.x;
  if (j >= n) return;
  int o = orig ? orig[j] : j;
  unsigned s0 = indptr[o], s1 = indptr[o + 1];
  float s = 1e-12f;
  for (unsigned pos = s0; pos < s1; ++pos) {
    int a = adj[pos];
    float ws = 0.f;
    if (!MASKED || a >= 0) {
      float d = deg[a];
      ws = (w ? w[a] : 1.0f) / (d > 0.f ? d : 1.0f);
    }
    ws_slot[pos] = ws;
    s += ws;
  }
  aggrw[j] = s;
  float inv = 1.0f / s;
  for (unsigned pos = s0; pos < s1; ++pos) ec_slot[pos] = ws_slot[pos] * inv;
}

// per src-node: ec in src-CSR slot order (for the up/un-aggregating econv)
template<bool MASKED>
__global__ void k_ew_src(const int* __restrict__ adj_src, const unsigned* __restrict__ indptr_src,
                         const int* __restrict__ orig, const float* __restrict__ w,
                         const float* __restrict__ deg, const float* __restrict__ aggrw, int n,
                         float* __restrict__ ec_slot) {
  int j = blockIdx.x * blockDim.x + threadIdx.x;
  if (j >= n) return;
  int o = orig ? orig[j] : j;
  unsigned s0 = indptr_src[o], s1 = indptr_src[o + 1];
  float d = deg[j];
  float wn = (w ? w[j] : 1.0f) / (d > 0.f ? d : 1.0f);
  for (unsigned pos = s0; pos < s1; ++pos) {
    int a = adj_src[pos];
    ec_slot[pos] = (!MASKED || a >= 0) ? (wn / aggrw[a]) : 0.f;
  }
}

// ---------------- pooling ----------------
DEV unsigned mono_key(float f) {
  unsigned u = __float_as_uint(f);
  return (u & 0x80000000u) ? ~u : (u | 0x80000000u);
}

__global__ void k_pnorm(const float* __restrict__ p, float* __restrict__ pinv) {
  int lane = threadIdx.x;
  float v = p[lane] * p[lane] + p[lane + 64] * p[lane + 64];
  #pragma unroll
  for (int off = 32; off >= 1; off >>= 1) v += __shfl_xor(v, off);
  if (lane == 0) *pinv = 1.0f / sqrtf(v);
}

__global__ void k_score(const float* __restrict__ x, const float* __restrict__ p,
                        const float* __restrict__ pinv, int n,
                        float* __restrict__ score, unsigned* __restrict__ keys) {
  int wid = (blockIdx.x * blockDim.x + threadIdx.x) >> 6;
  int lane = threadIdx.x & 63;
  if (wid >= n) return;
  const float2 xv = *(const float2*)(x + (size_t)wid * D + lane * 2);
  float partial = xv.x * p[lane * 2] + xv.y * p[lane * 2 + 1];
  #pragma unroll
  for (int off = 32; off >= 1; off >>= 1) partial += __shfl_xor(partial, off);
  if (lane == 0) {
    float sc = partial * (*pinv);
    score[wid] = sc;
    keys[wid] = mono_key(sc);
  }
}

__global__ void k_sel_init(unsigned* bins, unsigned* state, int k) {
  int t = threadIdx.x;
  if (t < 256) bins[t] = 0u;
  if (t == 0) { state[0] = 0u; state[1] = (unsigned)k; }
}

__global__ void k_hist(const unsigned* __restrict__ keys, int n, const unsigned* __restrict__ state,
                       unsigned* __restrict__ bins, int byte) {
  __shared__ unsigned lb[256];
  for (int i = threadIdx.x; i < 256; i += blockDim.x) lb[i] = 0u;
  __syncthreads();
  unsigned prefix = state[0];
  unsigned mask = (byte == 3) ? 0u : (0xFFFFFFFFu << ((byte + 1) * 8));
  for (int i = blockIdx.x * blockDim.x + threadIdx.x; i < n; i += gridDim.x * blockDim.x) {
    unsigned key = keys[i];
    if ((key & mask) == (prefix & mask))
      atomicAdd(&lb[(key >> (byte * 8)) & 255], 1u);
  }
  __syncthreads();
  for (int i = threadIdx.x; i < 256; i += blockDim.x)
    if (lb[i]) atomicAdd(&bins[i], lb[i]);
}

__global__ void k_pick(unsigned* bins, unsigned* state, int byte) {
  if (threadIdx.x == 0) {
    unsigned r = state[1];
    int b;
    for (b = 255; b > 0; --b) {
      unsigned c = bins[b];
      if (c >= r) break;
      r -= c;
    }
    state[0] |= ((unsigned)b) << (byte * 8);
    state[1] = r;
  }
  __syncthreads();
  for (int i = threadIdx.x; i < 256; i += blockDim.x) bins[i] = 0u;
}

__global__ void k_pack(const unsigned* __restrict__ keys, const unsigned* __restrict__ state,
                       const float* __restrict__ aggrw, const int* __restrict__ orig,
                       int n, int* __restrict__ perm, int* __restrict__ new_id,
                       float* __restrict__ w_next, int* __restrict__ orig_next) {
  __shared__ unsigned wsA[16], offA[16], wsB[16], offB[16];
  __shared__ unsigned cEq, cSel;
  int t = threadIdx.x, lane = t & 63, w = t >> 6;
  unsigned T = state[0], r = state[1];
  if (t == 0) { cEq = 0; cSel = 0; }
  __syncthreads();
  for (int base = 0; base < n; base += 1024) {
    int i = base + t;
    unsigned key = (i < n) ? keys[i] : 0u;
    unsigned gt = (i < n && key > T) ? 1u : 0u;
    unsigned eq = (i < n && key == T) ? 1u : 0u;
    unsigned s = eq;
    #pragma unroll
    for (int off = 1; off < 64; off <<= 1) {
      unsigned u = __shfl_up(s, (unsigned)off);
      if (lane >= off) s += u;
    }
    if (lane == 63) wsA[w] = s;
    __syncthreads();
    if (t == 0) {
      unsigned run = cEq;
      for (int j = 0; j < 16; ++j) { offA[j] = run; run += wsA[j]; }
      cEq = run;
    }
    __syncthreads();
    unsigned eqrank = offA[w] + s - eq;
    unsigned sel = gt | (eq & ((eqrank < r) ? 1u : 0u));
    unsigned s2 = sel;
    #pragma unroll
    for (int off = 1; off < 64; off <<= 1) {
      unsigned u = __shfl_up(s2, (unsigned)off);
      if (lane >= off) s2 += u;
    }
    if (lane == 63) wsB[w] = s2;
    __syncthreads();
    if (t == 0) {
      unsigned run = cSel;
      for (int j = 0; j < 16; ++j) { offB[j] = run; run += wsB[j]; }
      cSel = run;
    }
    __syncthreads();
    if (i < n) {
      if (sel) {
        int pos = (int)(offB[w] + s2 - sel);
        perm[pos] = i;
        new_id[i] = pos;
        w_next[pos] = aggrw[i];
        orig_next[pos] = orig ? orig[i] : i;
      } else {
        new_id[i] = -1;
      }
    }
    __syncthreads();
  }
}

__global__ void k_gate(const float* __restrict__ xin, const int* __restrict__ perm,
                       const float* __restrict__ score, int k, float* __restrict__ xout,
                       unsigned* __restrict__ outbf) {
  int wid = (blockIdx.x * blockDim.x + threadIdx.x) >> 6;
  int lane = threadIdx.x & 63;
  if (wid >= k) return;
  int j = perm[wid];
  float g = tanhf(score[j]);
  float2 v = *(const float2*)(xin + (size_t)j * D + lane * 2);
  v.x *= g; v.y *= g;
  *(float2*)(xout + (size_t)wid * D + lane * 2) = v;
  if (outbf) {
    unsigned p = (unsigned)f2bf(v.x) | ((unsigned)f2bf(v.y) << 16);
    outbf[(size_t)wid * 64 + lane] = p;
  }
}

// unpool: write bf16 mirror only (mirror pre-zeroed); consumers gather bf16
__global__ void k_scatter_bf(const float* __restrict__ xin, const int* __restrict__ perm,
                             int k, unsigned* __restrict__ outbf) {
  int wid = (blockIdx.x * blockDim.x + threadIdx.x) >> 6;
  int lane = threadIdx.x & 63;
  if (wid >= k) return;
  int p = perm[wid];
  float2 v = *(const float2*)(xin + (size_t)wid * D + lane * 2);
  unsigned pk = (unsigned)f2bf(v.x) | ((unsigned)f2bf(v.y) << 16);
  outbf[(size_t)p * 64 + lane] = pk;
}

__global__ void k_add(const float* __restrict__ a, const float* __restrict__ b,
                      float* __restrict__ out, int total4) {
  int i = blockIdx.x * blockDim.x + threadIdx.x;
  if (i < total4) {
    float4 av = ((const float4*)a)[i];
    float4 bv = ((const float4*)b)[i];
    ((float4*)out)[i] = make_float4(av.x + bv.x, av.y + bv.y, av.z + bv.z, av.w + bv.w);
  }
}

// =============================================================================
extern "C" void kernel_launch(void* const* d_in, const int* in_sizes, int n_in,
                              void* d_out, int out_size, void* d_ws, size_t ws_size,
                              hipStream_t stream) {
  const float* x_in   = (const float*)d_in[0];
  const int*   ei     = (const int*)d_in[1];
  const int*   src0   = ei;
  const int*   dst0   = ei + E0;
  const float* Wl     = (const float*)d_in[2];
  const float* bl     = (const float*)d_in[3];
  const float* Wr     = (const float*)d_in[4];
  const float* pool_p = (const float*)d_in[5];
  float* out = (float*)d_out;

  const int n0 = N0, k0 = 25000, n1 = 25000, k1 = 12500, n2 = 12500;

  char* ws = (char*)d_ws;
  size_t off = 0;
  auto alloc = [&](size_t bytes) -> char* {
    char* p = ws + off;
    off += (bytes + 255) & ~(size_t)255;
    return p;
  };
  const size_t NBY = (size_t)N0 * D * 4;   // 25.6 MB
  float* B0    = (float*)alloc(NBY);
  float* B1    = (float*)alloc(NBY);
  float* B2    = (float*)alloc(NBY);
  float* down0 = (float*)alloc(NBY);
  float* down1 = (float*)alloc(NBY / 2);
  unsigned* MA = (unsigned*)alloc((size_t)N0 * D * 2);  // bf16 mirror A
  unsigned* MB = (unsigned*)alloc((size_t)N0 * D * 2);  // bf16 mirror B
  int* adj0_dst = (int*)alloc(E0 * 4);
  int* adj0_src = (int*)alloc(E0 * 4);
  int* adj1_dst = (int*)alloc(E0 * 4);
  int* adj1_src = (int*)alloc(E0 * 4);
  float* ec0_src = (float*)alloc(E0 * 4);
  float* ec1_src = (float*)alloc(E0 * 4);
  float* ec_dst  = (float*)alloc(E0 * 4);
  float* ws_slot = (float*)alloc(E0 * 4);
  int* adj2_dst  = (int*)ws_slot;          // alias: ws_slot dead before adj2 is built
  unsigned* indptr_dst = (unsigned*)alloc((N0 + 1) * 4);
  unsigned* indptr_src = (unsigned*)alloc((N0 + 1) * 4);
  unsigned* cnt_src = (unsigned*)alloc(N0 * 4);   // reused as fill cursor
  unsigned* cnt_dst = (unsigned*)alloc(N0 * 4);
  float* deg   = (float*)alloc(N0 * 4);
  float* aggrw = (float*)alloc(N0 * 4);
  float* w1 = (float*)alloc(n1 * 4);
  float* w2 = (float*)alloc(n2 * 4);
  float* score = (float*)alloc(N0 * 4);
  unsigned* keys = (unsigned*)alloc(N0 * 4);
  int* perm0 = (int*)alloc(k0 * 4);
  int* perm1 = (int*)alloc(k1 * 4);
  int* orig1 = (int*)alloc(k0 * 4);
  int* orig2 = (int*)alloc(k1 * 4);
  int* new_id = (int*)alloc(N0 * 4);
  unsigned* bins  = (unsigned*)alloc(256 * 4);
  unsigned* state = (unsigned*)alloc(8);
  float* pinv = (float*)alloc(4);
  float* BT = (float*)alloc((size_t)10 * 256 * 128 * 4);

  const int EG = (E0 + 255) / 256;

  // ---- CSR build ----
  hipMemsetAsync(cnt_src, 0, N0 * 4, stream);
  hipMemsetAsync(cnt_dst, 0, N0 * 4, stream);
  k_count<<<EG, 256, 0, stream>>>(src0, dst0, cnt_src, cnt_dst);
  k_scan<<<1, 1024, 0, stream>>>(cnt_src, indptr_src, N0);
  k_scan<<<1, 1024, 0, stream>>>(cnt_dst, indptr_dst, N0);
  hipMemcpyAsync(cnt_dst, indptr_dst, N0 * 4, hipMemcpyDeviceToDevice, stream);
  k_filla<<<EG, 256, 0, stream>>>(dst0, src0, cnt_dst, adj0_dst);
  hipMemcpyAsync(cnt_src, indptr_src, N0 * 4, hipMemcpyDeviceToDevice, stream);
  k_filla<<<EG, 256, 0, stream>>>(src0, dst0, cnt_src, adj0_src);
  k_wt<<<(10 * 256 * 128 + 255) / 256, 256, 0, stream>>>(Wl, Wr, BT);

  auto gemm = [&](const float* meanb, const float* xin, float* yout, unsigned short* ybf,
                  int n, int cidx) {
    k_conv_gemm<<<(n + 63) / 64, 256, 0, stream>>>(meanb, xin, BT + (size_t)cidx * 256 * 128,
                                                   bl + cidx * 128, yout, ybf, n);
  };

  auto pool_sel = [&](const float* xpool, int n, int kk, int level, const int* orig,
                      int* perm, float* w_next, int* orig_next,
                      float* xout, unsigned* xout_bf) {
    k_pnorm<<<1, 64, 0, stream>>>(pool_p + level * D, pinv);
    k_score<<<(n + 3) / 4, 256, 0, stream>>>(xpool, pool_p + level * D, pinv, n, score, keys);
    k_sel_init<<<1, 256, 0, stream>>>(bins, state, kk);
    for (int byte = 3; byte >= 0; --byte) {
      k_hist<<<256, 256, 0, stream>>>(keys, n, state, bins, byte);
      k_pick<<<1, 256, 0, stream>>>(bins, state, byte);
    }
    k_pack<<<1, 1024, 0, stream>>>(keys, state, aggrw, orig, n, perm, new_id, w_next, orig_next);
    k_gate<<<(kk + 3) / 4, 256, 0, stream>>>(xpool, perm, score, kk, xout, xout_bf);
  };

  // ======== down level 0 (f32, selection-exact) ========
  k_sage<false, false><<<(n0 + 3) / 4, 256, 0, stream>>>(x_in, adj0_dst, indptr_dst, nullptr, n0, B1);
  gemm(B1, x_in, B2, nullptr, n0, 0);
  k_sage<false, false><<<(n0 + 3) / 4, 256, 0, stream>>>(B2, adj0_dst, indptr_dst, nullptr, n0, B1);
  gemm(B1, B2, down0, nullptr, n0, 1);
  // cal_ew level 0
  k_deg_len<<<(n0 + 255) / 256, 256, 0, stream>>>(indptr_src, n0, deg);
  k_ew_dst<false><<<(n0 + 255) / 256, 256, 0, stream>>>(adj0_dst, indptr_dst, nullptr, nullptr, deg, n0,
                                                        ws_slot, aggrw, ec_dst);
  k_ew_src<false><<<(n0 + 255) / 256, 256, 0, stream>>>(adj0_src, indptr_src, nullptr, nullptr, deg, aggrw,
                                                        n0, ec0_src);
  k_econv2<false, false><<<(n0 + 3) / 4, 256, 0, stream>>>(down0, adj0_dst, ec_dst, indptr_dst, nullptr,
                                                           n0, B1, nullptr);
  // pool 0 (output stays f32 — level-1 selection must be exact)
  pool_sel(B1, n0, k0, 0, nullptr, perm0, w1, orig1, B2, nullptr);
  k_adj_next<<<EG, 256, 0, stream>>>(adj0_dst, new_id, adj1_dst);
  k_adj_next<<<EG, 256, 0, stream>>>(adj0_src, new_id, adj1_src);

  // ======== down level 1 (f32) ========
  k_sage<false, true><<<(n1 + 3) / 4, 256, 0, stream>>>(B2, adj1_dst, indptr_dst, orig1, n1, B1);
  gemm(B1, B2, B0, nullptr, n1, 2);
  k_sage<false, true><<<(n1 + 3) / 4, 256, 0, stream>>>(B0, adj1_dst, indptr_dst, orig1, n1, B1);
  gemm(B1, B0, down1, nullptr, n1, 3);
  // cal_ew level 1
  k_deg_mask<<<(n1 + 255) / 256, 256, 0, stream>>>(adj1_src, indptr_src, orig1, n1, deg);
  k_ew_dst<true><<<(n1 + 255) / 256, 256, 0, stream>>>(adj1_dst, indptr_dst, orig1, w1, deg, n1,
                                                       ws_slot, aggrw, ec_dst);
  k_ew_src<true><<<(n1 + 255) / 256, 256, 0, stream>>>(adj1_src, indptr_src, orig1, w1, deg, aggrw,
                                                       n1, ec1_src);
  k_econv2<false, true><<<(n1 + 3) / 4, 256, 0, stream>>>(down1, adj1_dst, ec_dst, indptr_dst, orig1,
                                                          n1, B1, nullptr);
  // pool 1 (output feeds selection-free bottom -> bf16 mirror MA)
  pool_sel(B1, n1, k1, 1, orig1, perm1, w2, orig2, B2, MA);
  k_adj_next<<<EG, 256, 0, stream>>>(adj1_dst, new_id, adj2_dst);   // aliases ws_slot (dead)

  // ======== bottom (bf16 gathers) ========
  k_sage<true, true><<<(n2 + 3) / 4, 256, 0, stream>>>(MA, adj2_dst, indptr_dst, orig2, n2, B1);
  gemm(B1, B2, B0, (unsigned short*)MB, n2, 4);
  k_sage<true, true><<<(n2 + 3) / 4, 256, 0, stream>>>(MB, adj2_dst, indptr_dst, orig2, n2, B1);
  gemm(B1, B0, B2, nullptr, n2, 5);

  // ======== up u=1 (bf16 gathers) ========
  hipMemsetAsync(MA, 0, (size_t)n1 * D * 2, stream);
  k_scatter_bf<<<(n2 + 3) / 4, 256, 0, stream>>>(B2, perm1, n2, MA);
  k_econv2<true, true><<<(n1 + 3) / 4, 256, 0, stream>>>(MA, adj1_src, ec1_src, indptr_src, orig1,
                                                         n1, B1, MB);
  k_sage<true, true><<<(n1 + 3) / 4, 256, 0, stream>>>(MB, adj1_dst, indptr_dst, orig1, n1, B0);
  gemm(B0, B1, B2, (unsigned short*)MA, n1, 6);
  k_sage<true, true><<<(n1 + 3) / 4, 256, 0, stream>>>(MA, adj1_dst, indptr_dst, orig1, n1, B0);
  gemm(B0, B2, B1, nullptr, n1, 7);
  k_add<<<((n1 * D / 4) + 255) / 256, 256, 0, stream>>>(B1, down1, B1, n1 * D / 4);

  // ======== up u=0 (bf16 gathers) ========
  hipMemsetAsync(MA, 0, (size_t)n0 * D * 2, stream);
  k_scatter_bf<<<(n1 + 3) / 4, 256, 0, stream>>>(B1, perm0, n1, MA);
  k_econv2<true, false><<<(n0 + 3) / 4, 256, 0, stream>>>(MA, adj0_src, ec0_src, indptr_src, nullptr,
                                                          n0, B2, MB);
  k_sage<true, false><<<(n0 + 3) / 4, 256, 0, stream>>>(MB, adj0_dst, indptr_dst, nullptr, n0, B1);
  gemm(B1, B2, B0, (unsigned short*)MA, n0, 8);
  k_sage<true, false><<<(n0 + 3) / 4, 256, 0, stream>>>(MA, adj0_dst, indptr_dst, nullptr, n0, B1);
  gemm(B1, B0, B2, nullptr, n0, 9);
  k_add<<<((n0 * D / 4) + 255) / 256, 256, 0, stream>>>(B2, down0, out, n0 * D / 4);
}

// Round 3
// 1333.366 us; speedup vs baseline: 1.7736x; 1.1293x over previous
//
#include <hip/hip_runtime.h>
#include <stdint.h>

#define DEV __device__ __forceinline__

constexpr int N0 = 50000;
constexpr int E0 = 800000;
constexpr int D  = 128;

DEV float bf2f(unsigned u) { return __uint_as_float(u << 16); }
DEV unsigned short f2bf(float f) {
  unsigned u = __float_as_uint(f);
  unsigned r = u + 0x7fffu + ((u >> 16) & 1u);   // round-to-nearest-even
  return (unsigned short)(r >> 16);
}

DEV unsigned wave_incl_scan(unsigned v, int lane) {
  #pragma unroll
  for (int off = 1; off < 64; off <<= 1) {
    unsigned u = __shfl_up(v, (unsigned)off);
    if (lane >= off) v += u;
  }
  return v;
}

// ---------------- CSR build ----------------
__global__ void k_count(const int* __restrict__ src, const int* __restrict__ dst,
                        unsigned* cnt_src, unsigned* cnt_dst) {
  int e = blockIdx.x * blockDim.x + threadIdx.x;
  if (e < E0) {
    atomicAdd(&cnt_src[src[e]], 1u);
    atomicAdd(&cnt_dst[dst[e]], 1u);
  }
}

// ---- 2-level exclusive scan: partial sums -> tiny serial scan -> apply ----
__global__ void k_psum(const unsigned* __restrict__ in, int n, unsigned* __restrict__ part) {
  int t = threadIdx.x, lane = t & 63, w = t >> 6;
  int base = blockIdx.x * 1024 + t * 4;
  unsigned s = 0;
  #pragma unroll
  for (int j = 0; j < 4; ++j) { int i = base + j; if (i < n) s += in[i]; }
  #pragma unroll
  for (int off = 32; off >= 1; off >>= 1) s += __shfl_xor(s, off);
  __shared__ unsigned ws[4];
  if (lane == 0) ws[w] = s;
  __syncthreads();
  if (t == 0) part[blockIdx.x] = ws[0] + ws[1] + ws[2] + ws[3];
}

__global__ void k_scoff(const unsigned* __restrict__ part, int nch,
                        unsigned* __restrict__ off, unsigned* __restrict__ total_out) {
  if (threadIdx.x == 0) {
    unsigned run = 0;
    for (int c = 0; c < nch; ++c) { off[c] = run; run += part[c]; }
    *total_out = run;
  }
}

__global__ void k_sapply(const unsigned* __restrict__ in, const unsigned* __restrict__ choff,
                         int n, unsigned* __restrict__ out) {
  int t = threadIdx.x, lane = t & 63, w = t >> 6;
  int base = blockIdx.x * 1024 + t * 4;
  unsigned v[4]; unsigned s = 0;
  #pragma unroll
  for (int j = 0; j < 4; ++j) { int i = base + j; v[j] = (i < n) ? in[i] : 0u; s += v[j]; }
  unsigned incl = wave_incl_scan(s, lane);
  __shared__ unsigned wsum[4], woff[4];
  if (lane == 63) wsum[w] = incl;
  __syncthreads();
  if (t == 0) { unsigned run = 0; for (int j = 0; j < 4; ++j) { woff[j] = run; run += wsum[j]; } }
  __syncthreads();
  unsigned run = choff[blockIdx.x] + woff[w] + incl - s;
  #pragma unroll
  for (int j = 0; j < 4; ++j) {
    int i = base + j;
    if (i < n) out[i] = run;
    run += v[j];
  }
}

// fill packed adjacency: adj[pos] = other endpoint of edge, slot order by key's CSR
__global__ void k_filla(const int* __restrict__ key, const int* __restrict__ other,
                        unsigned* cursor, int* __restrict__ adj) {
  int e = blockIdx.x * blockDim.x + threadIdx.x;
  if (e < E0) {
    unsigned pos = atomicAdd(&cursor[key[e]], 1u);
    adj[pos] = other[e];
  }
}

// compose level mask/relabel
__global__ void k_adj_next(const int* __restrict__ adj_prev, const int* __restrict__ new_id,
                           int* __restrict__ adj_out) {
  int pos = blockIdx.x * blockDim.x + threadIdx.x;
  if (pos < E0) {
    int a = adj_prev[pos];
    adj_out[pos] = (a >= 0) ? new_id[a] : -1;
  }
}

// ---------------- weight transpose: BT[c][k][o], k<128 -> Wl, else Wr ----------------
__global__ void k_wt(const float* __restrict__ Wl, const float* __restrict__ Wr, float* __restrict__ BT) {
  int idx = blockIdx.x * blockDim.x + threadIdx.x;
  if (idx < 10 * 256 * 128) {
    int o = idx & 127;
    int k = (idx >> 7) & 255;
    int c = idx >> 15;
    float v = (k < 128) ? Wl[(c * 128 + o) * 128 + k] : Wr[(c * 128 + o) * 128 + (k - 128)];
    BT[idx] = v;
  }
}

// ---------------- SAGE mean aggregation: wave per node, strip-mined x4 ----------------
template<bool BF, bool MASKED>
__global__ void k_sage(const void* __restrict__ xv, const int* __restrict__ adj,
                       const unsigned* __restrict__ indptr, const int* __restrict__ orig,
                       int n, float* __restrict__ mean) {
  int wid = (blockIdx.x * blockDim.x + threadIdx.x) >> 6;
  int lane = threadIdx.x & 63;
  if (wid >= n) return;
  int o = orig ? orig[wid] : wid;
  unsigned s0 = indptr[o], s1 = indptr[o + 1];
  const float* xf = (const float*)xv;
  const unsigned* xb = (const unsigned*)xv;
  float a0 = 0.f, a1 = 0.f, cnt = 0.f;
  unsigned idx = s0;
  for (; idx + 4 <= s1; idx += 4) {
    int ad[4];
    #pragma unroll
    for (int j = 0; j < 4; ++j) ad[j] = adj[idx + j];
    #pragma unroll
    for (int j = 0; j < 4; ++j) {
      if (!MASKED || ad[j] >= 0) {
        float x0, x1;
        if (BF) { unsigned u = xb[(size_t)ad[j] * 64 + lane]; x0 = bf2f(u & 0xffffu); x1 = bf2f(u >> 16); }
        else    { float2 v = *(const float2*)(xf + (size_t)ad[j] * D + lane * 2); x0 = v.x; x1 = v.y; }
        a0 += x0; a1 += x1; cnt += 1.f;
      }
    }
  }
  for (; idx < s1; ++idx) {
    int a = adj[idx];
    if (!MASKED || a >= 0) {
      float x0, x1;
      if (BF) { unsigned u = xb[(size_t)a * 64 + lane]; x0 = bf2f(u & 0xffffu); x1 = bf2f(u >> 16); }
      else    { float2 v = *(const float2*)(xf + (size_t)a * D + lane * 2); x0 = v.x; x1 = v.y; }
      a0 += x0; a1 += x1; cnt += 1.f;
    }
  }
  if (!MASKED) cnt = (float)(s1 - s0);
  float inv = 1.0f / fmaxf(cnt, 1.0f);
  *(float2*)(mean + (size_t)wid * D + lane * 2) = make_float2(a0 * inv, a1 * inv);
}

// ---------------- weighted edge conv ----------------
template<bool BF, bool MASKED>
__global__ void k_econv2(const void* __restrict__ xv, const int* __restrict__ adj,
                         const float* __restrict__ ecs, const unsigned* __restrict__ indptr,
                         const int* __restrict__ orig, int n,
                         float* __restrict__ out, unsigned* __restrict__ outbf) {
  int wid = (blockIdx.x * blockDim.x + threadIdx.x) >> 6;
  int lane = threadIdx.x & 63;
  if (wid >= n) return;
  int o = orig ? orig[wid] : wid;
  unsigned s0 = indptr[o], s1 = indptr[o + 1];
  const float* xf = (const float*)xv;
  const unsigned* xb = (const unsigned*)xv;
  float a0 = 0.f, a1 = 0.f;
  unsigned idx = s0;
  for (; idx + 4 <= s1; idx += 4) {
    int ad[4]; float wv[4];
    #pragma unroll
    for (int j = 0; j < 4; ++j) { ad[j] = adj[idx + j]; wv[j] = ecs[idx + j]; }
    #pragma unroll
    for (int j = 0; j < 4; ++j) {
      if (!MASKED || ad[j] >= 0) {
        float x0, x1;
        if (BF) { unsigned u = xb[(size_t)ad[j] * 64 + lane]; x0 = bf2f(u & 0xffffu); x1 = bf2f(u >> 16); }
        else    { float2 v = *(const float2*)(xf + (size_t)ad[j] * D + lane * 2); x0 = v.x; x1 = v.y; }
        a0 = fmaf(wv[j], x0, a0); a1 = fmaf(wv[j], x1, a1);
      }
    }
  }
  for (; idx < s1; ++idx) {
    int a = adj[idx]; float wgt = ecs[idx];
    if (!MASKED || a >= 0) {
      float x0, x1;
      if (BF) { unsigned u = xb[(size_t)a * 64 + lane]; x0 = bf2f(u & 0xffffu); x1 = bf2f(u >> 16); }
      else    { float2 v = *(const float2*)(xf + (size_t)a * D + lane * 2); x0 = v.x; x1 = v.y; }
      a0 = fmaf(wgt, x0, a0); a1 = fmaf(wgt, x1, a1);
    }
  }
  *(float2*)(out + (size_t)wid * D + lane * 2) = make_float2(a0, a1);
  if (outbf) {
    unsigned p = (unsigned)f2bf(a0) | ((unsigned)f2bf(a1) << 16);
    outbf[(size_t)wid * 64 + lane] = p;
  }
}

// ---------------- fused conv GEMM: y = mean@Wl^T + bl + x@Wr^T (+ bf16 mirror) ----------------
__launch_bounds__(256)
__global__ void k_conv_gemm(const float* __restrict__ mean, const float* __restrict__ xin,
                            const float* __restrict__ BT, const float* __restrict__ bias,
                            float* __restrict__ y, unsigned short* __restrict__ ybf, int n) {
  __shared__ float As[64][17];
  __shared__ float Bs[16][128];
  int tid = threadIdx.x;
  int tx = tid & 15, ty = tid >> 4;
  int row0 = blockIdx.x * 64;
  float acc[4][8];
  #pragma unroll
  for (int r = 0; r < 4; ++r)
    #pragma unroll
    for (int c = 0; c < 8; ++c) acc[r][c] = 0.f;

  int lm = tid >> 2;
  int lk = (tid & 3) * 4;
  int bk = tid >> 4;
  int bo = (tid & 15) * 8;

  for (int kc = 0; kc < 16; ++kc) {
    int k0 = kc * 16;
    const float* A = (k0 < 128) ? mean : xin;
    int kk = k0 & 127;
    int gr = row0 + lm;
    float4 av = make_float4(0.f, 0.f, 0.f, 0.f);
    if (gr < n) av = *(const float4*)(A + (size_t)gr * D + kk + lk);
    As[lm][lk + 0] = av.x; As[lm][lk + 1] = av.y; As[lm][lk + 2] = av.z; As[lm][lk + 3] = av.w;
    float4 bv0 = *(const float4*)(BT + (size_t)(k0 + bk) * 128 + bo);
    float4 bv1 = *(const float4*)(BT + (size_t)(k0 + bk) * 128 + bo + 4);
    *(float4*)&Bs[bk][bo] = bv0;
    *(float4*)&Bs[bk][bo + 4] = bv1;
    __syncthreads();
    #pragma unroll
    for (int k = 0; k < 16; ++k) {
      float a[4];
      #pragma unroll
      for (int r = 0; r < 4; ++r) a[r] = As[ty * 4 + r][k];
      float4 b0 = *(const float4*)&Bs[k][tx * 4];
      float4 b1 = *(const float4*)&Bs[k][64 + tx * 4];
      float bb[8] = {b0.x, b0.y, b0.z, b0.w, b1.x, b1.y, b1.z, b1.w};
      #pragma unroll
      for (int r = 0; r < 4; ++r)
        #pragma unroll
        for (int c = 0; c < 8; ++c)
          acc[r][c] = fmaf(a[r], bb[c], acc[r][c]);
    }
    __syncthreads();
  }
  float4 bs0 = *(const float4*)(bias + tx * 4);
  float4 bs1 = *(const float4*)(bias + 64 + tx * 4);
  #pragma unroll
  for (int r = 0; r < 4; ++r) {
    int gr = row0 + ty * 4 + r;
    if (gr < n) {
      float4 o0 = make_float4(acc[r][0] + bs0.x, acc[r][1] + bs0.y, acc[r][2] + bs0.z, acc[r][3] + bs0.w);
      float4 o1 = make_float4(acc[r][4] + bs1.x, acc[r][5] + bs1.y, acc[r][6] + bs1.z, acc[r][7] + bs1.w);
      *(float4*)(y + (size_t)gr * D + tx * 4) = o0;
      *(float4*)(y + (size_t)gr * D + 64 + tx * 4) = o1;
      if (ybf) {
        ushort4 p0; p0.x = f2bf(o0.x); p0.y = f2bf(o0.y); p0.z = f2bf(o0.z); p0.w = f2bf(o0.w);
        ushort4 p1; p1.x = f2bf(o1.x); p1.y = f2bf(o1.y); p1.z = f2bf(o1.z); p1.w = f2bf(o1.w);
        *(ushort4*)(ybf + (size_t)gr * D + tx * 4) = p0;
        *(ushort4*)(ybf + (size_t)gr * D + 64 + tx * 4) = p1;
      }
    }
  }
}

// ---------------- cal_ew (all in CSR slot order) ----------------
__global__ void k_deg_len(const unsigned* __restrict__ indptr, int n, float* __restrict__ deg) {
  int j = blockIdx.x * blockDim.x + threadIdx.x;
  if (j < n) deg[j] = (float)(indptr[j + 1] - indptr[j]);
}

__global__ void k_deg_mask(const int* __restrict__ adj_src, const unsigned* __restrict__ indptr_src,
                           const int* __restrict__ orig, int n, float* __restrict__ deg) {
  int j = blockIdx.x * blockDim.x + threadIdx.x;
  if (j >= n) return;
  int o = orig ? orig[j] : j;
  unsigned s0 = indptr_src[o], s1 = indptr_src[o + 1];
  float d = 0.f;
  for (unsigned i = s0; i < s1; ++i) d += (adj_src[i] >= 0) ? 1.f : 0.f;
  deg[j] = d;
}

template<bool MASKED>
__global__ void k_ew_dst(const int* __restrict__ adj, const unsigned* __restrict__ indptr,
                         const int* __restrict__ orig, const float* __restrict__ w,
                         const float* __restrict__ deg, int n,
                         float* __restrict__ ws_slot, float* __restrict__ aggrw,
                         float* __restrict__ ec_slot) {
  int j = blockIdx.x * blockDim.x + threadIdx.x;
  if (j >= n) return;
  int o = orig ? orig[j] : j;
  unsigned s0 = indptr[o], s1 = indptr[o + 1];
  float s = 1e-12f;
  for (unsigned pos = s0; pos < s1; ++pos) {
    int a = adj[pos];
    float ws = 0.f;
    if (!MASKED || a >= 0) {
      float d = deg[a];
      ws = (w ? w[a] : 1.0f) / (d > 0.f ? d : 1.0f);
    }
    ws_slot[pos] = ws;
    s += ws;
  }
  aggrw[j] = s;
  float inv = 1.0f / s;
  for (unsigned pos = s0; pos < s1; ++pos) ec_slot[pos] = ws_slot[pos] * inv;
}

template<bool MASKED>
__global__ void k_ew_src(const int* __restrict__ adj_src, const unsigned* __restrict__ indptr_src,
                         const int* __restrict__ orig, const float* __restrict__ w,
                         const float* __restrict__ deg, const float* __restrict__ aggrw, int n,
                         float* __restrict__ ec_slot) {
  int j = blockIdx.x * blockDim.x + threadIdx.x;
  if (j >= n) return;
  int o = orig ? orig[j] : j;
  unsigned s0 = indptr_src[o], s1 = indptr_src[o + 1];
  float d = deg[j];
  float wn = (w ? w[j] : 1.0f) / (d > 0.f ? d : 1.0f);
  for (unsigned pos = s0; pos < s1; ++pos) {
    int a = adj_src[pos];
    ec_slot[pos] = (!MASKED || a >= 0) ? (wn / aggrw[a]) : 0.f;
  }
}

// ---------------- pooling ----------------
DEV unsigned mono_key(float f) {
  unsigned u = __float_as_uint(f);
  return (u & 0x80000000u) ? ~u : (u | 0x80000000u);
}

// score with fused p-norm (each wave computes ||p|| itself)
__global__ void k_score(const float* __restrict__ x, const float* __restrict__ p,
                        int n, float* __restrict__ score, unsigned* __restrict__ keys) {
  int wid = (blockIdx.x * blockDim.x + threadIdx.x) >> 6;
  int lane = threadIdx.x & 63;
  if (wid >= n) return;
  float p0 = p[lane * 2], p1 = p[lane * 2 + 1];
  const float2 xv = *(const float2*)(x + (size_t)wid * D + lane * 2);
  float partial = xv.x * p0 + xv.y * p1;
  float pn = p0 * p0 + p1 * p1;
  #pragma unroll
  for (int off = 32; off >= 1; off >>= 1) {
    partial += __shfl_xor(partial, off);
    pn += __shfl_xor(pn, off);
  }
  if (lane == 0) {
    float sc = partial * (1.0f / sqrtf(pn));
    score[wid] = sc;
    keys[wid] = mono_key(sc);
  }
}

__global__ void k_sel_init(unsigned* bins, unsigned* state, int k) {
  int t = threadIdx.x;
  if (t < 256) bins[t] = 0u;
  if (t == 0) { state[0] = 0u; state[1] = (unsigned)k; }
}

__global__ void k_hist(const unsigned* __restrict__ keys, int n, const unsigned* __restrict__ state,
                       unsigned* __restrict__ bins, int byte) {
  __shared__ unsigned lb[256];
  for (int i = threadIdx.x; i < 256; i += blockDim.x) lb[i] = 0u;
  __syncthreads();
  unsigned prefix = state[0];
  unsigned mask = (byte == 3) ? 0u : (0xFFFFFFFFu << ((byte + 1) * 8));
  for (int i = blockIdx.x * blockDim.x + threadIdx.x; i < n; i += gridDim.x * blockDim.x) {
    unsigned key = keys[i];
    if ((key & mask) == (prefix & mask))
      atomicAdd(&lb[(key >> (byte * 8)) & 255], 1u);
  }
  __syncthreads();
  for (int i = threadIdx.x; i < 256; i += blockDim.x)
    if (lb[i]) atomicAdd(&bins[i], lb[i]);
}

__global__ void k_pick(unsigned* bins, unsigned* state, int byte) {
  if (threadIdx.x == 0) {
    unsigned r = state[1];
    int b;
    for (b = 255; b > 0; --b) {
      unsigned c = bins[b];
      if (c >= r) break;
      r -= c;
    }
    state[0] |= ((unsigned)b) << (byte * 8);
    state[1] = r;
  }
  __syncthreads();
  for (int i = threadIdx.x; i < 256; i += blockDim.x) bins[i] = 0u;
}

// ---- parallel pack: flags partials -> chunk offsets -> finalize ----
__global__ void k_flags(const unsigned* __restrict__ keys, const unsigned* __restrict__ state,
                        int n, uint2* __restrict__ part) {
  int t = threadIdx.x, lane = t & 63, w = t >> 6;
  int base = blockIdx.x * 1024 + t * 4;
  unsigned T = state[0];
  unsigned cnt = 0;
  #pragma unroll
  for (int j = 0; j < 4; ++j) {
    int i = base + j;
    if (i < n) {
      unsigned key = keys[i];
      cnt += (key > T ? 1u : 0u) + ((key == T ? 1u : 0u) << 16);
    }
  }
  #pragma unroll
  for (int off = 32; off >= 1; off >>= 1) cnt += __shfl_xor(cnt, off);
  __shared__ unsigned ws[4];
  if (lane == 0) ws[w] = cnt;
  __syncthreads();
  if (t == 0) {
    unsigned s = ws[0] + ws[1] + ws[2] + ws[3];
    part[blockIdx.x] = make_uint2(s & 0xffffu, s >> 16);
  }
}

__global__ void k_choff(const uint2* __restrict__ part, int nch, uint2* __restrict__ off) {
  if (threadIdx.x == 0) {
    unsigned g = 0, e = 0;
    for (int c = 0; c < nch; ++c) { off[c] = make_uint2(g, e); g += part[c].x; e += part[c].y; }
  }
}

__global__ void k_pack2(const unsigned* __restrict__ keys, const unsigned* __restrict__ state,
                        const uint2* __restrict__ choff, const float* __restrict__ aggrw,
                        const int* __restrict__ orig, int n,
                        int* __restrict__ perm, int* __restrict__ new_id,
                        float* __restrict__ w_next, int* __restrict__ orig_next) {
  int t = threadIdx.x, lane = t & 63, w = t >> 6;
  int base = blockIdx.x * 1024 + t * 4;
  unsigned T = state[0], r = state[1];
  unsigned f[4];
  unsigned cnt = 0;
  #pragma unroll
  for (int j = 0; j < 4; ++j) {
    int i = base + j;
    unsigned key = (i < n) ? keys[i] : 0u;
    unsigned gt = (i < n && key > T) ? 1u : 0u;
    unsigned eq = (i < n && key == T) ? 1u : 0u;
    f[j] = gt | (eq << 1);
    cnt += gt + (eq << 16);
  }
  unsigned incl = wave_incl_scan(cnt, lane);
  __shared__ unsigned wsum[4], woff[4];
  if (lane == 63) wsum[w] = incl;
  __syncthreads();
  if (t == 0) { unsigned run = 0; for (int j = 0; j < 4; ++j) { woff[j] = run; run += wsum[j]; } }
  __syncthreads();
  unsigned before = woff[w] + incl - cnt;
  uint2 o0 = choff[blockIdx.x];
  unsigned gt_b = o0.x + (before & 0xffffu);
  unsigned eq_b = o0.y + (before >> 16);
  #pragma unroll
  for (int j = 0; j < 4; ++j) {
    int i = base + j;
    if (i >= n) break;
    unsigned gt = f[j] & 1u, eq = (f[j] >> 1) & 1u;
    bool sel = gt || (eq && eq_b < r);
    if (sel) {
      int pos = (int)(gt_b + (eq_b < r ? eq_b : r));
      perm[pos] = i;
      new_id[i] = pos;
      w_next[pos] = aggrw[i];
      orig_next[pos] = orig ? orig[i] : i;
    } else {
      new_id[i] = -1;
    }
    gt_b += gt; eq_b += eq;
  }
}

__global__ void k_gate(const float* __restrict__ xin, const int* __restrict__ perm,
                       const float* __restrict__ score, int k, float* __restrict__ xout,
                       unsigned* __restrict__ outbf) {
  int wid = (blockIdx.x * blockDim.x + threadIdx.x) >> 6;
  int lane = threadIdx.x & 63;
  if (wid >= k) return;
  int j = perm[wid];
  float g = tanhf(score[j]);
  float2 v = *(const float2*)(xin + (size_t)j * D + lane * 2);
  v.x *= g; v.y *= g;
  *(float2*)(xout + (size_t)wid * D + lane * 2) = v;
  if (outbf) {
    unsigned p = (unsigned)f2bf(v.x) | ((unsigned)f2bf(v.y) << 16);
    outbf[(size_t)wid * 64 + lane] = p;
  }
}

__global__ void k_scatter_bf(const float* __restrict__ xin, const int* __restrict__ perm,
                             int k, unsigned* __restrict__ outbf) {
  int wid = (blockIdx.x * blockDim.x + threadIdx.x) >> 6;
  int lane = threadIdx.x & 63;
  if (wid >= k) return;
  int p = perm[wid];
  float2 v = *(const float2*)(xin + (size_t)wid * D + lane * 2);
  unsigned pk = (unsigned)f2bf(v.x) | ((unsigned)f2bf(v.y) << 16);
  outbf[(size_t)p * 64 + lane] = pk;
}

__global__ void k_add(const float* __restrict__ a, const float* __restrict__ b,
                      float* __restrict__ out, int total4) {
  int i = blockIdx.x * blockDim.x + threadIdx.x;
  if (i < total4) {
    float4 av = ((const float4*)a)[i];
    float4 bv = ((const float4*)b)[i];
    ((float4*)out)[i] = make_float4(av.x + bv.x, av.y + bv.y, av.z + bv.z, av.w + bv.w);
  }
}

// =============================================================================
extern "C" void kernel_launch(void* const* d_in, const int* in_sizes, int n_in,
                              void* d_out, int out_size, void* d_ws, size_t ws_size,
                              hipStream_t stream) {
  const float* x_in   = (const float*)d_in[0];
  const int*   ei     = (const int*)d_in[1];
  const int*   src0   = ei;
  const int*   dst0   = ei + E0;
  const float* Wl     = (const float*)d_in[2];
  const float* bl     = (const float*)d_in[3];
  const float* Wr     = (const float*)d_in[4];
  const float* pool_p = (const float*)d_in[5];
  float* out = (float*)d_out;

  const int n0 = N0, k0 = 25000, n1 = 25000, k1 = 12500, n2 = 12500;
  const int NCH0 = (N0 + 1023) / 1024;   // 49

  char* ws = (char*)d_ws;
  size_t off = 0;
  auto alloc = [&](size_t bytes) -> char* {
    char* p = ws + off;
    off += (bytes + 255) & ~(size_t)255;
    return p;
  };
  const size_t NBY = (size_t)N0 * D * 4;
  float* B0    = (float*)alloc(NBY);
  float* B1    = (float*)alloc(NBY);
  float* B2    = (float*)alloc(NBY);
  float* down0 = (float*)alloc(NBY);
  float* down1 = (float*)alloc(NBY / 2);
  unsigned* MA = (unsigned*)alloc((size_t)N0 * D * 2);
  unsigned* MB = (unsigned*)alloc((size_t)N0 * D * 2);
  int* adj0_dst = (int*)alloc(E0 * 4);
  int* adj0_src = (int*)alloc(E0 * 4);
  int* adj1_dst = (int*)alloc(E0 * 4);
  int* adj1_src = (int*)alloc(E0 * 4);
  float* ec0_src = (float*)alloc(E0 * 4);
  float* ec1_src = (float*)alloc(E0 * 4);
  float* ec_dst  = (float*)alloc(E0 * 4);
  float* ws_slot = (float*)alloc(E0 * 4);
  int* adj2_dst  = (int*)ws_slot;          // alias: ws_slot dead before adj2 is built
  unsigned* indptr_dst = (unsigned*)alloc((N0 + 1) * 4);
  unsigned* indptr_src = (unsigned*)alloc((N0 + 1) * 4);
  unsigned* cnt_src = (unsigned*)alloc(N0 * 4);
  unsigned* cnt_dst = (unsigned*)alloc(N0 * 4);
  float* deg   = (float*)alloc(N0 * 4);
  float* aggrw = (float*)alloc(N0 * 4);
  float* w1 = (float*)alloc(n1 * 4);
  float* w2 = (float*)alloc(n2 * 4);
  float* score = (float*)alloc(N0 * 4);
  unsigned* keys = (unsigned*)alloc(N0 * 4);
  int* perm0 = (int*)alloc(k0 * 4);
  int* perm1 = (int*)alloc(k1 * 4);
  int* orig1 = (int*)alloc(k0 * 4);
  int* orig2 = (int*)alloc(k1 * 4);
  int* new_id = (int*)alloc(N0 * 4);
  unsigned* bins  = (unsigned*)alloc(256 * 4);
  unsigned* state = (unsigned*)alloc(8);
  unsigned* spart = (unsigned*)alloc(64 * 4);
  unsigned* soff  = (unsigned*)alloc(64 * 4);
  uint2* ppart = (uint2*)alloc(64 * 8);
  uint2* poff  = (uint2*)alloc(64 * 8);
  float* BT = (float*)alloc((size_t)10 * 256 * 128 * 4);

  const int EG = (E0 + 255) / 256;

  auto scan_np1 = [&](const unsigned* in, unsigned* outp, int n, int nch) {
    k_psum<<<nch, 256, 0, stream>>>(in, n, spart);
    k_scoff<<<1, 64, 0, stream>>>(spart, nch, soff, outp + n);
    k_sapply<<<nch, 256, 0, stream>>>(in, soff, n, outp);
  };

  // ---- CSR build ----
  hipMemsetAsync(cnt_src, 0, N0 * 4, stream);
  hipMemsetAsync(cnt_dst, 0, N0 * 4, stream);
  k_count<<<EG, 256, 0, stream>>>(src0, dst0, cnt_src, cnt_dst);
  scan_np1(cnt_src, indptr_src, N0, NCH0);
  scan_np1(cnt_dst, indptr_dst, N0, NCH0);
  hipMemcpyAsync(cnt_dst, indptr_dst, N0 * 4, hipMemcpyDeviceToDevice, stream);
  k_filla<<<EG, 256, 0, stream>>>(dst0, src0, cnt_dst, adj0_dst);
  hipMemcpyAsync(cnt_src, indptr_src, N0 * 4, hipMemcpyDeviceToDevice, stream);
  k_filla<<<EG, 256, 0, stream>>>(src0, dst0, cnt_src, adj0_src);
  k_wt<<<(10 * 256 * 128 + 255) / 256, 256, 0, stream>>>(Wl, Wr, BT);

  auto gemm = [&](const float* meanb, const float* xin, float* yout, unsigned short* ybf,
                  int n, int cidx) {
    k_conv_gemm<<<(n + 63) / 64, 256, 0, stream>>>(meanb, xin, BT + (size_t)cidx * 256 * 128,
                                                   bl + cidx * 128, yout, ybf, n);
  };

  auto pool_sel = [&](const float* xpool, int n, int kk, int level, const int* orig,
                      int* perm, float* w_next, int* orig_next,
                      float* xout, unsigned* xout_bf) {
    int nch = (n + 1023) / 1024;
    k_score<<<(n + 3) / 4, 256, 0, stream>>>(xpool, pool_p + level * D, n, score, keys);
    k_sel_init<<<1, 256, 0, stream>>>(bins, state, kk);
    for (int byte = 3; byte >= 0; --byte) {
      k_hist<<<256, 256, 0, stream>>>(keys, n, state, bins, byte);
      k_pick<<<1, 256, 0, stream>>>(bins, state, byte);
    }
    k_flags<<<nch, 256, 0, stream>>>(keys, state, n, ppart);
    k_choff<<<1, 64, 0, stream>>>(ppart, nch, poff);
    k_pack2<<<nch, 256, 0, stream>>>(keys, state, poff, aggrw, orig, n, perm, new_id, w_next, orig_next);
    k_gate<<<(kk + 3) / 4, 256, 0, stream>>>(xpool, perm, score, kk, xout, xout_bf);
  };

  // ======== down level 0 (f32, selection-exact) ========
  k_sage<false, false><<<(n0 + 3) / 4, 256, 0, stream>>>(x_in, adj0_dst, indptr_dst, nullptr, n0, B1);
  gemm(B1, x_in, B2, nullptr, n0, 0);
  k_sage<false, false><<<(n0 + 3) / 4, 256, 0, stream>>>(B2, adj0_dst, indptr_dst, nullptr, n0, B1);
  gemm(B1, B2, down0, nullptr, n0, 1);
  k_deg_len<<<(n0 + 255) / 256, 256, 0, stream>>>(indptr_src, n0, deg);
  k_ew_dst<false><<<(n0 + 255) / 256, 256, 0, stream>>>(adj0_dst, indptr_dst, nullptr, nullptr, deg, n0,
                                                        ws_slot, aggrw, ec_dst);
  k_ew_src<false><<<(n0 + 255) / 256, 256, 0, stream>>>(adj0_src, indptr_src, nullptr, nullptr, deg, aggrw,
                                                        n0, ec0_src);
  k_econv2<false, false><<<(n0 + 3) / 4, 256, 0, stream>>>(down0, adj0_dst, ec_dst, indptr_dst, nullptr,
                                                           n0, B1, nullptr);
  pool_sel(B1, n0, k0, 0, nullptr, perm0, w1, orig1, B2, nullptr);
  k_adj_next<<<EG, 256, 0, stream>>>(adj0_dst, new_id, adj1_dst);
  k_adj_next<<<EG, 256, 0, stream>>>(adj0_src, new_id, adj1_src);

  // ======== down level 1 (f32) ========
  k_sage<false, true><<<(n1 + 3) / 4, 256, 0, stream>>>(B2, adj1_dst, indptr_dst, orig1, n1, B1);
  gemm(B1, B2, B0, nullptr, n1, 2);
  k_sage<false, true><<<(n1 + 3) / 4, 256, 0, stream>>>(B0, adj1_dst, indptr_dst, orig1, n1, B1);
  gemm(B1, B0, down1, nullptr, n1, 3);
  k_deg_mask<<<(n1 + 255) / 256, 256, 0, stream>>>(adj1_src, indptr_src, orig1, n1, deg);
  k_ew_dst<true><<<(n1 + 255) / 256, 256, 0, stream>>>(adj1_dst, indptr_dst, orig1, w1, deg, n1,
                                                       ws_slot, aggrw, ec_dst);
  k_ew_src<true><<<(n1 + 255) / 256, 256, 0, stream>>>(adj1_src, indptr_src, orig1, w1, deg, aggrw,
                                                       n1, ec1_src);
  k_econv2<false, true><<<(n1 + 3) / 4, 256, 0, stream>>>(down1, adj1_dst, ec_dst, indptr_dst, orig1,
                                                          n1, B1, nullptr);
  pool_sel(B1, n1, k1, 1, orig1, perm1, w2, orig2, B2, MA);
  k_adj_next<<<EG, 256, 0, stream>>>(adj1_dst, new_id, adj2_dst);   // aliases ws_slot (dead)

  // ======== bottom (bf16 gathers) ========
  k_sage<true, true><<<(n2 + 3) / 4, 256, 0, stream>>>(MA, adj2_dst, indptr_dst, orig2, n2, B1);
  gemm(B1, B2, B0, (unsigned short*)MB, n2, 4);
  k_sage<true, true><<<(n2 + 3) / 4, 256, 0, stream>>>(MB, adj2_dst, indptr_dst, orig2, n2, B1);
  gemm(B1, B0, B2, nullptr, n2, 5);

  // ======== up u=1 (bf16 gathers) ========
  hipMemsetAsync(MA, 0, (size_t)n1 * D * 2, stream);
  k_scatter_bf<<<(n2 + 3) / 4, 256, 0, stream>>>(B2, perm1, n2, MA);
  k_econv2<true, true><<<(n1 + 3) / 4, 256, 0, stream>>>(MA, adj1_src, ec1_src, indptr_src, orig1,
                                                         n1, B1, MB);
  k_sage<true, true><<<(n1 + 3) / 4, 256, 0, stream>>>(MB, adj1_dst, indptr_dst, orig1, n1, B0);
  gemm(B0, B1, B2, (unsigned short*)MA, n1, 6);
  k_sage<true, true><<<(n1 + 3) / 4, 256, 0, stream>>>(MA, adj1_dst, indptr_dst, orig1, n1, B0);
  gemm(B0, B2, B1, nullptr, n1, 7);
  k_add<<<((n1 * D / 4) + 255) / 256, 256, 0, stream>>>(B1, down1, B1, n1 * D / 4);

  // ======== up u=0 (bf16 gathers) ========
  hipMemsetAsync(MA, 0, (size_t)n0 * D * 2, stream);
  k_scatter_bf<<<(n1 + 3) / 4, 256, 0, stream>>>(B1, perm0, n1, MA);
  k_econv2<true, false><<<(n0 + 3) / 4, 256, 0, stream>>>(MA, adj0_src, ec0_src, indptr_src, nullptr,
                                                          n0, B2, MB);
  k_sage<true, false><<<(n0 + 3) / 4, 256, 0, stream>>>(MB, adj0_dst, indptr_dst, nullptr, n0, B1);
  gemm(B1, B2, B0, (unsigned short*)MA, n0, 8);
  k_sage<true, false><<<(n0 + 3) / 4, 256, 0, stream>>>(MA, adj0_dst, indptr_dst, nullptr, n0, B1);
  gemm(B1, B0, B2, nullptr, n0, 9);
  k_add<<<((n0 * D / 4) + 255) / 256, 256, 0, stream>>>(B2, down0, out, n0 * D / 4);
}

// Round 4
// 1220.563 us; speedup vs baseline: 1.9375x; 1.0924x over previous
//
#include <hip/hip_runtime.h>
#include <stdint.h>

#define DEV __device__ __forceinline__

constexpr int N0 = 50000;
constexpr int E0 = 800000;
constexpr int D  = 128;

typedef __attribute__((ext_vector_type(8))) short bf16x8;
typedef __attribute__((ext_vector_type(4))) float f32x4;

DEV float bf2f(unsigned u) { return __uint_as_float(u << 16); }
DEV unsigned short f2bf(float f) {
  unsigned u = __float_as_uint(f);
  unsigned r = u + 0x7fffu + ((u >> 16) & 1u);   // round-to-nearest-even
  return (unsigned short)(r >> 16);
}

DEV unsigned wave_incl_scan(unsigned v, int lane) {
  #pragma unroll
  for (int off = 1; off < 64; off <<= 1) {
    unsigned u = __shfl_up(v, (unsigned)off);
    if (lane >= off) v += u;
  }
  return v;
}

// ---------------- CSR build ----------------
// count AND record per-edge rank (atomicAdd return) so fill needs no atomics
__global__ void k_count(const int* __restrict__ src, const int* __restrict__ dst,
                        unsigned* cnt_src, unsigned* cnt_dst,
                        unsigned* __restrict__ rank_src, unsigned* __restrict__ rank_dst) {
  int e = blockIdx.x * blockDim.x + threadIdx.x;
  if (e < E0) {
    rank_src[e] = atomicAdd(&cnt_src[src[e]], 1u);
    rank_dst[e] = atomicAdd(&cnt_dst[dst[e]], 1u);
  }
}

// ---- 2-level exclusive scan ----
__global__ void k_psum(const unsigned* __restrict__ in, int n, unsigned* __restrict__ part) {
  int t = threadIdx.x, lane = t & 63, w = t >> 6;
  int base = blockIdx.x * 1024 + t * 4;
  unsigned s = 0;
  #pragma unroll
  for (int j = 0; j < 4; ++j) { int i = base + j; if (i < n) s += in[i]; }
  #pragma unroll
  for (int off = 32; off >= 1; off >>= 1) s += __shfl_xor(s, off);
  __shared__ unsigned ws[4];
  if (lane == 0) ws[w] = s;
  __syncthreads();
  if (t == 0) part[blockIdx.x] = ws[0] + ws[1] + ws[2] + ws[3];
}

__global__ void k_scoff(const unsigned* __restrict__ part, int nch,
                        unsigned* __restrict__ off, unsigned* __restrict__ total_out) {
  if (threadIdx.x == 0) {
    unsigned run = 0;
    for (int c = 0; c < nch; ++c) { off[c] = run; run += part[c]; }
    *total_out = run;
  }
}

__global__ void k_sapply(const unsigned* __restrict__ in, const unsigned* __restrict__ choff,
                         int n, unsigned* __restrict__ out) {
  int t = threadIdx.x, lane = t & 63, w = t >> 6;
  int base = blockIdx.x * 1024 + t * 4;
  unsigned v[4]; unsigned s = 0;
  #pragma unroll
  for (int j = 0; j < 4; ++j) { int i = base + j; v[j] = (i < n) ? in[i] : 0u; s += v[j]; }
  unsigned incl = wave_incl_scan(s, lane);
  __shared__ unsigned wsum[4], woff[4];
  if (lane == 63) wsum[w] = incl;
  __syncthreads();
  if (t == 0) { unsigned run = 0; for (int j = 0; j < 4; ++j) { woff[j] = run; run += wsum[j]; } }
  __syncthreads();
  unsigned run = choff[blockIdx.x] + woff[w] + incl - s;
  #pragma unroll
  for (int j = 0; j < 4; ++j) {
    int i = base + j;
    if (i < n) out[i] = run;
    run += v[j];
  }
}

// atomic-free merged fill of both CSR adjacency arrays
__global__ void k_fill2(const int* __restrict__ src, const int* __restrict__ dst,
                        const unsigned* __restrict__ rank_src, const unsigned* __restrict__ rank_dst,
                        const unsigned* __restrict__ indptr_src, const unsigned* __restrict__ indptr_dst,
                        int* __restrict__ adj_src, int* __restrict__ adj_dst) {
  int e = blockIdx.x * blockDim.x + threadIdx.x;
  if (e < E0) {
    int s = src[e], d = dst[e];
    adj_dst[indptr_dst[d] + rank_dst[e]] = s;
    adj_src[indptr_src[s] + rank_src[e]] = d;
  }
}

// compose level mask/relabel (both arrays in one pass)
__global__ void k_adj_next2(const int* __restrict__ adjd, const int* __restrict__ adjs,
                            const int* __restrict__ new_id,
                            int* __restrict__ outd, int* __restrict__ outs) {
  int pos = blockIdx.x * blockDim.x + threadIdx.x;
  if (pos < E0) {
    int a = adjd[pos];
    outd[pos] = (a >= 0) ? new_id[a] : -1;
    int b = adjs[pos];
    outs[pos] = (b >= 0) ? new_id[b] : -1;
  }
}

__global__ void k_adj_next(const int* __restrict__ adj_prev, const int* __restrict__ new_id,
                           int* __restrict__ adj_out) {
  int pos = blockIdx.x * blockDim.x + threadIdx.x;
  if (pos < E0) {
    int a = adj_prev[pos];
    adj_out[pos] = (a >= 0) ? new_id[a] : -1;
  }
}

// ---------------- weight prep ----------------
// f32 BT for convs 0-3: BT[c][k][o], k<128 -> Wl, else Wr
__global__ void k_wt(const float* __restrict__ Wl, const float* __restrict__ Wr, float* __restrict__ BT) {
  int idx = blockIdx.x * blockDim.x + threadIdx.x;
  if (idx < 4 * 256 * 128) {
    int o = idx & 127;
    int k = (idx >> 7) & 255;
    int c = idx >> 15;
    float v = (k < 128) ? Wl[(c * 128 + o) * 128 + k] : Wr[(c * 128 + o) * 128 + (k - 128)];
    BT[idx] = v;
  }
}

// MFMA-fragment-packed split-bf16 weights for convs 4-9:
// element (c,ks,ct,lane,j) = W[k=ks*32+(lane>>4)*8+j][o=ct*16+(lane&15)], conv = c+4
__global__ void k_wt_pk(const float* __restrict__ Wl, const float* __restrict__ Wr,
                        unsigned short* __restrict__ Bhi, unsigned short* __restrict__ Blo) {
  int idx = blockIdx.x * blockDim.x + threadIdx.x;
  if (idx >= 6 * 8 * 8 * 64) return;
  int l  = idx & 63;
  int ct = (idx >> 6) & 7;
  int ks = (idx >> 9) & 7;
  int c  = idx >> 12;          // 0..5 -> conv c+4
  int k0 = ks * 32 + (l >> 4) * 8;
  int o  = ct * 16 + (l & 15);
  int conv = c + 4;
  const float* Wrow = (k0 < 128) ? (Wl + ((size_t)conv * 128 + o) * 128 + k0)
                                 : (Wr + ((size_t)conv * 128 + o) * 128 + (k0 - 128));
  size_t base = (size_t)idx * 8;
  #pragma unroll
  for (int j = 0; j < 8; ++j) {
    float wv = Wrow[j];
    unsigned short h = f2bf(wv);
    Bhi[base + j] = h;
    Blo[base + j] = f2bf(wv - bf2f(h));
  }
}

// ---------------- SAGE mean aggregation ----------------
template<bool BF, bool MASKED>
__global__ void k_sage(const void* __restrict__ xv, const int* __restrict__ adj,
                       const unsigned* __restrict__ indptr, const int* __restrict__ orig,
                       int n, float* __restrict__ mean) {
  int wid = (blockIdx.x * blockDim.x + threadIdx.x) >> 6;
  int lane = threadIdx.x & 63;
  if (wid >= n) return;
  int o = orig ? orig[wid] : wid;
  unsigned s0 = indptr[o], s1 = indptr[o + 1];
  const float* xf = (const float*)xv;
  const unsigned* xb = (const unsigned*)xv;
  float a0 = 0.f, a1 = 0.f, cnt = 0.f;
  unsigned idx = s0;
  for (; idx + 4 <= s1; idx += 4) {
    int ad[4];
    #pragma unroll
    for (int j = 0; j < 4; ++j) ad[j] = adj[idx + j];
    #pragma unroll
    for (int j = 0; j < 4; ++j) {
      if (!MASKED || ad[j] >= 0) {
        float x0, x1;
        if (BF) { unsigned u = xb[(size_t)ad[j] * 64 + lane]; x0 = bf2f(u & 0xffffu); x1 = bf2f(u >> 16); }
        else    { float2 v = *(const float2*)(xf + (size_t)ad[j] * D + lane * 2); x0 = v.x; x1 = v.y; }
        a0 += x0; a1 += x1; cnt += 1.f;
      }
    }
  }
  for (; idx < s1; ++idx) {
    int a = adj[idx];
    if (!MASKED || a >= 0) {
      float x0, x1;
      if (BF) { unsigned u = xb[(size_t)a * 64 + lane]; x0 = bf2f(u & 0xffffu); x1 = bf2f(u >> 16); }
      else    { float2 v = *(const float2*)(xf + (size_t)a * D + lane * 2); x0 = v.x; x1 = v.y; }
      a0 += x0; a1 += x1; cnt += 1.f;
    }
  }
  if (!MASKED) cnt = (float)(s1 - s0);
  float inv = 1.0f / fmaxf(cnt, 1.0f);
  *(float2*)(mean + (size_t)wid * D + lane * 2) = make_float2(a0 * inv, a1 * inv);
}

// ---------------- weighted edge conv ----------------
template<bool BF, bool MASKED>
__global__ void k_econv2(const void* __restrict__ xv, const int* __restrict__ adj,
                         const float* __restrict__ ecs, const unsigned* __restrict__ indptr,
                         const int* __restrict__ orig, int n,
                         float* __restrict__ out, unsigned* __restrict__ outbf) {
  int wid = (blockIdx.x * blockDim.x + threadIdx.x) >> 6;
  int lane = threadIdx.x & 63;
  if (wid >= n) return;
  int o = orig ? orig[wid] : wid;
  unsigned s0 = indptr[o], s1 = indptr[o + 1];
  const float* xf = (const float*)xv;
  const unsigned* xb = (const unsigned*)xv;
  float a0 = 0.f, a1 = 0.f;
  unsigned idx = s0;
  for (; idx + 4 <= s1; idx += 4) {
    int ad[4]; float wv[4];
    #pragma unroll
    for (int j = 0; j < 4; ++j) { ad[j] = adj[idx + j]; wv[j] = ecs[idx + j]; }
    #pragma unroll
    for (int j = 0; j < 4; ++j) {
      if (!MASKED || ad[j] >= 0) {
        float x0, x1;
        if (BF) { unsigned u = xb[(size_t)ad[j] * 64 + lane]; x0 = bf2f(u & 0xffffu); x1 = bf2f(u >> 16); }
        else    { float2 v = *(const float2*)(xf + (size_t)ad[j] * D + lane * 2); x0 = v.x; x1 = v.y; }
        a0 = fmaf(wv[j], x0, a0); a1 = fmaf(wv[j], x1, a1);
      }
    }
  }
  for (; idx < s1; ++idx) {
    int a = adj[idx]; float wgt = ecs[idx];
    if (!MASKED || a >= 0) {
      float x0, x1;
      if (BF) { unsigned u = xb[(size_t)a * 64 + lane]; x0 = bf2f(u & 0xffffu); x1 = bf2f(u >> 16); }
      else    { float2 v = *(const float2*)(xf + (size_t)a * D + lane * 2); x0 = v.x; x1 = v.y; }
      a0 = fmaf(wgt, x0, a0); a1 = fmaf(wgt, x1, a1);
    }
  }
  *(float2*)(out + (size_t)wid * D + lane * 2) = make_float2(a0, a1);
  if (outbf) {
    unsigned p = (unsigned)f2bf(a0) | ((unsigned)f2bf(a1) << 16);
    outbf[(size_t)wid * 64 + lane] = p;
  }
}

// ---------------- f32 conv GEMM (convs 0-3, selection-exact) ----------------
__launch_bounds__(256)
__global__ void k_conv_gemm(const float* __restrict__ mean, const float* __restrict__ xin,
                            const float* __restrict__ BT, const float* __restrict__ bias,
                            float* __restrict__ y, unsigned short* __restrict__ ybf, int n) {
  __shared__ float As[64][17];
  __shared__ float Bs[16][128];
  int tid = threadIdx.x;
  int tx = tid & 15, ty = tid >> 4;
  int row0 = blockIdx.x * 64;
  float acc[4][8];
  #pragma unroll
  for (int r = 0; r < 4; ++r)
    #pragma unroll
    for (int c = 0; c < 8; ++c) acc[r][c] = 0.f;

  int lm = tid >> 2;
  int lk = (tid & 3) * 4;
  int bk = tid >> 4;
  int bo = (tid & 15) * 8;

  for (int kc = 0; kc < 16; ++kc) {
    int k0 = kc * 16;
    const float* A = (k0 < 128) ? mean : xin;
    int kk = k0 & 127;
    int gr = row0 + lm;
    float4 av = make_float4(0.f, 0.f, 0.f, 0.f);
    if (gr < n) av = *(const float4*)(A + (size_t)gr * D + kk + lk);
    As[lm][lk + 0] = av.x; As[lm][lk + 1] = av.y; As[lm][lk + 2] = av.z; As[lm][lk + 3] = av.w;
    float4 bv0 = *(const float4*)(BT + (size_t)(k0 + bk) * 128 + bo);
    float4 bv1 = *(const float4*)(BT + (size_t)(k0 + bk) * 128 + bo + 4);
    *(float4*)&Bs[bk][bo] = bv0;
    *(float4*)&Bs[bk][bo + 4] = bv1;
    __syncthreads();
    #pragma unroll
    for (int k = 0; k < 16; ++k) {
      float a[4];
      #pragma unroll
      for (int r = 0; r < 4; ++r) a[r] = As[ty * 4 + r][k];
      float4 b0 = *(const float4*)&Bs[k][tx * 4];
      float4 b1 = *(const float4*)&Bs[k][64 + tx * 4];
      float bb[8] = {b0.x, b0.y, b0.z, b0.w, b1.x, b1.y, b1.z, b1.w};
      #pragma unroll
      for (int r = 0; r < 4; ++r)
        #pragma unroll
        for (int c = 0; c < 8; ++c)
          acc[r][c] = fmaf(a[r], bb[c], acc[r][c]);
    }
    __syncthreads();
  }
  float4 bs0 = *(const float4*)(bias + tx * 4);
  float4 bs1 = *(const float4*)(bias + 64 + tx * 4);
  #pragma unroll
  for (int r = 0; r < 4; ++r) {
    int gr = row0 + ty * 4 + r;
    if (gr < n) {
      float4 o0 = make_float4(acc[r][0] + bs0.x, acc[r][1] + bs0.y, acc[r][2] + bs0.z, acc[r][3] + bs0.w);
      float4 o1 = make_float4(acc[r][4] + bs1.x, acc[r][5] + bs1.y, acc[r][6] + bs1.z, acc[r][7] + bs1.w);
      *(float4*)(y + (size_t)gr * D + tx * 4) = o0;
      *(float4*)(y + (size_t)gr * D + 64 + tx * 4) = o1;
      if (ybf) {
        ushort4 p0; p0.x = f2bf(o0.x); p0.y = f2bf(o0.y); p0.z = f2bf(o0.z); p0.w = f2bf(o0.w);
        ushort4 p1; p1.x = f2bf(o1.x); p1.y = f2bf(o1.y); p1.z = f2bf(o1.z); p1.w = f2bf(o1.w);
        *(ushort4*)(ybf + (size_t)gr * D + tx * 4) = p0;
        *(ushort4*)(ybf + (size_t)gr * D + 64 + tx * 4) = p1;
      }
    }
  }
}

// ---------------- split-bf16 MFMA GEMM (convs 4-9, post-selection) ----------------
// y = [mean|xin] @ W^T + bias (+skip). A decomposed hi+lo bf16; 3 MFMA terms.
// LDS-free: A global->reg per 16-row wave tile; B pre-packed fragment-order.
__launch_bounds__(256)
__global__ void k_gemm_mfma(const float* __restrict__ mean, const float* __restrict__ xin,
                            const unsigned short* __restrict__ Bhi, const unsigned short* __restrict__ Blo,
                            const float* __restrict__ bias, const float* __restrict__ skip,
                            float* __restrict__ y, unsigned short* __restrict__ ybf, int n) {
  int tid = threadIdx.x;
  int lane = tid & 63, w = tid >> 6;
  int row0 = blockIdx.x * 64 + w * 16;
  int arow = row0 + (lane & 15);
  int kgrp = lane >> 4;                 // 0..3
  bool rowok = arow < n;
  f32x4 acc[8];
  #pragma unroll
  for (int ct = 0; ct < 8; ++ct) acc[ct] = f32x4{0.f, 0.f, 0.f, 0.f};

  #pragma unroll
  for (int ks = 0; ks < 8; ++ks) {
    const float* A = (ks < 4) ? mean : xin;
    int kk = (ks & 3) * 32 + kgrp * 8;
    float av[8];
    if (rowok) {
      float4 a0 = *(const float4*)(A + (size_t)arow * D + kk);
      float4 a1 = *(const float4*)(A + (size_t)arow * D + kk + 4);
      av[0] = a0.x; av[1] = a0.y; av[2] = a0.z; av[3] = a0.w;
      av[4] = a1.x; av[5] = a1.y; av[6] = a1.z; av[7] = a1.w;
    } else {
      #pragma unroll
      for (int j = 0; j < 8; ++j) av[j] = 0.f;
    }
    bf16x8 ahi, alo;
    #pragma unroll
    for (int j = 0; j < 8; ++j) {
      unsigned short h = f2bf(av[j]);
      ahi[j] = (short)h;
      alo[j] = (short)f2bf(av[j] - bf2f(h));
    }
    #pragma unroll
    for (int ct = 0; ct < 8; ++ct) {
      size_t boff = (((size_t)ks * 8 + ct) * 64 + lane) * 8;
      bf16x8 bh = *(const bf16x8*)(Bhi + boff);
      bf16x8 bl = *(const bf16x8*)(Blo + boff);
      acc[ct] = __builtin_amdgcn_mfma_f32_16x16x32_bf16(ahi, bh, acc[ct], 0, 0, 0);
      acc[ct] = __builtin_amdgcn_mfma_f32_16x16x32_bf16(alo, bh, acc[ct], 0, 0, 0);
      acc[ct] = __builtin_amdgcn_mfma_f32_16x16x32_bf16(ahi, bl, acc[ct], 0, 0, 0);
    }
  }
  int ccol = lane & 15;
  #pragma unroll
  for (int ct = 0; ct < 8; ++ct) {
    int col = ct * 16 + ccol;
    float bb = bias[col];
    #pragma unroll
    for (int r = 0; r < 4; ++r) {
      int row = row0 + kgrp * 4 + r;
      if (row < n) {
        float v = acc[ct][r] + bb;
        if (skip) v += skip[(size_t)row * D + col];
        y[(size_t)row * D + col] = v;
        if (ybf) ybf[(size_t)row * D + col] = f2bf(v);
      }
    }
  }
}

// ---------------- cal_ew ----------------
__global__ void k_deg_len(const unsigned* __restrict__ indptr, int n, float* __restrict__ deg) {
  int j = blockIdx.x * blockDim.x + threadIdx.x;
  if (j < n) deg[j] = (float)(indptr[j + 1] - indptr[j]);
}

__global__ void k_deg_mask(const int* __restrict__ adj_src, const unsigned* __restrict__ indptr_src,
                           const int* __restrict__ orig, int n, float* __restrict__ deg) {
  int j = blockIdx.x * blockDim.x + threadIdx.x;
  if (j >= n) return;
  int o = orig ? orig[j] : j;
  unsigned s0 = indptr_src[o], s1 = indptr_src[o + 1];
  float d = 0.f;
  for (unsigned i = s0; i < s1; ++i) d += (adj_src[i] >= 0) ? 1.f : 0.f;
  deg[j] = d;
}

template<bool MASKED>
__global__ void k_ew_dst(const int* __restrict__ adj, const unsigned* __restrict__ indptr,
                         const int* __restrict__ orig, const float* __restrict__ w,
                         const float* __restrict__ deg, int n,
                         float* __restrict__ ws_slot, float* __restrict__ aggrw,
                         float* __restrict__ ec_slot) {
  int j = blockIdx.x * blockDim.x + threadIdx.x;
  if (j >= n) return;
  int o = orig ? orig[j] : j;
  unsigned s0 = indptr[o], s1 = indptr[o + 1];
  float s = 1e-12f;
  for (unsigned pos = s0; pos < s1; ++pos) {
    int a = adj[pos];
    float ws = 0.f;
    if (!MASKED || a >= 0) {
      float d = deg[a];
      ws = (w ? w[a] : 1.0f) / (d > 0.f ? d : 1.0f);
    }
    ws_slot[pos] = ws;
    s += ws;
  }
  aggrw[j] = s;
  float inv = 1.0f / s;
  for (unsigned pos = s0; pos < s1; ++pos) ec_slot[pos] = ws_slot[pos] * inv;
}

template<bool MASKED>
__global__ void k_ew_src(const int* __restrict__ adj_src, const unsigned* __restrict__ indptr_src,
                         const int* __restrict__ orig, const float* __restrict__ w,
                         const float* __restrict__ deg, const float* __restrict__ aggrw, int n,
                         float* __restrict__ ec_slot) {
  int j = blockIdx.x * blockDim.x + threadIdx.x;
  if (j >= n) return;
  int o = orig ? orig[j] : j;
  unsigned s0 = indptr_src[o], s1 = indptr_src[o + 1];
  float d = deg[j];
  float wn = (w ? w[j] : 1.0f) / (d > 0.f ? d : 1.0f);
  for (unsigned pos = s0; pos < s1; ++pos) {
    int a = adj_src[pos];
    ec_slot[pos] = (!MASKED || a >= 0) ? (wn / aggrw[a]) : 0.f;
  }
}

// ---------------- pooling ----------------
DEV unsigned mono_key(float f) {
  unsigned u = __float_as_uint(f);
  return (u & 0x80000000u) ? ~u : (u | 0x80000000u);
}

__global__ void k_score(const float* __restrict__ x, const float* __restrict__ p,
                        int n, float* __restrict__ score, unsigned* __restrict__ keys) {
  int wid = (blockIdx.x * blockDim.x + threadIdx.x) >> 6;
  int lane = threadIdx.x & 63;
  if (wid >= n) return;
  float p0 = p[lane * 2], p1 = p[lane * 2 + 1];
  const float2 xv = *(const float2*)(x + (size_t)wid * D + lane * 2);
  float partial = xv.x * p0 + xv.y * p1;
  float pn = p0 * p0 + p1 * p1;
  #pragma unroll
  for (int off = 32; off >= 1; off >>= 1) {
    partial += __shfl_xor(partial, off);
    pn += __shfl_xor(pn, off);
  }
  if (lane == 0) {
    float sc = partial * (1.0f / sqrtf(pn));
    score[wid] = sc;
    keys[wid] = mono_key(sc);
  }
}

// single-block fused 4-pass radix select -> state = {threshold key, residual rank}
__launch_bounds__(1024)
__global__ void k_select(const unsigned* __restrict__ keys, int n, int k,
                         unsigned* __restrict__ state) {
  __shared__ unsigned bins[256];
  __shared__ unsigned sh_prefix, sh_r;
  int t = threadIdx.x;
  if (t == 0) { sh_prefix = 0u; sh_r = (unsigned)k; }
  for (int byte = 3; byte >= 0; --byte) {
    if (t < 256) bins[t] = 0u;
    __syncthreads();
    unsigned prefix = sh_prefix;
    unsigned mask = (byte == 3) ? 0u : (0xFFFFFFFFu << ((byte + 1) * 8));
    for (int i = t; i < n; i += 1024) {
      unsigned key = keys[i];
      if ((key & mask) == (prefix & mask))
        atomicAdd(&bins[(key >> (byte * 8)) & 255], 1u);
    }
    __syncthreads();
    if (t == 0) {
      unsigned r = sh_r; int b;
      for (b = 255; b > 0; --b) {
        unsigned c = bins[b];
        if (c >= r) break;
        r -= c;
      }
      sh_prefix = prefix | (((unsigned)b) << (byte * 8));
      sh_r = r;
    }
    __syncthreads();
  }
  if (t == 0) { state[0] = sh_prefix; state[1] = sh_r; }
}

// ---- parallel pack ----
__global__ void k_flags(const unsigned* __restrict__ keys, const unsigned* __restrict__ state,
                        int n, uint2* __restrict__ part) {
  int t = threadIdx.x, lane = t & 63, w = t >> 6;
  int base = blockIdx.x * 1024 + t * 4;
  unsigned T = state[0];
  unsigned cnt = 0;
  #pragma unroll
  for (int j = 0; j < 4; ++j) {
    int i = base + j;
    if (i < n) {
      unsigned key = keys[i];
      cnt += (key > T ? 1u : 0u) + ((key == T ? 1u : 0u) << 16);
    }
  }
  #pragma unroll
  for (int off = 32; off >= 1; off >>= 1) cnt += __shfl_xor(cnt, off);
  __shared__ unsigned ws[4];
  if (lane == 0) ws[w] = cnt;
  __syncthreads();
  if (t == 0) {
    unsigned s = ws[0] + ws[1] + ws[2] + ws[3];
    part[blockIdx.x] = make_uint2(s & 0xffffu, s >> 16);
  }
}

__global__ void k_choff(const uint2* __restrict__ part, int nch, uint2* __restrict__ off) {
  if (threadIdx.x == 0) {
    unsigned g = 0, e = 0;
    for (int c = 0; c < nch; ++c) { off[c] = make_uint2(g, e); g += part[c].x; e += part[c].y; }
  }
}

__global__ void k_pack2(const unsigned* __restrict__ keys, const unsigned* __restrict__ state,
                        const uint2* __restrict__ choff, const float* __restrict__ aggrw,
                        const int* __restrict__ orig, int n,
                        int* __restrict__ perm, int* __restrict__ new_id,
                        float* __restrict__ w_next, int* __restrict__ orig_next) {
  int t = threadIdx.x, lane = t & 63, w = t >> 6;
  int base = blockIdx.x * 1024 + t * 4;
  unsigned T = state[0], r = state[1];
  unsigned f[4];
  unsigned cnt = 0;
  #pragma unroll
  for (int j = 0; j < 4; ++j) {
    int i = base + j;
    unsigned key = (i < n) ? keys[i] : 0u;
    unsigned gt = (i < n && key > T) ? 1u : 0u;
    unsigned eq = (i < n && key == T) ? 1u : 0u;
    f[j] = gt | (eq << 1);
    cnt += gt + (eq << 16);
  }
  unsigned incl = wave_incl_scan(cnt, lane);
  __shared__ unsigned wsum[4], woff[4];
  if (lane == 63) wsum[w] = incl;
  __syncthreads();
  if (t == 0) { unsigned run = 0; for (int j = 0; j < 4; ++j) { woff[j] = run; run += wsum[j]; } }
  __syncthreads();
  unsigned before = woff[w] + incl - cnt;
  uint2 o0 = choff[blockIdx.x];
  unsigned gt_b = o0.x + (before & 0xffffu);
  unsigned eq_b = o0.y + (before >> 16);
  #pragma unroll
  for (int j = 0; j < 4; ++j) {
    int i = base + j;
    if (i >= n) break;
    unsigned gt = f[j] & 1u, eq = (f[j] >> 1) & 1u;
    bool sel = gt || (eq && eq_b < r);
    if (sel) {
      int pos = (int)(gt_b + (eq_b < r ? eq_b : r));
      perm[pos] = i;
      new_id[i] = pos;
      w_next[pos] = aggrw[i];
      orig_next[pos] = orig ? orig[i] : i;
    } else {
      new_id[i] = -1;
    }
    gt_b += gt; eq_b += eq;
  }
}

__global__ void k_gate(const float* __restrict__ xin, const int* __restrict__ perm,
                       const float* __restrict__ score, int k, float* __restrict__ xout,
                       unsigned* __restrict__ outbf) {
  int wid = (blockIdx.x * blockDim.x + threadIdx.x) >> 6;
  int lane = threadIdx.x & 63;
  if (wid >= k) return;
  int j = perm[wid];
  float g = tanhf(score[j]);
  float2 v = *(const float2*)(xin + (size_t)j * D + lane * 2);
  v.x *= g; v.y *= g;
  *(float2*)(xout + (size_t)wid * D + lane * 2) = v;
  if (outbf) {
    unsigned p = (unsigned)f2bf(v.x) | ((unsigned)f2bf(v.y) << 16);
    outbf[(size_t)wid * 64 + lane] = p;
  }
}

__global__ void k_scatter_bf(const float* __restrict__ xin, const int* __restrict__ perm,
                             int k, unsigned* __restrict__ outbf) {
  int wid = (blockIdx.x * blockDim.x + threadIdx.x) >> 6;
  int lane = threadIdx.x & 63;
  if (wid >= k) return;
  int p = perm[wid];
  float2 v = *(const float2*)(xin + (size_t)wid * D + lane * 2);
  unsigned pk = (unsigned)f2bf(v.x) | ((unsigned)f2bf(v.y) << 16);
  outbf[(size_t)p * 64 + lane] = pk;
}

// =============================================================================
extern "C" void kernel_launch(void* const* d_in, const int* in_sizes, int n_in,
                              void* d_out, int out_size, void* d_ws, size_t ws_size,
                              hipStream_t stream) {
  const float* x_in   = (const float*)d_in[0];
  const int*   ei     = (const int*)d_in[1];
  const int*   src0   = ei;
  const int*   dst0   = ei + E0;
  const float* Wl     = (const float*)d_in[2];
  const float* bl     = (const float*)d_in[3];
  const float* Wr     = (const float*)d_in[4];
  const float* pool_p = (const float*)d_in[5];
  float* out = (float*)d_out;

  const int n0 = N0, k0 = 25000, n1 = 25000, k1 = 12500, n2 = 12500;
  const int NCH0 = (N0 + 1023) / 1024;   // 49

  char* ws = (char*)d_ws;
  size_t off = 0;
  auto alloc = [&](size_t bytes) -> char* {
    char* p = ws + off;
    off += (bytes + 255) & ~(size_t)255;
    return p;
  };
  const size_t NBY = (size_t)N0 * D * 4;
  float* B0    = (float*)alloc(NBY);
  float* B1    = (float*)alloc(NBY);
  float* B2    = (float*)alloc(NBY);
  float* down0 = (float*)alloc(NBY);
  float* down1 = (float*)alloc(NBY / 2);
  unsigned* MA = (unsigned*)alloc((size_t)N0 * D * 2);
  unsigned* MB = (unsigned*)alloc((size_t)N0 * D * 2);
  int* adj0_dst = (int*)alloc(E0 * 4);
  int* adj0_src = (int*)alloc(E0 * 4);
  int* adj1_dst = (int*)alloc(E0 * 4);
  int* adj1_src = (int*)alloc(E0 * 4);
  float* ec0_src = (float*)alloc(E0 * 4);
  float* ec1_src = (float*)alloc(E0 * 4);
  float* ec_dst  = (float*)alloc(E0 * 4);
  float* ws_slot = (float*)alloc(E0 * 4);
  int* adj2_dst  = (int*)ws_slot;          // alias: ws_slot dead before adj2 is built
  unsigned* rank_src = (unsigned*)alloc(E0 * 4);
  unsigned* rank_dst = (unsigned*)alloc(E0 * 4);
  unsigned* indptr_dst = (unsigned*)alloc((N0 + 1) * 4);
  unsigned* indptr_src = (unsigned*)alloc((N0 + 1) * 4);
  unsigned* cnt_src = (unsigned*)alloc(N0 * 4);
  unsigned* cnt_dst = (unsigned*)alloc(N0 * 4);
  float* deg   = (float*)alloc(N0 * 4);
  float* aggrw = (float*)alloc(N0 * 4);
  float* w1 = (float*)alloc(n1 * 4);
  float* w2 = (float*)alloc(n2 * 4);
  float* score = (float*)alloc(N0 * 4);
  unsigned* keys = (unsigned*)alloc(N0 * 4);
  int* perm0 = (int*)alloc(k0 * 4);
  int* perm1 = (int*)alloc(k1 * 4);
  int* orig1 = (int*)alloc(k0 * 4);
  int* orig2 = (int*)alloc(k1 * 4);
  int* new_id = (int*)alloc(N0 * 4);
  unsigned* state = (unsigned*)alloc(8);
  unsigned* spart = (unsigned*)alloc(64 * 4);
  unsigned* soff  = (unsigned*)alloc(64 * 4);
  uint2* ppart = (uint2*)alloc(64 * 8);
  uint2* poff  = (uint2*)alloc(64 * 8);
  float* BT = (float*)alloc((size_t)4 * 256 * 128 * 4);
  unsigned short* Bhi = (unsigned short*)alloc((size_t)6 * 8 * 8 * 64 * 8 * 2);
  unsigned short* Blo = (unsigned short*)alloc((size_t)6 * 8 * 8 * 64 * 8 * 2);

  const int EG = (E0 + 255) / 256;

  auto scan_np1 = [&](const unsigned* in, unsigned* outp, int n, int nch) {
    k_psum<<<nch, 256, 0, stream>>>(in, n, spart);
    k_scoff<<<1, 64, 0, stream>>>(spart, nch, soff, outp + n);
    k_sapply<<<nch, 256, 0, stream>>>(in, soff, n, outp);
  };

  // ---- CSR build (rank-from-count, atomic-free fill) ----
  hipMemsetAsync(cnt_src, 0, N0 * 4, stream);
  hipMemsetAsync(cnt_dst, 0, N0 * 4, stream);
  k_count<<<EG, 256, 0, stream>>>(src0, dst0, cnt_src, cnt_dst, rank_src, rank_dst);
  scan_np1(cnt_src, indptr_src, N0, NCH0);
  scan_np1(cnt_dst, indptr_dst, N0, NCH0);
  k_fill2<<<EG, 256, 0, stream>>>(src0, dst0, rank_src, rank_dst, indptr_src, indptr_dst,
                                  adj0_src, adj0_dst);
  k_wt<<<(4 * 256 * 128 + 255) / 256, 256, 0, stream>>>(Wl, Wr, BT);
  k_wt_pk<<<(6 * 8 * 8 * 64 + 255) / 256, 256, 0, stream>>>(Wl, Wr, Bhi, Blo);

  auto gemm = [&](const float* meanb, const float* xin, float* yout, unsigned short* ybf,
                  int n, int cidx) {
    k_conv_gemm<<<(n + 63) / 64, 256, 0, stream>>>(meanb, xin, BT + (size_t)cidx * 256 * 128,
                                                   bl + cidx * 128, yout, ybf, n);
  };
  auto gemm_mx = [&](const float* meanb, const float* xin, float* yout, unsigned short* ybf,
                     const float* skip, int n, int cidx) {
    size_t o = (size_t)(cidx - 4) * 8 * 8 * 64 * 8;
    k_gemm_mfma<<<(n + 63) / 64, 256, 0, stream>>>(meanb, xin, Bhi + o, Blo + o,
                                                   bl + cidx * 128, skip, yout, ybf, n);
  };

  auto pool_sel = [&](const float* xpool, int n, int kk, int level, const int* orig,
                      int* perm, float* w_next, int* orig_next,
                      float* xout, unsigned* xout_bf) {
    int nch = (n + 1023) / 1024;
    k_score<<<(n + 3) / 4, 256, 0, stream>>>(xpool, pool_p + level * D, n, score, keys);
    k_select<<<1, 1024, 0, stream>>>(keys, n, kk, state);
    k_flags<<<nch, 256, 0, stream>>>(keys, state, n, ppart);
    k_choff<<<1, 64, 0, stream>>>(ppart, nch, poff);
    k_pack2<<<nch, 256, 0, stream>>>(keys, state, poff, aggrw, orig, n, perm, new_id, w_next, orig_next);
    k_gate<<<(kk + 3) / 4, 256, 0, stream>>>(xpool, perm, score, kk, xout, xout_bf);
  };

  // ======== down level 0 (f32, selection-exact) ========
  k_sage<false, false><<<(n0 + 3) / 4, 256, 0, stream>>>(x_in, adj0_dst, indptr_dst, nullptr, n0, B1);
  gemm(B1, x_in, B2, nullptr, n0, 0);
  k_sage<false, false><<<(n0 + 3) / 4, 256, 0, stream>>>(B2, adj0_dst, indptr_dst, nullptr, n0, B1);
  gemm(B1, B2, down0, nullptr, n0, 1);
  k_deg_len<<<(n0 + 255) / 256, 256, 0, stream>>>(indptr_src, n0, deg);
  k_ew_dst<false><<<(n0 + 255) / 256, 256, 0, stream>>>(adj0_dst, indptr_dst, nullptr, nullptr, deg, n0,
                                                        ws_slot, aggrw, ec_dst);
  k_ew_src<false><<<(n0 + 255) / 256, 256, 0, stream>>>(adj0_src, indptr_src, nullptr, nullptr, deg, aggrw,
                                                        n0, ec0_src);
  k_econv2<false, false><<<(n0 + 3) / 4, 256, 0, stream>>>(down0, adj0_dst, ec_dst, indptr_dst, nullptr,
                                                           n0, B1, nullptr);
  pool_sel(B1, n0, k0, 0, nullptr, perm0, w1, orig1, B2, nullptr);
  k_adj_next2<<<EG, 256, 0, stream>>>(adj0_dst, adj0_src, new_id, adj1_dst, adj1_src);

  // ======== down level 1 (f32) ========
  k_sage<false, true><<<(n1 + 3) / 4, 256, 0, stream>>>(B2, adj1_dst, indptr_dst, orig1, n1, B1);
  gemm(B1, B2, B0, nullptr, n1, 2);
  k_sage<false, true><<<(n1 + 3) / 4, 256, 0, stream>>>(B0, adj1_dst, indptr_dst, orig1, n1, B1);
  gemm(B1, B0, down1, nullptr, n1, 3);
  k_deg_mask<<<(n1 + 255) / 256, 256, 0, stream>>>(adj1_src, indptr_src, orig1, n1, deg);
  k_ew_dst<true><<<(n1 + 255) / 256, 256, 0, stream>>>(adj1_dst, indptr_dst, orig1, w1, deg, n1,
                                                       ws_slot, aggrw, ec_dst);
  k_ew_src<true><<<(n1 + 255) / 256, 256, 0, stream>>>(adj1_src, indptr_src, orig1, w1, deg, aggrw,
                                                       n1, ec1_src);
  k_econv2<false, true><<<(n1 + 3) / 4, 256, 0, stream>>>(down1, adj1_dst, ec_dst, indptr_dst, orig1,
                                                          n1, B1, nullptr);
  pool_sel(B1, n1, k1, 1, orig1, perm1, w2, orig2, B2, MA);
  k_adj_next<<<EG, 256, 0, stream>>>(adj1_dst, new_id, adj2_dst);   // aliases ws_slot (dead)

  // ======== bottom (bf16 gathers, MFMA convs) ========
  k_sage<true, true><<<(n2 + 3) / 4, 256, 0, stream>>>(MA, adj2_dst, indptr_dst, orig2, n2, B1);
  gemm_mx(B1, B2, B0, (unsigned short*)MB, nullptr, n2, 4);
  k_sage<true, true><<<(n2 + 3) / 4, 256, 0, stream>>>(MB, adj2_dst, indptr_dst, orig2, n2, B1);
  gemm_mx(B1, B0, B2, nullptr, nullptr, n2, 5);

  // ======== up u=1 (bf16 gathers, MFMA convs; skip fused into conv 7) ========
  hipMemsetAsync(MA, 0, (size_t)n1 * D * 2, stream);
  k_scatter_bf<<<(n2 + 3) / 4, 256, 0, stream>>>(B2, perm1, n2, MA);
  k_econv2<true, true><<<(n1 + 3) / 4, 256, 0, stream>>>(MA, adj1_src, ec1_src, indptr_src, orig1,
                                                         n1, B1, MB);
  k_sage<true, true><<<(n1 + 3) / 4, 256, 0, stream>>>(MB, adj1_dst, indptr_dst, orig1, n1, B0);
  gemm_mx(B0, B1, B2, (unsigned short*)MA, nullptr, n1, 6);
  k_sage<true, true><<<(n1 + 3) / 4, 256, 0, stream>>>(MA, adj1_dst, indptr_dst, orig1, n1, B0);
  gemm_mx(B0, B2, B1, nullptr, down1, n1, 7);

  // ======== up u=0 (bf16 gathers, MFMA convs; skip fused into conv 9) ========
  hipMemsetAsync(MA, 0, (size_t)n0 * D * 2, stream);
  k_scatter_bf<<<(n1 + 3) / 4, 256, 0, stream>>>(B1, perm0, n1, MA);
  k_econv2<true, false><<<(n0 + 3) / 4, 256, 0, stream>>>(MA, adj0_src, ec0_src, indptr_src, nullptr,
                                                          n0, B2, MB);
  k_sage<true, false><<<(n0 + 3) / 4, 256, 0, stream>>>(MB, adj0_dst, indptr_dst, nullptr, n0, B1);
  gemm_mx(B1, B2, B0, (unsigned short*)MA, nullptr, n0, 8);
  k_sage<true, false><<<(n0 + 3) / 4, 256, 0, stream>>>(MA, adj0_dst, indptr_dst, nullptr, n0, B1);
  gemm_mx(B1, B0, out, nullptr, down0, n0, 9);
}

// Round 5
// 1192.317 us; speedup vs baseline: 1.9834x; 1.0237x over previous
//
#include <hip/hip_runtime.h>
#include <stdint.h>

#define DEV __device__ __forceinline__

constexpr int N0 = 50000;
constexpr int E0 = 800000;
constexpr int D  = 128;

typedef __attribute__((ext_vector_type(8))) short bf16x8;
typedef __attribute__((ext_vector_type(4))) float f32x4;

DEV float bf2f(unsigned u) { return __uint_as_float(u << 16); }
DEV unsigned short f2bf(float f) {
  unsigned u = __float_as_uint(f);
  unsigned r = u + 0x7fffu + ((u >> 16) & 1u);   // round-to-nearest-even
  return (unsigned short)(r >> 16);
}

DEV unsigned wave_incl_scan(unsigned v, int lane) {
  #pragma unroll
  for (int off = 1; off < 64; off <<= 1) {
    unsigned u = __shfl_up(v, (unsigned)off);
    if (lane >= off) v += u;
  }
  return v;
}

// ---------------- CSR build ----------------
// count AND record per-edge rank (atomicAdd return) so fill needs no atomics
__global__ void k_count(const int* __restrict__ src, const int* __restrict__ dst,
                        unsigned* cnt_src, unsigned* cnt_dst,
                        unsigned* __restrict__ rank_src, unsigned* __restrict__ rank_dst) {
  int e = blockIdx.x * blockDim.x + threadIdx.x;
  if (e < E0) {
    rank_src[e] = atomicAdd(&cnt_src[src[e]], 1u);
    rank_dst[e] = atomicAdd(&cnt_dst[dst[e]], 1u);
  }
}

// ---- 2-level exclusive scan ----
__global__ void k_psum(const unsigned* __restrict__ in, int n, unsigned* __restrict__ part) {
  int t = threadIdx.x, lane = t & 63, w = t >> 6;
  int base = blockIdx.x * 1024 + t * 4;
  unsigned s = 0;
  #pragma unroll
  for (int j = 0; j < 4; ++j) { int i = base + j; if (i < n) s += in[i]; }
  #pragma unroll
  for (int off = 32; off >= 1; off >>= 1) s += __shfl_xor(s, off);
  __shared__ unsigned ws[4];
  if (lane == 0) ws[w] = s;
  __syncthreads();
  if (t == 0) part[blockIdx.x] = ws[0] + ws[1] + ws[2] + ws[3];
}

__global__ void k_scoff(const unsigned* __restrict__ part, int nch,
                        unsigned* __restrict__ off, unsigned* __restrict__ total_out) {
  if (threadIdx.x == 0) {
    unsigned run = 0;
    for (int c = 0; c < nch; ++c) { off[c] = run; run += part[c]; }
    *total_out = run;
  }
}

__global__ void k_sapply(const unsigned* __restrict__ in, const unsigned* __restrict__ choff,
                         int n, unsigned* __restrict__ out) {
  int t = threadIdx.x, lane = t & 63, w = t >> 6;
  int base = blockIdx.x * 1024 + t * 4;
  unsigned v[4]; unsigned s = 0;
  #pragma unroll
  for (int j = 0; j < 4; ++j) { int i = base + j; v[j] = (i < n) ? in[i] : 0u; s += v[j]; }
  unsigned incl = wave_incl_scan(s, lane);
  __shared__ unsigned wsum[4], woff[4];
  if (lane == 63) wsum[w] = incl;
  __syncthreads();
  if (t == 0) { unsigned run = 0; for (int j = 0; j < 4; ++j) { woff[j] = run; run += wsum[j]; } }
  __syncthreads();
  unsigned run = choff[blockIdx.x] + woff[w] + incl - s;
  #pragma unroll
  for (int j = 0; j < 4; ++j) {
    int i = base + j;
    if (i < n) out[i] = run;
    run += v[j];
  }
}

// atomic-free merged fill of both CSR adjacency arrays
__global__ void k_fill2(const int* __restrict__ src, const int* __restrict__ dst,
                        const unsigned* __restrict__ rank_src, const unsigned* __restrict__ rank_dst,
                        const unsigned* __restrict__ indptr_src, const unsigned* __restrict__ indptr_dst,
                        int* __restrict__ adj_src, int* __restrict__ adj_dst) {
  int e = blockIdx.x * blockDim.x + threadIdx.x;
  if (e < E0) {
    int s = src[e], d = dst[e];
    adj_dst[indptr_dst[d] + rank_dst[e]] = s;
    adj_src[indptr_src[s] + rank_src[e]] = d;
  }
}

// compose level mask/relabel (both arrays in one pass)
__global__ void k_adj_next2(const int* __restrict__ adjd, const int* __restrict__ adjs,
                            const int* __restrict__ new_id,
                            int* __restrict__ outd, int* __restrict__ outs) {
  int pos = blockIdx.x * blockDim.x + threadIdx.x;
  if (pos < E0) {
    int a = adjd[pos];
    outd[pos] = (a >= 0) ? new_id[a] : -1;
    int b = adjs[pos];
    outs[pos] = (b >= 0) ? new_id[b] : -1;
  }
}

__global__ void k_adj_next(const int* __restrict__ adj_prev, const int* __restrict__ new_id,
                           int* __restrict__ adj_out) {
  int pos = blockIdx.x * blockDim.x + threadIdx.x;
  if (pos < E0) {
    int a = adj_prev[pos];
    adj_out[pos] = (a >= 0) ? new_id[a] : -1;
  }
}

// ---------------- weight prep ----------------
// f32 BT for convs 0-3: BT[c][k][o], k<128 -> Wl, else Wr
__global__ void k_wt(const float* __restrict__ Wl, const float* __restrict__ Wr, float* __restrict__ BT) {
  int idx = blockIdx.x * blockDim.x + threadIdx.x;
  if (idx < 4 * 256 * 128) {
    int o = idx & 127;
    int k = (idx >> 7) & 255;
    int c = idx >> 15;
    float v = (k < 128) ? Wl[(c * 128 + o) * 128 + k] : Wr[(c * 128 + o) * 128 + (k - 128)];
    BT[idx] = v;
  }
}

// MFMA-fragment-packed split-bf16 weights for convs 4-9:
// element (c,ks,ct,lane,j) = W[k=ks*32+(lane>>4)*8+j][o=ct*16+(lane&15)], conv = c+4
__global__ void k_wt_pk(const float* __restrict__ Wl, const float* __restrict__ Wr,
                        unsigned short* __restrict__ Bhi, unsigned short* __restrict__ Blo) {
  int idx = blockIdx.x * blockDim.x + threadIdx.x;
  if (idx >= 6 * 8 * 8 * 64) return;
  int l  = idx & 63;
  int ct = (idx >> 6) & 7;
  int ks = (idx >> 9) & 7;
  int c  = idx >> 12;          // 0..5 -> conv c+4
  int k0 = ks * 32 + (l >> 4) * 8;
  int o  = ct * 16 + (l & 15);
  int conv = c + 4;
  const float* Wrow = (k0 < 128) ? (Wl + ((size_t)conv * 128 + o) * 128 + k0)
                                 : (Wr + ((size_t)conv * 128 + o) * 128 + (k0 - 128));
  size_t base = (size_t)idx * 8;
  #pragma unroll
  for (int j = 0; j < 8; ++j) {
    float wv = Wrow[j];
    unsigned short h = f2bf(wv);
    Bhi[base + j] = h;
    Blo[base + j] = f2bf(wv - bf2f(h));
  }
}

// ---------------- SAGE mean aggregation ----------------
template<bool BF, bool MASKED>
__global__ void k_sage(const void* __restrict__ xv, const int* __restrict__ adj,
                       const unsigned* __restrict__ indptr, const int* __restrict__ orig,
                       int n, float* __restrict__ mean) {
  int wid = (blockIdx.x * blockDim.x + threadIdx.x) >> 6;
  int lane = threadIdx.x & 63;
  if (wid >= n) return;
  int o = orig ? orig[wid] : wid;
  unsigned s0 = indptr[o], s1 = indptr[o + 1];
  const float* xf = (const float*)xv;
  const unsigned* xb = (const unsigned*)xv;
  float a0 = 0.f, a1 = 0.f, cnt = 0.f;
  unsigned idx = s0;
  for (; idx + 4 <= s1; idx += 4) {
    int ad[4];
    #pragma unroll
    for (int j = 0; j < 4; ++j) ad[j] = adj[idx + j];
    #pragma unroll
    for (int j = 0; j < 4; ++j) {
      if (!MASKED || ad[j] >= 0) {
        float x0, x1;
        if (BF) { unsigned u = xb[(size_t)ad[j] * 64 + lane]; x0 = bf2f(u & 0xffffu); x1 = bf2f(u >> 16); }
        else    { float2 v = *(const float2*)(xf + (size_t)ad[j] * D + lane * 2); x0 = v.x; x1 = v.y; }
        a0 += x0; a1 += x1; cnt += 1.f;
      }
    }
  }
  for (; idx < s1; ++idx) {
    int a = adj[idx];
    if (!MASKED || a >= 0) {
      float x0, x1;
      if (BF) { unsigned u = xb[(size_t)a * 64 + lane]; x0 = bf2f(u & 0xffffu); x1 = bf2f(u >> 16); }
      else    { float2 v = *(const float2*)(xf + (size_t)a * D + lane * 2); x0 = v.x; x1 = v.y; }
      a0 += x0; a1 += x1; cnt += 1.f;
    }
  }
  if (!MASKED) cnt = (float)(s1 - s0);
  float inv = 1.0f / fmaxf(cnt, 1.0f);
  *(float2*)(mean + (size_t)wid * D + lane * 2) = make_float2(a0 * inv, a1 * inv);
}

// ---------------- weighted edge conv ----------------
template<bool BF, bool MASKED>
__global__ void k_econv2(const void* __restrict__ xv, const int* __restrict__ adj,
                         const float* __restrict__ ecs, const unsigned* __restrict__ indptr,
                         const int* __restrict__ orig, int n,
                         float* __restrict__ out, unsigned* __restrict__ outbf) {
  int wid = (blockIdx.x * blockDim.x + threadIdx.x) >> 6;
  int lane = threadIdx.x & 63;
  if (wid >= n) return;
  int o = orig ? orig[wid] : wid;
  unsigned s0 = indptr[o], s1 = indptr[o + 1];
  const float* xf = (const float*)xv;
  const unsigned* xb = (const unsigned*)xv;
  float a0 = 0.f, a1 = 0.f;
  unsigned idx = s0;
  for (; idx + 4 <= s1; idx += 4) {
    int ad[4]; float wv[4];
    #pragma unroll
    for (int j = 0; j < 4; ++j) { ad[j] = adj[idx + j]; wv[j] = ecs[idx + j]; }
    #pragma unroll
    for (int j = 0; j < 4; ++j) {
      if (!MASKED || ad[j] >= 0) {
        float x0, x1;
        if (BF) { unsigned u = xb[(size_t)ad[j] * 64 + lane]; x0 = bf2f(u & 0xffffu); x1 = bf2f(u >> 16); }
        else    { float2 v = *(const float2*)(xf + (size_t)ad[j] * D + lane * 2); x0 = v.x; x1 = v.y; }
        a0 = fmaf(wv[j], x0, a0); a1 = fmaf(wv[j], x1, a1);
      }
    }
  }
  for (; idx < s1; ++idx) {
    int a = adj[idx]; float wgt = ecs[idx];
    if (!MASKED || a >= 0) {
      float x0, x1;
      if (BF) { unsigned u = xb[(size_t)a * 64 + lane]; x0 = bf2f(u & 0xffffu); x1 = bf2f(u >> 16); }
      else    { float2 v = *(const float2*)(xf + (size_t)a * D + lane * 2); x0 = v.x; x1 = v.y; }
      a0 = fmaf(wgt, x0, a0); a1 = fmaf(wgt, x1, a1);
    }
  }
  *(float2*)(out + (size_t)wid * D + lane * 2) = make_float2(a0, a1);
  if (outbf) {
    unsigned p = (unsigned)f2bf(a0) | ((unsigned)f2bf(a1) << 16);
    outbf[(size_t)wid * 64 + lane] = p;
  }
}

// ---------------- f32 conv GEMM (convs 0-3, selection-exact) ----------------
__launch_bounds__(256)
__global__ void k_conv_gemm(const float* __restrict__ mean, const float* __restrict__ xin,
                            const float* __restrict__ BT, const float* __restrict__ bias,
                            float* __restrict__ y, unsigned short* __restrict__ ybf, int n) {
  __shared__ float As[64][17];
  __shared__ float Bs[16][128];
  int tid = threadIdx.x;
  int tx = tid & 15, ty = tid >> 4;
  int row0 = blockIdx.x * 64;
  float acc[4][8];
  #pragma unroll
  for (int r = 0; r < 4; ++r)
    #pragma unroll
    for (int c = 0; c < 8; ++c) acc[r][c] = 0.f;

  int lm = tid >> 2;
  int lk = (tid & 3) * 4;
  int bk = tid >> 4;
  int bo = (tid & 15) * 8;

  for (int kc = 0; kc < 16; ++kc) {
    int k0 = kc * 16;
    const float* A = (k0 < 128) ? mean : xin;
    int kk = k0 & 127;
    int gr = row0 + lm;
    float4 av = make_float4(0.f, 0.f, 0.f, 0.f);
    if (gr < n) av = *(const float4*)(A + (size_t)gr * D + kk + lk);
    As[lm][lk + 0] = av.x; As[lm][lk + 1] = av.y; As[lm][lk + 2] = av.z; As[lm][lk + 3] = av.w;
    float4 bv0 = *(const float4*)(BT + (size_t)(k0 + bk) * 128 + bo);
    float4 bv1 = *(const float4*)(BT + (size_t)(k0 + bk) * 128 + bo + 4);
    *(float4*)&Bs[bk][bo] = bv0;
    *(float4*)&Bs[bk][bo + 4] = bv1;
    __syncthreads();
    #pragma unroll
    for (int k = 0; k < 16; ++k) {
      float a[4];
      #pragma unroll
      for (int r = 0; r < 4; ++r) a[r] = As[ty * 4 + r][k];
      float4 b0 = *(const float4*)&Bs[k][tx * 4];
      float4 b1 = *(const float4*)&Bs[k][64 + tx * 4];
      float bb[8] = {b0.x, b0.y, b0.z, b0.w, b1.x, b1.y, b1.z, b1.w};
      #pragma unroll
      for (int r = 0; r < 4; ++r)
        #pragma unroll
        for (int c = 0; c < 8; ++c)
          acc[r][c] = fmaf(a[r], bb[c], acc[r][c]);
    }
    __syncthreads();
  }
  float4 bs0 = *(const float4*)(bias + tx * 4);
  float4 bs1 = *(const float4*)(bias + 64 + tx * 4);
  #pragma unroll
  for (int r = 0; r < 4; ++r) {
    int gr = row0 + ty * 4 + r;
    if (gr < n) {
      float4 o0 = make_float4(acc[r][0] + bs0.x, acc[r][1] + bs0.y, acc[r][2] + bs0.z, acc[r][3] + bs0.w);
      float4 o1 = make_float4(acc[r][4] + bs1.x, acc[r][5] + bs1.y, acc[r][6] + bs1.z, acc[r][7] + bs1.w);
      *(float4*)(y + (size_t)gr * D + tx * 4) = o0;
      *(float4*)(y + (size_t)gr * D + 64 + tx * 4) = o1;
      if (ybf) {
        ushort4 p0; p0.x = f2bf(o0.x); p0.y = f2bf(o0.y); p0.z = f2bf(o0.z); p0.w = f2bf(o0.w);
        ushort4 p1; p1.x = f2bf(o1.x); p1.y = f2bf(o1.y); p1.z = f2bf(o1.z); p1.w = f2bf(o1.w);
        *(ushort4*)(ybf + (size_t)gr * D + tx * 4) = p0;
        *(ushort4*)(ybf + (size_t)gr * D + 64 + tx * 4) = p1;
      }
    }
  }
}

// ---------------- split-bf16 MFMA GEMM (convs 4-9, post-selection) ----------------
__launch_bounds__(256)
__global__ void k_gemm_mfma(const float* __restrict__ mean, const float* __restrict__ xin,
                            const unsigned short* __restrict__ Bhi, const unsigned short* __restrict__ Blo,
                            const float* __restrict__ bias, const float* __restrict__ skip,
                            float* __restrict__ y, unsigned short* __restrict__ ybf, int n) {
  int tid = threadIdx.x;
  int lane = tid & 63, w = tid >> 6;
  int row0 = blockIdx.x * 64 + w * 16;
  int arow = row0 + (lane & 15);
  int kgrp = lane >> 4;                 // 0..3
  bool rowok = arow < n;
  f32x4 acc[8];
  #pragma unroll
  for (int ct = 0; ct < 8; ++ct) acc[ct] = f32x4{0.f, 0.f, 0.f, 0.f};

  #pragma unroll
  for (int ks = 0; ks < 8; ++ks) {
    const float* A = (ks < 4) ? mean : xin;
    int kk = (ks & 3) * 32 + kgrp * 8;
    float av[8];
    if (rowok) {
      float4 a0 = *(const float4*)(A + (size_t)arow * D + kk);
      float4 a1 = *(const float4*)(A + (size_t)arow * D + kk + 4);
      av[0] = a0.x; av[1] = a0.y; av[2] = a0.z; av[3] = a0.w;
      av[4] = a1.x; av[5] = a1.y; av[6] = a1.z; av[7] = a1.w;
    } else {
      #pragma unroll
      for (int j = 0; j < 8; ++j) av[j] = 0.f;
    }
    bf16x8 ahi, alo;
    #pragma unroll
    for (int j = 0; j < 8; ++j) {
      unsigned short h = f2bf(av[j]);
      ahi[j] = (short)h;
      alo[j] = (short)f2bf(av[j] - bf2f(h));
    }
    #pragma unroll
    for (int ct = 0; ct < 8; ++ct) {
      size_t boff = (((size_t)ks * 8 + ct) * 64 + lane) * 8;
      bf16x8 bh = *(const bf16x8*)(Bhi + boff);
      bf16x8 bl = *(const bf16x8*)(Blo + boff);
      acc[ct] = __builtin_amdgcn_mfma_f32_16x16x32_bf16(ahi, bh, acc[ct], 0, 0, 0);
      acc[ct] = __builtin_amdgcn_mfma_f32_16x16x32_bf16(alo, bh, acc[ct], 0, 0, 0);
      acc[ct] = __builtin_amdgcn_mfma_f32_16x16x32_bf16(ahi, bl, acc[ct], 0, 0, 0);
    }
  }
  int ccol = lane & 15;
  #pragma unroll
  for (int ct = 0; ct < 8; ++ct) {
    int col = ct * 16 + ccol;
    float bb = bias[col];
    #pragma unroll
    for (int r = 0; r < 4; ++r) {
      int row = row0 + kgrp * 4 + r;
      if (row < n) {
        float v = acc[ct][r] + bb;
        if (skip) v += skip[(size_t)row * D + col];
        y[(size_t)row * D + col] = v;
        if (ybf) ybf[(size_t)row * D + col] = f2bf(v);
      }
    }
  }
}

// ---------------- cal_ew ----------------
__global__ void k_deg_len(const unsigned* __restrict__ indptr, int n, float* __restrict__ deg) {
  int j = blockIdx.x * blockDim.x + threadIdx.x;
  if (j < n) deg[j] = (float)(indptr[j + 1] - indptr[j]);
}

__global__ void k_deg_mask(const int* __restrict__ adj_src, const unsigned* __restrict__ indptr_src,
                           const int* __restrict__ orig, int n, float* __restrict__ deg) {
  int j = blockIdx.x * blockDim.x + threadIdx.x;
  if (j >= n) return;
  int o = orig ? orig[j] : j;
  unsigned s0 = indptr_src[o], s1 = indptr_src[o + 1];
  float d = 0.f;
  for (unsigned i = s0; i < s1; ++i) d += (adj_src[i] >= 0) ? 1.f : 0.f;
  deg[j] = d;
}

template<bool MASKED>
__global__ void k_ew_dst(const int* __restrict__ adj, const unsigned* __restrict__ indptr,
                         const int* __restrict__ orig, const float* __restrict__ w,
                         const float* __restrict__ deg, int n,
                         float* __restrict__ ws_slot, float* __restrict__ aggrw,
                         float* __restrict__ ec_slot) {
  int j = blockIdx.x * blockDim.x + threadIdx.x;
  if (j >= n) return;
  int o = orig ? orig[j] : j;
  unsigned s0 = indptr[o], s1 = indptr[o + 1];
  float s = 1e-12f;
  for (unsigned pos = s0; pos < s1; ++pos) {
    int a = adj[pos];
    float ws = 0.f;
    if (!MASKED || a >= 0) {
      float d = deg[a];
      ws = (w ? w[a] : 1.0f) / (d > 0.f ? d : 1.0f);
    }
    ws_slot[pos] = ws;
    s += ws;
  }
  aggrw[j] = s;
  float inv = 1.0f / s;
  for (unsigned pos = s0; pos < s1; ++pos) ec_slot[pos] = ws_slot[pos] * inv;
}

template<bool MASKED>
__global__ void k_ew_src(const int* __restrict__ adj_src, const unsigned* __restrict__ indptr_src,
                         const int* __restrict__ orig, const float* __restrict__ w,
                         const float* __restrict__ deg, const float* __restrict__ aggrw, int n,
                         float* __restrict__ ec_slot) {
  int j = blockIdx.x * blockDim.x + threadIdx.x;
  if (j >= n) return;
  int o = orig ? orig[j] : j;
  unsigned s0 = indptr_src[o], s1 = indptr_src[o + 1];
  float d = deg[j];
  float wn = (w ? w[j] : 1.0f) / (d > 0.f ? d : 1.0f);
  for (unsigned pos = s0; pos < s1; ++pos) {
    int a = adj_src[pos];
    ec_slot[pos] = (!MASKED || a >= 0) ? (wn / aggrw[a]) : 0.f;
  }
}

// ---------------- pooling ----------------
DEV unsigned mono_key(float f) {
  unsigned u = __float_as_uint(f);
  return (u & 0x80000000u) ? ~u : (u | 0x80000000u);
}

__global__ void k_score(const float* __restrict__ x, const float* __restrict__ p,
                        int n, float* __restrict__ score, unsigned* __restrict__ keys) {
  int wid = (blockIdx.x * blockDim.x + threadIdx.x) >> 6;
  int lane = threadIdx.x & 63;
  if (wid >= n) return;
  float p0 = p[lane * 2], p1 = p[lane * 2 + 1];
  const float2 xv = *(const float2*)(x + (size_t)wid * D + lane * 2);
  float partial = xv.x * p0 + xv.y * p1;
  float pn = p0 * p0 + p1 * p1;
  #pragma unroll
  for (int off = 32; off >= 1; off >>= 1) {
    partial += __shfl_xor(partial, off);
    pn += __shfl_xor(pn, off);
  }
  if (lane == 0) {
    float sc = partial * (1.0f / sqrtf(pn));
    score[wid] = sc;
    keys[wid] = mono_key(sc);
  }
}

// multi-block radix select (proven R3 form): init -> 4x(hist+pick)
__global__ void k_sel_init(unsigned* bins, unsigned* state, int k) {
  int t = threadIdx.x;
  if (t < 256) bins[t] = 0u;
  if (t == 0) { state[0] = 0u; state[1] = (unsigned)k; }
}

__global__ void k_hist(const unsigned* __restrict__ keys, int n, const unsigned* __restrict__ state,
                       unsigned* __restrict__ bins, int byte) {
  __shared__ unsigned lb[256];
  for (int i = threadIdx.x; i < 256; i += blockDim.x) lb[i] = 0u;
  __syncthreads();
  unsigned prefix = state[0];
  unsigned mask = (byte == 3) ? 0u : (0xFFFFFFFFu << ((byte + 1) * 8));
  for (int i = blockIdx.x * blockDim.x + threadIdx.x; i < n; i += gridDim.x * blockDim.x) {
    unsigned key = keys[i];
    if ((key & mask) == (prefix & mask))
      atomicAdd(&lb[(key >> (byte * 8)) & 255], 1u);
  }
  __syncthreads();
  for (int i = threadIdx.x; i < 256; i += blockDim.x)
    if (lb[i]) atomicAdd(&bins[i], lb[i]);
}

__global__ void k_pick(unsigned* bins, unsigned* state, int byte) {
  if (threadIdx.x == 0) {
    unsigned r = state[1];
    int b;
    for (b = 255; b > 0; --b) {
      unsigned c = bins[b];
      if (c >= r) break;
      r -= c;
    }
    state[0] |= ((unsigned)b) << (byte * 8);
    state[1] = r;
  }
  __syncthreads();
  for (int i = threadIdx.x; i < 256; i += blockDim.x) bins[i] = 0u;
}

// ---- parallel pack ----
__global__ void k_flags(const unsigned* __restrict__ keys, const unsigned* __restrict__ state,
                        int n, uint2* __restrict__ part) {
  int t = threadIdx.x, lane = t & 63, w = t >> 6;
  int base = blockIdx.x * 1024 + t * 4;
  unsigned T = state[0];
  unsigned cnt = 0;
  #pragma unroll
  for (int j = 0; j < 4; ++j) {
    int i = base + j;
    if (i < n) {
      unsigned key = keys[i];
      cnt += (key > T ? 1u : 0u) + ((key == T ? 1u : 0u) << 16);
    }
  }
  #pragma unroll
  for (int off = 32; off >= 1; off >>= 1) cnt += __shfl_xor(cnt, off);
  __shared__ unsigned ws[4];
  if (lane == 0) ws[w] = cnt;
  __syncthreads();
  if (t == 0) {
    unsigned s = ws[0] + ws[1] + ws[2] + ws[3];
    part[blockIdx.x] = make_uint2(s & 0xffffu, s >> 16);
  }
}

__global__ void k_choff(const uint2* __restrict__ part, int nch, uint2* __restrict__ off) {
  if (threadIdx.x == 0) {
    unsigned g = 0, e = 0;
    for (int c = 0; c < nch; ++c) { off[c] = make_uint2(g, e); g += part[c].x; e += part[c].y; }
  }
}

__global__ void k_pack2(const unsigned* __restrict__ keys, const unsigned* __restrict__ state,
                        const uint2* __restrict__ choff, const float* __restrict__ aggrw,
                        const int* __restrict__ orig, int n,
                        int* __restrict__ perm, int* __restrict__ new_id,
                        float* __restrict__ w_next, int* __restrict__ orig_next) {
  int t = threadIdx.x, lane = t & 63, w = t >> 6;
  int base = blockIdx.x * 1024 + t * 4;
  unsigned T = state[0], r = state[1];
  unsigned f[4];
  unsigned cnt = 0;
  #pragma unroll
  for (int j = 0; j < 4; ++j) {
    int i = base + j;
    unsigned key = (i < n) ? keys[i] : 0u;
    unsigned gt = (i < n && key > T) ? 1u : 0u;
    unsigned eq = (i < n && key == T) ? 1u : 0u;
    f[j] = gt | (eq << 1);
    cnt += gt + (eq << 16);
  }
  unsigned incl = wave_incl_scan(cnt, lane);
  __shared__ unsigned wsum[4], woff[4];
  if (lane == 63) wsum[w] = incl;
  __syncthreads();
  if (t == 0) { unsigned run = 0; for (int j = 0; j < 4; ++j) { woff[j] = run; run += wsum[j]; } }
  __syncthreads();
  unsigned before = woff[w] + incl - cnt;
  uint2 o0 = choff[blockIdx.x];
  unsigned gt_b = o0.x + (before & 0xffffu);
  unsigned eq_b = o0.y + (before >> 16);
  #pragma unroll
  for (int j = 0; j < 4; ++j) {
    int i = base + j;
    if (i >= n) break;
    unsigned gt = f[j] & 1u, eq = (f[j] >> 1) & 1u;
    bool sel = gt || (eq && eq_b < r);
    if (sel) {
      int pos = (int)(gt_b + (eq_b < r ? eq_b : r));
      perm[pos] = i;
      new_id[i] = pos;
      w_next[pos] = aggrw[i];
      orig_next[pos] = orig ? orig[i] : i;
    } else {
      new_id[i] = -1;
    }
    gt_b += gt; eq_b += eq;
  }
}

__global__ void k_gate(const float* __restrict__ xin, const int* __restrict__ perm,
                       const float* __restrict__ score, int k, float* __restrict__ xout,
                       unsigned* __restrict__ outbf) {
  int wid = (blockIdx.x * blockDim.x + threadIdx.x) >> 6;
  int lane = threadIdx.x & 63;
  if (wid >= k) return;
  int j = perm[wid];
  float g = tanhf(score[j]);
  float2 v = *(const float2*)(xin + (size_t)j * D + lane * 2);
  v.x *= g; v.y *= g;
  *(float2*)(xout + (size_t)wid * D + lane * 2) = v;
  if (outbf) {
    unsigned p = (unsigned)f2bf(v.x) | ((unsigned)f2bf(v.y) << 16);
    outbf[(size_t)wid * 64 + lane] = p;
  }
}

__global__ void k_scatter_bf(const float* __restrict__ xin, const int* __restrict__ perm,
                             int k, unsigned* __restrict__ outbf) {
  int wid = (blockIdx.x * blockDim.x + threadIdx.x) >> 6;
  int lane = threadIdx.x & 63;
  if (wid >= k) return;
  int p = perm[wid];
  float2 v = *(const float2*)(xin + (size_t)wid * D + lane * 2);
  unsigned pk = (unsigned)f2bf(v.x) | ((unsigned)f2bf(v.y) << 16);
  outbf[(size_t)p * 64 + lane] = pk;
}

// =============================================================================
extern "C" void kernel_launch(void* const* d_in, const int* in_sizes, int n_in,
                              void* d_out, int out_size, void* d_ws, size_t ws_size,
                              hipStream_t stream) {
  const float* x_in   = (const float*)d_in[0];
  const int*   ei     = (const int*)d_in[1];
  const int*   src0   = ei;
  const int*   dst0   = ei + E0;
  const float* Wl     = (const float*)d_in[2];
  const float* bl     = (const float*)d_in[3];
  const float* Wr     = (const float*)d_in[4];
  const float* pool_p = (const float*)d_in[5];
  float* out = (float*)d_out;

  const int n0 = N0, k0 = 25000, n1 = 25000, k1 = 12500, n2 = 12500;
  const int NCH0 = (N0 + 1023) / 1024;   // 49

  char* ws = (char*)d_ws;
  size_t off = 0;
  auto alloc = [&](size_t bytes) -> char* {
    char* p = ws + off;
    off += (bytes + 255) & ~(size_t)255;
    return p;
  };
  const size_t NBY = (size_t)N0 * D * 4;
  float* B0    = (float*)alloc(NBY);
  float* B1    = (float*)alloc(NBY);
  float* B2    = (float*)alloc(NBY);
  float* down0 = (float*)alloc(NBY);
  float* down1 = (float*)alloc(NBY / 2);
  unsigned* MA = (unsigned*)alloc((size_t)N0 * D * 2);
  unsigned* MB = (unsigned*)alloc((size_t)N0 * D * 2);
  int* adj0_dst = (int*)alloc(E0 * 4);
  int* adj0_src = (int*)alloc(E0 * 4);
  int* adj1_dst = (int*)alloc(E0 * 4);
  int* adj1_src = (int*)alloc(E0 * 4);
  float* ec0_src = (float*)alloc(E0 * 4);
  float* ec1_src = (float*)alloc(E0 * 4);
  float* ec_dst  = (float*)alloc(E0 * 4);
  float* ws_slot = (float*)alloc(E0 * 4);
  int* adj2_dst  = (int*)ws_slot;          // alias: ws_slot dead before adj2 is built
  unsigned* rank_src = (unsigned*)alloc(E0 * 4);
  unsigned* rank_dst = (unsigned*)alloc(E0 * 4);
  unsigned* indptr_dst = (unsigned*)alloc((N0 + 1) * 4);
  unsigned* indptr_src = (unsigned*)alloc((N0 + 1) * 4);
  unsigned* cnt_src = (unsigned*)alloc(N0 * 4);
  unsigned* cnt_dst = (unsigned*)alloc(N0 * 4);
  float* deg   = (float*)alloc(N0 * 4);
  float* aggrw = (float*)alloc(N0 * 4);
  float* w1 = (float*)alloc(n1 * 4);
  float* w2 = (float*)alloc(n2 * 4);
  float* score = (float*)alloc(N0 * 4);
  unsigned* keys = (unsigned*)alloc(N0 * 4);
  int* perm0 = (int*)alloc(k0 * 4);
  int* perm1 = (int*)alloc(k1 * 4);
  int* orig1 = (int*)alloc(k0 * 4);
  int* orig2 = (int*)alloc(k1 * 4);
  int* new_id = (int*)alloc(N0 * 4);
  unsigned* bins  = (unsigned*)alloc(256 * 4);
  unsigned* state = (unsigned*)alloc(8);
  unsigned* spart = (unsigned*)alloc(64 * 4);
  unsigned* soff  = (unsigned*)alloc(64 * 4);
  uint2* ppart = (uint2*)alloc(64 * 8);
  uint2* poff  = (uint2*)alloc(64 * 8);
  float* BT = (float*)alloc((size_t)4 * 256 * 128 * 4);
  unsigned short* Bhi = (unsigned short*)alloc((size_t)6 * 8 * 8 * 64 * 8 * 2);
  unsigned short* Blo = (unsigned short*)alloc((size_t)6 * 8 * 8 * 64 * 8 * 2);

  const int EG = (E0 + 255) / 256;

  auto scan_np1 = [&](const unsigned* in, unsigned* outp, int n, int nch) {
    k_psum<<<nch, 256, 0, stream>>>(in, n, spart);
    k_scoff<<<1, 64, 0, stream>>>(spart, nch, soff, outp + n);
    k_sapply<<<nch, 256, 0, stream>>>(in, soff, n, outp);
  };

  // ---- CSR build (rank-from-count, atomic-free fill) ----
  hipMemsetAsync(cnt_src, 0, N0 * 4, stream);
  hipMemsetAsync(cnt_dst, 0, N0 * 4, stream);
  k_count<<<EG, 256, 0, stream>>>(src0, dst0, cnt_src, cnt_dst, rank_src, rank_dst);
  scan_np1(cnt_src, indptr_src, N0, NCH0);
  scan_np1(cnt_dst, indptr_dst, N0, NCH0);
  k_fill2<<<EG, 256, 0, stream>>>(src0, dst0, rank_src, rank_dst, indptr_src, indptr_dst,
                                  adj0_src, adj0_dst);
  k_wt<<<(4 * 256 * 128 + 255) / 256, 256, 0, stream>>>(Wl, Wr, BT);
  k_wt_pk<<<(6 * 8 * 8 * 64 + 255) / 256, 256, 0, stream>>>(Wl, Wr, Bhi, Blo);

  auto gemm = [&](const float* meanb, const float* xin, float* yout, unsigned short* ybf,
                  int n, int cidx) {
    k_conv_gemm<<<(n + 63) / 64, 256, 0, stream>>>(meanb, xin, BT + (size_t)cidx * 256 * 128,
                                                   bl + cidx * 128, yout, ybf, n);
  };
  auto gemm_mx = [&](const float* meanb, const float* xin, float* yout, unsigned short* ybf,
                     const float* skip, int n, int cidx) {
    size_t o = (size_t)(cidx - 4) * 8 * 8 * 64 * 8;
    k_gemm_mfma<<<(n + 63) / 64, 256, 0, stream>>>(meanb, xin, Bhi + o, Blo + o,
                                                   bl + cidx * 128, skip, yout, ybf, n);
  };

  auto pool_sel = [&](const float* xpool, int n, int kk, int level, const int* orig,
                      int* perm, float* w_next, int* orig_next,
                      float* xout, unsigned* xout_bf) {
    int nch = (n + 1023) / 1024;
    k_score<<<(n + 3) / 4, 256, 0, stream>>>(xpool, pool_p + level * D, n, score, keys);
    k_sel_init<<<1, 256, 0, stream>>>(bins, state, kk);
    for (int byte = 3; byte >= 0; --byte) {
      k_hist<<<256, 256, 0, stream>>>(keys, n, state, bins, byte);
      k_pick<<<1, 256, 0, stream>>>(bins, state, byte);
    }
    k_flags<<<nch, 256, 0, stream>>>(keys, state, n, ppart);
    k_choff<<<1, 64, 0, stream>>>(ppart, nch, poff);
    k_pack2<<<nch, 256, 0, stream>>>(keys, state, poff, aggrw, orig, n, perm, new_id, w_next, orig_next);
    k_gate<<<(kk + 3) / 4, 256, 0, stream>>>(xpool, perm, score, kk, xout, xout_bf);
  };

  // ======== down level 0 (f32, selection-exact) ========
  k_sage<false, false><<<(n0 + 3) / 4, 256, 0, stream>>>(x_in, adj0_dst, indptr_dst, nullptr, n0, B1);
  gemm(B1, x_in, B2, nullptr, n0, 0);
  k_sage<false, false><<<(n0 + 3) / 4, 256, 0, stream>>>(B2, adj0_dst, indptr_dst, nullptr, n0, B1);
  gemm(B1, B2, down0, nullptr, n0, 1);
  k_deg_len<<<(n0 + 255) / 256, 256, 0, stream>>>(indptr_src, n0, deg);
  k_ew_dst<false><<<(n0 + 255) / 256, 256, 0, stream>>>(adj0_dst, indptr_dst, nullptr, nullptr, deg, n0,
                                                        ws_slot, aggrw, ec_dst);
  k_ew_src<false><<<(n0 + 255) / 256, 256, 0, stream>>>(adj0_src, indptr_src, nullptr, nullptr, deg, aggrw,
                                                        n0, ec0_src);
  k_econv2<false, false><<<(n0 + 3) / 4, 256, 0, stream>>>(down0, adj0_dst, ec_dst, indptr_dst, nullptr,
                                                           n0, B1, nullptr);
  pool_sel(B1, n0, k0, 0, nullptr, perm0, w1, orig1, B2, nullptr);
  k_adj_next2<<<EG, 256, 0, stream>>>(adj0_dst, adj0_src, new_id, adj1_dst, adj1_src);

  // ======== down level 1 (f32) ========
  k_sage<false, true><<<(n1 + 3) / 4, 256, 0, stream>>>(B2, adj1_dst, indptr_dst, orig1, n1, B1);
  gemm(B1, B2, B0, nullptr, n1, 2);
  k_sage<false, true><<<(n1 + 3) / 4, 256, 0, stream>>>(B0, adj1_dst, indptr_dst, orig1, n1, B1);
  gemm(B1, B0, down1, nullptr, n1, 3);
  k_deg_mask<<<(n1 + 255) / 256, 256, 0, stream>>>(adj1_src, indptr_src, orig1, n1, deg);
  k_ew_dst<true><<<(n1 + 255) / 256, 256, 0, stream>>>(adj1_dst, indptr_dst, orig1, w1, deg, n1,
                                                       ws_slot, aggrw, ec_dst);
  k_ew_src<true><<<(n1 + 255) / 256, 256, 0, stream>>>(adj1_src, indptr_src, orig1, w1, deg, aggrw,
                                                       n1, ec1_src);
  k_econv2<false, true><<<(n1 + 3) / 4, 256, 0, stream>>>(down1, adj1_dst, ec_dst, indptr_dst, orig1,
                                                          n1, B1, nullptr);
  pool_sel(B1, n1, k1, 1, orig1, perm1, w2, orig2, B2, MA);
  k_adj_next<<<EG, 256, 0, stream>>>(adj1_dst, new_id, adj2_dst);   // aliases ws_slot (dead)

  // ======== bottom (bf16 gathers, MFMA convs) ========
  k_sage<true, true><<<(n2 + 3) / 4, 256, 0, stream>>>(MA, adj2_dst, indptr_dst, orig2, n2, B1);
  gemm_mx(B1, B2, B0, (unsigned short*)MB, nullptr, n2, 4);
  k_sage<true, true><<<(n2 + 3) / 4, 256, 0, stream>>>(MB, adj2_dst, indptr_dst, orig2, n2, B1);
  gemm_mx(B1, B0, B2, nullptr, nullptr, n2, 5);

  // ======== up u=1 (bf16 gathers, MFMA convs; skip fused into conv 7) ========
  hipMemsetAsync(MA, 0, (size_t)n1 * D * 2, stream);
  k_scatter_bf<<<(n2 + 3) / 4, 256, 0, stream>>>(B2, perm1, n2, MA);
  k_econv2<true, true><<<(n1 + 3) / 4, 256, 0, stream>>>(MA, adj1_src, ec1_src, indptr_src, orig1,
                                                         n1, B1, MB);
  k_sage<true, true><<<(n1 + 3) / 4, 256, 0, stream>>>(MB, adj1_dst, indptr_dst, orig1, n1, B0);
  gemm_mx(B0, B1, B2, (unsigned short*)MA, nullptr, n1, 6);
  k_sage<true, true><<<(n1 + 3) / 4, 256, 0, stream>>>(MA, adj1_dst, indptr_dst, orig1, n1, B0);
  gemm_mx(B0, B2, B1, nullptr, down1, n1, 7);

  // ======== up u=0 (bf16 gathers, MFMA convs; skip fused into conv 9) ========
  hipMemsetAsync(MA, 0, (size_t)n0 * D * 2, stream);
  k_scatter_bf<<<(n1 + 3) / 4, 256, 0, stream>>>(B1, perm0, n1, MA);
  k_econv2<true, false><<<(n0 + 3) / 4, 256, 0, stream>>>(MA, adj0_src, ec0_src, indptr_src, nullptr,
                                                          n0, B2, MB);
  k_sage<true, false><<<(n0 + 3) / 4, 256, 0, stream>>>(MB, adj0_dst, indptr_dst, nullptr, n0, B1);
  gemm_mx(B1, B2, B0, (unsigned short*)MA, nullptr, n0, 8);
  k_sage<true, false><<<(n0 + 3) / 4, 256, 0, stream>>>(MA, adj0_dst, indptr_dst, nullptr, n0, B1);
  gemm_mx(B1, B0, out, nullptr, down0, n0, 9);
}

// Round 6
// 1146.501 us; speedup vs baseline: 2.0626x; 1.0400x over previous
//
#include <hip/hip_runtime.h>
#include <stdint.h>

#define DEV __device__ __forceinline__

constexpr int N0 = 50000;
constexpr int E0 = 800000;
constexpr int D  = 128;

typedef __attribute__((ext_vector_type(8))) short bf16x8;
typedef __attribute__((ext_vector_type(4))) float f32x4;

DEV float bf2f(unsigned u) { return __uint_as_float(u << 16); }
DEV unsigned short f2bf(float f) {
  unsigned u = __float_as_uint(f);
  unsigned r = u + 0x7fffu + ((u >> 16) & 1u);   // round-to-nearest-even
  return (unsigned short)(r >> 16);
}

DEV unsigned wave_incl_scan(unsigned v, int lane) {
  #pragma unroll
  for (int off = 1; off < 64; off <<= 1) {
    unsigned u = __shfl_up(v, (unsigned)off);
    if (lane >= off) v += u;
  }
  return v;
}

// ---------------- CSR build ----------------
__global__ void k_count(const int* __restrict__ src, const int* __restrict__ dst,
                        unsigned* cnt_src, unsigned* cnt_dst,
                        unsigned* __restrict__ rank_src, unsigned* __restrict__ rank_dst) {
  int e = blockIdx.x * blockDim.x + threadIdx.x;
  if (e < E0) {
    rank_src[e] = atomicAdd(&cnt_src[src[e]], 1u);
    rank_dst[e] = atomicAdd(&cnt_dst[dst[e]], 1u);
  }
}

// ---- 2-level exclusive scan ----
__global__ void k_psum(const unsigned* __restrict__ in, int n, unsigned* __restrict__ part) {
  int t = threadIdx.x, lane = t & 63, w = t >> 6;
  int base = blockIdx.x * 1024 + t * 4;
  unsigned s = 0;
  #pragma unroll
  for (int j = 0; j < 4; ++j) { int i = base + j; if (i < n) s += in[i]; }
  #pragma unroll
  for (int off = 32; off >= 1; off >>= 1) s += __shfl_xor(s, off);
  __shared__ unsigned ws[4];
  if (lane == 0) ws[w] = s;
  __syncthreads();
  if (t == 0) part[blockIdx.x] = ws[0] + ws[1] + ws[2] + ws[3];
}

__global__ void k_scoff(const unsigned* __restrict__ part, int nch,
                        unsigned* __restrict__ off, unsigned* __restrict__ total_out) {
  if (threadIdx.x == 0) {
    unsigned run = 0;
    for (int c = 0; c < nch; ++c) { off[c] = run; run += part[c]; }
    *total_out = run;
  }
}

__global__ void k_sapply(const unsigned* __restrict__ in, const unsigned* __restrict__ choff,
                         int n, unsigned* __restrict__ out) {
  int t = threadIdx.x, lane = t & 63, w = t >> 6;
  int base = blockIdx.x * 1024 + t * 4;
  unsigned v[4]; unsigned s = 0;
  #pragma unroll
  for (int j = 0; j < 4; ++j) { int i = base + j; v[j] = (i < n) ? in[i] : 0u; s += v[j]; }
  unsigned incl = wave_incl_scan(s, lane);
  __shared__ unsigned wsum[4], woff[4];
  if (lane == 63) wsum[w] = incl;
  __syncthreads();
  if (t == 0) { unsigned run = 0; for (int j = 0; j < 4; ++j) { woff[j] = run; run += wsum[j]; } }
  __syncthreads();
  unsigned run = choff[blockIdx.x] + woff[w] + incl - s;
  #pragma unroll
  for (int j = 0; j < 4; ++j) {
    int i = base + j;
    if (i < n) out[i] = run;
    run += v[j];
  }
}

// atomic-free merged fill of both CSR adjacency arrays
__global__ void k_fill2(const int* __restrict__ src, const int* __restrict__ dst,
                        const unsigned* __restrict__ rank_src, const unsigned* __restrict__ rank_dst,
                        const unsigned* __restrict__ indptr_src, const unsigned* __restrict__ indptr_dst,
                        int* __restrict__ adj_src, int* __restrict__ adj_dst) {
  int e = blockIdx.x * blockDim.x + threadIdx.x;
  if (e < E0) {
    int s = src[e], d = dst[e];
    adj_dst[indptr_dst[d] + rank_dst[e]] = s;
    adj_src[indptr_src[s] + rank_src[e]] = d;
  }
}

__global__ void k_adj_next2(const int* __restrict__ adjd, const int* __restrict__ adjs,
                            const int* __restrict__ new_id,
                            int* __restrict__ outd, int* __restrict__ outs) {
  int pos = blockIdx.x * blockDim.x + threadIdx.x;
  if (pos < E0) {
    int a = adjd[pos];
    outd[pos] = (a >= 0) ? new_id[a] : -1;
    int b = adjs[pos];
    outs[pos] = (b >= 0) ? new_id[b] : -1;
  }
}

__global__ void k_adj_next(const int* __restrict__ adj_prev, const int* __restrict__ new_id,
                           int* __restrict__ adj_out) {
  int pos = blockIdx.x * blockDim.x + threadIdx.x;
  if (pos < E0) {
    int a = adj_prev[pos];
    adj_out[pos] = (a >= 0) ? new_id[a] : -1;
  }
}

// ---------------- weight prep: 3-plane split-bf16, MFMA fragment order ----------------
// element (c,ks,ct,lane,j) = W[k=ks*32+(lane>>4)*8+j][o=ct*16+(lane&15)], c = conv 0..9
__global__ void k_wt_pk3(const float* __restrict__ Wl, const float* __restrict__ Wr,
                         unsigned short* __restrict__ Bh, unsigned short* __restrict__ Bm,
                         unsigned short* __restrict__ Bl) {
  int idx = blockIdx.x * blockDim.x + threadIdx.x;
  if (idx >= 10 * 8 * 8 * 64) return;
  int l  = idx & 63;
  int ct = (idx >> 6) & 7;
  int ks = (idx >> 9) & 7;
  int c  = idx >> 12;          // conv 0..9
  int k0 = ks * 32 + (l >> 4) * 8;
  int o  = ct * 16 + (l & 15);
  const float* Wrow = (k0 < 128) ? (Wl + ((size_t)c * 128 + o) * 128 + k0)
                                 : (Wr + ((size_t)c * 128 + o) * 128 + (k0 - 128));
  size_t base = (size_t)idx * 8;
  #pragma unroll
  for (int j = 0; j < 8; ++j) {
    float wv = Wrow[j];
    unsigned short h = f2bf(wv);
    float r1 = wv - bf2f(h);
    unsigned short m = f2bf(r1);
    float r2 = r1 - bf2f(m);
    Bh[base + j] = h;
    Bm[base + j] = m;
    Bl[base + j] = f2bf(r2);
  }
}

// ---------------- f32 gather: 2 rows/wave-step (half-wave split), 4-batch ----------------
template<bool MEAN, bool MASKED, bool ECW>
__global__ void k_gf32(const float* __restrict__ x, const int* __restrict__ adj,
                       const float* __restrict__ ecs, const unsigned* __restrict__ indptr,
                       const int* __restrict__ orig, int n, float* __restrict__ out) {
  int wid = (blockIdx.x * blockDim.x + threadIdx.x) >> 6;
  int lane = threadIdx.x & 63;
  if (wid >= n) return;
  int o = orig ? orig[wid] : wid;
  unsigned s0 = indptr[o], s1 = indptr[o + 1];
  int half = lane >> 5, sl = lane & 31;
  float a0 = 0.f, a1 = 0.f, a2 = 0.f, a3 = 0.f, cnt = 0.f;
  for (unsigned idx = s0; idx < s1; idx += 8) {
    #pragma unroll
    for (int j = 0; j < 4; ++j) {
      unsigned e = idx + j * 2 + half;
      if (e < s1) {
        int a = adj[e];
        if (!MASKED || a >= 0) {
          const float4 v = *(const float4*)(x + (size_t)a * D + sl * 4);
          if (ECW) {
            float w = ecs[e];
            a0 = fmaf(w, v.x, a0); a1 = fmaf(w, v.y, a1);
            a2 = fmaf(w, v.z, a2); a3 = fmaf(w, v.w, a3);
          } else {
            a0 += v.x; a1 += v.y; a2 += v.z; a3 += v.w;
          }
          cnt += 1.f;
        }
      }
    }
  }
  a0 += __shfl_xor(a0, 32); a1 += __shfl_xor(a1, 32);
  a2 += __shfl_xor(a2, 32); a3 += __shfl_xor(a3, 32);
  if (MEAN) {
    cnt += __shfl_xor(cnt, 32);
    if (!MASKED) cnt = (float)(s1 - s0);
    float inv = 1.0f / fmaxf(cnt, 1.0f);
    a0 *= inv; a1 *= inv; a2 *= inv; a3 *= inv;
  }
  if (half == 0)
    *(float4*)(out + (size_t)wid * D + sl * 4) = make_float4(a0, a1, a2, a3);
}

// ---------------- bf16 gather: 4 rows/wave-step (quarter-wave split), 4-batch ----------------
template<bool MEAN, bool MASKED, bool ECW>
__global__ void k_gbf(const unsigned* __restrict__ xb, const int* __restrict__ adj,
                      const float* __restrict__ ecs, const unsigned* __restrict__ indptr,
                      const int* __restrict__ orig, int n,
                      float* __restrict__ out, unsigned* __restrict__ outbf) {
  int wid = (blockIdx.x * blockDim.x + threadIdx.x) >> 6;
  int lane = threadIdx.x & 63;
  if (wid >= n) return;
  int o = orig ? orig[wid] : wid;
  unsigned s0 = indptr[o], s1 = indptr[o + 1];
  int q = lane >> 4, sl = lane & 15;
  float acc[8];
  #pragma unroll
  for (int k = 0; k < 8; ++k) acc[k] = 0.f;
  float cnt = 0.f;
  for (unsigned idx = s0; idx < s1; idx += 16) {
    #pragma unroll
    for (int j = 0; j < 4; ++j) {
      unsigned e = idx + j * 4 + q;
      if (e < s1) {
        int a = adj[e];
        if (!MASKED || a >= 0) {
          const uint4 v = *(const uint4*)(xb + (size_t)a * 64 + sl * 4);
          float f0 = bf2f(v.x & 0xffffu), f1 = bf2f(v.x >> 16);
          float f2 = bf2f(v.y & 0xffffu), f3 = bf2f(v.y >> 16);
          float f4 = bf2f(v.z & 0xffffu), f5 = bf2f(v.z >> 16);
          float f6 = bf2f(v.w & 0xffffu), f7 = bf2f(v.w >> 16);
          if (ECW) {
            float w = ecs[e];
            acc[0] = fmaf(w, f0, acc[0]); acc[1] = fmaf(w, f1, acc[1]);
            acc[2] = fmaf(w, f2, acc[2]); acc[3] = fmaf(w, f3, acc[3]);
            acc[4] = fmaf(w, f4, acc[4]); acc[5] = fmaf(w, f5, acc[5]);
            acc[6] = fmaf(w, f6, acc[6]); acc[7] = fmaf(w, f7, acc[7]);
          } else {
            acc[0] += f0; acc[1] += f1; acc[2] += f2; acc[3] += f3;
            acc[4] += f4; acc[5] += f5; acc[6] += f6; acc[7] += f7;
          }
          cnt += 1.f;
        }
      }
    }
  }
  #pragma unroll
  for (int k = 0; k < 8; ++k) {
    acc[k] += __shfl_xor(acc[k], 16);
    acc[k] += __shfl_xor(acc[k], 32);
  }
  if (MEAN) {
    cnt += __shfl_xor(cnt, 16);
    cnt += __shfl_xor(cnt, 32);
    if (!MASKED) cnt = (float)(s1 - s0);
    float inv = 1.0f / fmaxf(cnt, 1.0f);
    #pragma unroll
    for (int k = 0; k < 8; ++k) acc[k] *= inv;
  }
  if (q == 0) {
    *(float4*)(out + (size_t)wid * D + sl * 8)     = make_float4(acc[0], acc[1], acc[2], acc[3]);
    *(float4*)(out + (size_t)wid * D + sl * 8 + 4) = make_float4(acc[4], acc[5], acc[6], acc[7]);
    if (outbf) {
      uint4 p;
      p.x = (unsigned)f2bf(acc[0]) | ((unsigned)f2bf(acc[1]) << 16);
      p.y = (unsigned)f2bf(acc[2]) | ((unsigned)f2bf(acc[3]) << 16);
      p.z = (unsigned)f2bf(acc[4]) | ((unsigned)f2bf(acc[5]) << 16);
      p.w = (unsigned)f2bf(acc[6]) | ((unsigned)f2bf(acc[7]) << 16);
      *(uint4*)(outbf + (size_t)wid * 64 + sl * 4) = p;
    }
  }
}

// ---------------- 6-term 3-way-split MFMA GEMM (convs 0-3, selection-critical) ----------------
__launch_bounds__(256)
__global__ void k_gemm_mfma6(const float* __restrict__ mean, const float* __restrict__ xin,
                             const unsigned short* __restrict__ Bh, const unsigned short* __restrict__ Bm,
                             const unsigned short* __restrict__ Bl,
                             const float* __restrict__ bias,
                             float* __restrict__ y, int n) {
  int tid = threadIdx.x;
  int lane = tid & 63, w = tid >> 6;
  int row0 = blockIdx.x * 64 + w * 16;
  int arow = row0 + (lane & 15);
  int kgrp = lane >> 4;
  bool rowok = arow < n;
  f32x4 acc[8];
  #pragma unroll
  for (int ct = 0; ct < 8; ++ct) acc[ct] = f32x4{0.f, 0.f, 0.f, 0.f};

  #pragma unroll
  for (int ks = 0; ks < 8; ++ks) {
    const float* A = (ks < 4) ? mean : xin;
    int kk = (ks & 3) * 32 + kgrp * 8;
    float av[8];
    if (rowok) {
      float4 x0 = *(const float4*)(A + (size_t)arow * D + kk);
      float4 x1 = *(const float4*)(A + (size_t)arow * D + kk + 4);
      av[0] = x0.x; av[1] = x0.y; av[2] = x0.z; av[3] = x0.w;
      av[4] = x1.x; av[5] = x1.y; av[6] = x1.z; av[7] = x1.w;
    } else {
      #pragma unroll
      for (int j = 0; j < 8; ++j) av[j] = 0.f;
    }
    bf16x8 ah, am, al;
    #pragma unroll
    for (int j = 0; j < 8; ++j) {
      unsigned short h = f2bf(av[j]);
      float r1 = av[j] - bf2f(h);
      unsigned short m = f2bf(r1);
      float r2 = r1 - bf2f(m);
      ah[j] = (short)h; am[j] = (short)m; al[j] = (short)f2bf(r2);
    }
    #pragma unroll
    for (int ct = 0; ct < 8; ++ct) {
      size_t boff = (((size_t)ks * 8 + ct) * 64 + lane) * 8;
      bf16x8 bh = *(const bf16x8*)(Bh + boff);
      bf16x8 bm = *(const bf16x8*)(Bm + boff);
      bf16x8 bl = *(const bf16x8*)(Bl + boff);
      acc[ct] = __builtin_amdgcn_mfma_f32_16x16x32_bf16(ah, bh, acc[ct], 0, 0, 0);
      acc[ct] = __builtin_amdgcn_mfma_f32_16x16x32_bf16(ah, bm, acc[ct], 0, 0, 0);
      acc[ct] = __builtin_amdgcn_mfma_f32_16x16x32_bf16(am, bh, acc[ct], 0, 0, 0);
      acc[ct] = __builtin_amdgcn_mfma_f32_16x16x32_bf16(am, bm, acc[ct], 0, 0, 0);
      acc[ct] = __builtin_amdgcn_mfma_f32_16x16x32_bf16(ah, bl, acc[ct], 0, 0, 0);
      acc[ct] = __builtin_amdgcn_mfma_f32_16x16x32_bf16(al, bh, acc[ct], 0, 0, 0);
    }
  }
  int ccol = lane & 15;
  #pragma unroll
  for (int ct = 0; ct < 8; ++ct) {
    int col = ct * 16 + ccol;
    float bb = bias[col];
    #pragma unroll
    for (int r = 0; r < 4; ++r) {
      int row = row0 + kgrp * 4 + r;
      if (row < n) y[(size_t)row * D + col] = acc[ct][r] + bb;
    }
  }
}

// ---------------- 3-term split-bf16 MFMA GEMM (convs 4-9, post-selection) ----------------
__launch_bounds__(256)
__global__ void k_gemm_mfma(const float* __restrict__ mean, const float* __restrict__ xin,
                            const unsigned short* __restrict__ Bhi, const unsigned short* __restrict__ Blo,
                            const float* __restrict__ bias, const float* __restrict__ skip,
                            float* __restrict__ y, unsigned short* __restrict__ ybf, int n) {
  int tid = threadIdx.x;
  int lane = tid & 63, w = tid >> 6;
  int row0 = blockIdx.x * 64 + w * 16;
  int arow = row0 + (lane & 15);
  int kgrp = lane >> 4;
  bool rowok = arow < n;
  f32x4 acc[8];
  #pragma unroll
  for (int ct = 0; ct < 8; ++ct) acc[ct] = f32x4{0.f, 0.f, 0.f, 0.f};

  #pragma unroll
  for (int ks = 0; ks < 8; ++ks) {
    const float* A = (ks < 4) ? mean : xin;
    int kk = (ks & 3) * 32 + kgrp * 8;
    float av[8];
    if (rowok) {
      float4 x0 = *(const float4*)(A + (size_t)arow * D + kk);
      float4 x1 = *(const float4*)(A + (size_t)arow * D + kk + 4);
      av[0] = x0.x; av[1] = x0.y; av[2] = x0.z; av[3] = x0.w;
      av[4] = x1.x; av[5] = x1.y; av[6] = x1.z; av[7] = x1.w;
    } else {
      #pragma unroll
      for (int j = 0; j < 8; ++j) av[j] = 0.f;
    }
    bf16x8 ahi, alo;
    #pragma unroll
    for (int j = 0; j < 8; ++j) {
      unsigned short h = f2bf(av[j]);
      ahi[j] = (short)h;
      alo[j] = (short)f2bf(av[j] - bf2f(h));
    }
    #pragma unroll
    for (int ct = 0; ct < 8; ++ct) {
      size_t boff = (((size_t)ks * 8 + ct) * 64 + lane) * 8;
      bf16x8 bh = *(const bf16x8*)(Bhi + boff);
      bf16x8 bl = *(const bf16x8*)(Blo + boff);
      acc[ct] = __builtin_amdgcn_mfma_f32_16x16x32_bf16(ahi, bh, acc[ct], 0, 0, 0);
      acc[ct] = __builtin_amdgcn_mfma_f32_16x16x32_bf16(alo, bh, acc[ct], 0, 0, 0);
      acc[ct] = __builtin_amdgcn_mfma_f32_16x16x32_bf16(ahi, bl, acc[ct], 0, 0, 0);
    }
  }
  int ccol = lane & 15;
  #pragma unroll
  for (int ct = 0; ct < 8; ++ct) {
    int col = ct * 16 + ccol;
    float bb = bias[col];
    #pragma unroll
    for (int r = 0; r < 4; ++r) {
      int row = row0 + kgrp * 4 + r;
      if (row < n) {
        float v = acc[ct][r] + bb;
        if (skip) v += skip[(size_t)row * D + col];
        y[(size_t)row * D + col] = v;
        if (ybf) ybf[(size_t)row * D + col] = f2bf(v);
      }
    }
  }
}

// ---------------- cal_ew ----------------
__global__ void k_deg_mask(const int* __restrict__ adj_src, const unsigned* __restrict__ indptr_src,
                           const int* __restrict__ orig, int n, float* __restrict__ deg) {
  int j = blockIdx.x * blockDim.x + threadIdx.x;
  if (j >= n) return;
  int o = orig ? orig[j] : j;
  unsigned s0 = indptr_src[o], s1 = indptr_src[o + 1];
  float d = 0.f;
  for (unsigned i = s0; i < s1; ++i) d += (adj_src[i] >= 0) ? 1.f : 0.f;
  deg[j] = d;
}

// deg==nullptr -> degree from indptr_src diff (unmasked level 0)
template<bool MASKED>
__global__ void k_ew_dst(const int* __restrict__ adj, const unsigned* __restrict__ indptr,
                         const unsigned* __restrict__ ips,
                         const int* __restrict__ orig, const float* __restrict__ w,
                         const float* __restrict__ deg, int n,
                         float* __restrict__ ws_slot, float* __restrict__ aggrw,
                         float* __restrict__ ec_slot) {
  int j = blockIdx.x * blockDim.x + threadIdx.x;
  if (j >= n) return;
  int o = orig ? orig[j] : j;
  unsigned s0 = indptr[o], s1 = indptr[o + 1];
  float s = 1e-12f;
  for (unsigned pos = s0; pos < s1; ++pos) {
    int a = adj[pos];
    float ws = 0.f;
    if (!MASKED || a >= 0) {
      float d = deg ? deg[a] : (float)(ips[a + 1] - ips[a]);
      ws = (w ? w[a] : 1.0f) / (d > 0.f ? d : 1.0f);
    }
    ws_slot[pos] = ws;
    s += ws;
  }
  aggrw[j] = s;
  float inv = 1.0f / s;
  for (unsigned pos = s0; pos < s1; ++pos) ec_slot[pos] = ws_slot[pos] * inv;
}

template<bool MASKED>
__global__ void k_ew_src(const int* __restrict__ adj_src, const unsigned* __restrict__ indptr_src,
                         const int* __restrict__ orig, const float* __restrict__ w,
                         const float* __restrict__ deg, const float* __restrict__ aggrw, int n,
                         float* __restrict__ ec_slot) {
  int j = blockIdx.x * blockDim.x + threadIdx.x;
  if (j >= n) return;
  int o = orig ? orig[j] : j;
  unsigned s0 = indptr_src[o], s1 = indptr_src[o + 1];
  float d = deg ? deg[j] : (float)(s1 - s0);
  float wn = (w ? w[j] : 1.0f) / (d > 0.f ? d : 1.0f);
  for (unsigned pos = s0; pos < s1; ++pos) {
    int a = adj_src[pos];
    ec_slot[pos] = (!MASKED || a >= 0) ? (wn / aggrw[a]) : 0.f;
  }
}

// ---------------- pooling ----------------
DEV unsigned mono_key(float f) {
  unsigned u = __float_as_uint(f);
  return (u & 0x80000000u) ? ~u : (u | 0x80000000u);
}

__global__ void k_score(const float* __restrict__ x, const float* __restrict__ p,
                        int n, float* __restrict__ score, unsigned* __restrict__ keys) {
  int wid = (blockIdx.x * blockDim.x + threadIdx.x) >> 6;
  int lane = threadIdx.x & 63;
  if (wid >= n) return;
  float p0 = p[lane * 2], p1 = p[lane * 2 + 1];
  const float2 xv = *(const float2*)(x + (size_t)wid * D + lane * 2);
  float partial = xv.x * p0 + xv.y * p1;
  float pn = p0 * p0 + p1 * p1;
  #pragma unroll
  for (int off = 32; off >= 1; off >>= 1) {
    partial += __shfl_xor(partial, off);
    pn += __shfl_xor(pn, off);
  }
  if (lane == 0) {
    float sc = partial * (1.0f / sqrtf(pn));
    score[wid] = sc;
    keys[wid] = mono_key(sc);
  }
}

__global__ void k_sel_init(unsigned* bins, unsigned* state, int k) {
  int t = threadIdx.x;
  if (t < 256) bins[t] = 0u;
  if (t == 0) { state[0] = 0u; state[1] = (unsigned)k; }
}

__global__ void k_hist(const unsigned* __restrict__ keys, int n, const unsigned* __restrict__ state,
                       unsigned* __restrict__ bins, int byte) {
  __shared__ unsigned lb[256];
  for (int i = threadIdx.x; i < 256; i += blockDim.x) lb[i] = 0u;
  __syncthreads();
  unsigned prefix = state[0];
  unsigned mask = (byte == 3) ? 0u : (0xFFFFFFFFu << ((byte + 1) * 8));
  for (int i = blockIdx.x * blockDim.x + threadIdx.x; i < n; i += gridDim.x * blockDim.x) {
    unsigned key = keys[i];
    if ((key & mask) == (prefix & mask))
      atomicAdd(&lb[(key >> (byte * 8)) & 255], 1u);
  }
  __syncthreads();
  for (int i = threadIdx.x; i < 256; i += blockDim.x)
    if (lb[i]) atomicAdd(&bins[i], lb[i]);
}

__global__ void k_pick(unsigned* bins, unsigned* state, int byte) {
  if (threadIdx.x == 0) {
    unsigned r = state[1];
    int b;
    for (b = 255; b > 0; --b) {
      unsigned c = bins[b];
      if (c >= r) break;
      r -= c;
    }
    state[0] |= ((unsigned)b) << (byte * 8);
    state[1] = r;
  }
  __syncthreads();
  for (int i = threadIdx.x; i < 256; i += blockDim.x) bins[i] = 0u;
}

// ---- parallel pack ----
__global__ void k_flags(const unsigned* __restrict__ keys, const unsigned* __restrict__ state,
                        int n, uint2* __restrict__ part) {
  int t = threadIdx.x, lane = t & 63, w = t >> 6;
  int base = blockIdx.x * 1024 + t * 4;
  unsigned T = state[0];
  unsigned cnt = 0;
  #pragma unroll
  for (int j = 0; j < 4; ++j) {
    int i = base + j;
    if (i < n) {
      unsigned key = keys[i];
      cnt += (key > T ? 1u : 0u) + ((key == T ? 1u : 0u) << 16);
    }
  }
  #pragma unroll
  for (int off = 32; off >= 1; off >>= 1) cnt += __shfl_xor(cnt, off);
  __shared__ unsigned ws[4];
  if (lane == 0) ws[w] = cnt;
  __syncthreads();
  if (t == 0) {
    unsigned s = ws[0] + ws[1] + ws[2] + ws[3];
    part[blockIdx.x] = make_uint2(s & 0xffffu, s >> 16);
  }
}

__global__ void k_choff(const uint2* __restrict__ part, int nch, uint2* __restrict__ off) {
  if (threadIdx.x == 0) {
    unsigned g = 0, e = 0;
    for (int c = 0; c < nch; ++c) { off[c] = make_uint2(g, e); g += part[c].x; e += part[c].y; }
  }
}

__global__ void k_pack2(const unsigned* __restrict__ keys, const unsigned* __restrict__ state,
                        const uint2* __restrict__ choff, const float* __restrict__ aggrw,
                        const int* __restrict__ orig, int n,
                        int* __restrict__ perm, int* __restrict__ new_id,
                        float* __restrict__ w_next, int* __restrict__ orig_next) {
  int t = threadIdx.x, lane = t & 63, w = t >> 6;
  int base = blockIdx.x * 1024 + t * 4;
  unsigned T = state[0], r = state[1];
  unsigned f[4];
  unsigned cnt = 0;
  #pragma unroll
  for (int j = 0; j < 4; ++j) {
    int i = base + j;
    unsigned key = (i < n) ? keys[i] : 0u;
    unsigned gt = (i < n && key > T) ? 1u : 0u;
    unsigned eq = (i < n && key == T) ? 1u : 0u;
    f[j] = gt | (eq << 1);
    cnt += gt + (eq << 16);
  }
  unsigned incl = wave_incl_scan(cnt, lane);
  __shared__ unsigned wsum[4], woff[4];
  if (lane == 63) wsum[w] = incl;
  __syncthreads();
  if (t == 0) { unsigned run = 0; for (int j = 0; j < 4; ++j) { woff[j] = run; run += wsum[j]; } }
  __syncthreads();
  unsigned before = woff[w] + incl - cnt;
  uint2 o0 = choff[blockIdx.x];
  unsigned gt_b = o0.x + (before & 0xffffu);
  unsigned eq_b = o0.y + (before >> 16);
  #pragma unroll
  for (int j = 0; j < 4; ++j) {
    int i = base + j;
    if (i >= n) break;
    unsigned gt = f[j] & 1u, eq = (f[j] >> 1) & 1u;
    bool sel = gt || (eq && eq_b < r);
    if (sel) {
      int pos = (int)(gt_b + (eq_b < r ? eq_b : r));
      perm[pos] = i;
      new_id[i] = pos;
      w_next[pos] = aggrw[i];
      orig_next[pos] = orig ? orig[i] : i;
    } else {
      new_id[i] = -1;
    }
    gt_b += gt; eq_b += eq;
  }
}

__global__ void k_gate(const float* __restrict__ xin, const int* __restrict__ perm,
                       const float* __restrict__ score, int k, float* __restrict__ xout,
                       unsigned* __restrict__ outbf) {
  int wid = (blockIdx.x * blockDim.x + threadIdx.x) >> 6;
  int lane = threadIdx.x & 63;
  if (wid >= k) return;
  int j = perm[wid];
  float g = tanhf(score[j]);
  float2 v = *(const float2*)(xin + (size_t)j * D + lane * 2);
  v.x *= g; v.y *= g;
  *(float2*)(xout + (size_t)wid * D + lane * 2) = v;
  if (outbf) {
    unsigned p = (unsigned)f2bf(v.x) | ((unsigned)f2bf(v.y) << 16);
    outbf[(size_t)wid * 64 + lane] = p;
  }
}

__global__ void k_scatter_bf(const float* __restrict__ xin, const int* __restrict__ perm,
                             int k, unsigned* __restrict__ outbf) {
  int wid = (blockIdx.x * blockDim.x + threadIdx.x) >> 6;
  int lane = threadIdx.x & 63;
  if (wid >= k) return;
  int p = perm[wid];
  float2 v = *(const float2*)(xin + (size_t)wid * D + lane * 2);
  unsigned pk = (unsigned)f2bf(v.x) | ((unsigned)f2bf(v.y) << 16);
  outbf[(size_t)p * 64 + lane] = pk;
}

// =============================================================================
extern "C" void kernel_launch(void* const* d_in, const int* in_sizes, int n_in,
                              void* d_out, int out_size, void* d_ws, size_t ws_size,
                              hipStream_t stream) {
  const float* x_in   = (const float*)d_in[0];
  const int*   ei     = (const int*)d_in[1];
  const int*   src0   = ei;
  const int*   dst0   = ei + E0;
  const float* Wl     = (const float*)d_in[2];
  const float* bl     = (const float*)d_in[3];
  const float* Wr     = (const float*)d_in[4];
  const float* pool_p = (const float*)d_in[5];
  float* out = (float*)d_out;

  const int n0 = N0, k0 = 25000, n1 = 25000, k1 = 12500, n2 = 12500;
  const int NCH0 = (N0 + 1023) / 1024;   // 49

  char* ws = (char*)d_ws;
  size_t off = 0;
  auto alloc = [&](size_t bytes) -> char* {
    char* p = ws + off;
    off += (bytes + 255) & ~(size_t)255;
    return p;
  };
  const size_t NBY = (size_t)N0 * D * 4;
  float* B0    = (float*)alloc(NBY);
  float* B1    = (float*)alloc(NBY);
  float* B2    = (float*)alloc(NBY);
  float* down0 = (float*)alloc(NBY);
  float* down1 = (float*)alloc(NBY / 2);
  unsigned* MA = (unsigned*)alloc((size_t)N0 * D * 2);
  unsigned* MB = (unsigned*)alloc((size_t)N0 * D * 2);
  int* adj0_dst = (int*)alloc(E0 * 4);
  int* adj0_src = (int*)alloc(E0 * 4);
  int* adj1_dst = (int*)alloc(E0 * 4);
  int* adj1_src = (int*)alloc(E0 * 4);
  float* ec0_src = (float*)alloc(E0 * 4);
  float* ec1_src = (float*)alloc(E0 * 4);
  float* ec_dst  = (float*)alloc(E0 * 4);
  float* ws_slot = (float*)alloc(E0 * 4);
  int* adj2_dst  = (int*)ws_slot;          // alias: ws_slot dead before adj2 is built
  unsigned* rank_src = (unsigned*)alloc(E0 * 4);
  unsigned* rank_dst = (unsigned*)alloc(E0 * 4);
  unsigned* indptr_dst = (unsigned*)alloc((N0 + 1) * 4);
  unsigned* indptr_src = (unsigned*)alloc((N0 + 1) * 4);
  unsigned* cnt_src = (unsigned*)alloc(N0 * 4);
  unsigned* cnt_dst = (unsigned*)alloc(N0 * 4);
  float* deg   = (float*)alloc(N0 * 4);
  float* aggrw = (float*)alloc(N0 * 4);
  float* w1 = (float*)alloc(n1 * 4);
  float* w2 = (float*)alloc(n2 * 4);
  float* score = (float*)alloc(N0 * 4);
  unsigned* keys = (unsigned*)alloc(N0 * 4);
  int* perm0 = (int*)alloc(k0 * 4);
  int* perm1 = (int*)alloc(k1 * 4);
  int* orig1 = (int*)alloc(k0 * 4);
  int* orig2 = (int*)alloc(k1 * 4);
  int* new_id = (int*)alloc(N0 * 4);
  unsigned* bins  = (unsigned*)alloc(256 * 4);
  unsigned* state = (unsigned*)alloc(8);
  unsigned* spart = (unsigned*)alloc(64 * 4);
  unsigned* soff  = (unsigned*)alloc(64 * 4);
  uint2* ppart = (uint2*)alloc(64 * 8);
  uint2* poff  = (uint2*)alloc(64 * 8);
  // 3-plane packed weights: per conv 8*8*64*8 = 32768 bf16
  unsigned short* Bh = (unsigned short*)alloc((size_t)10 * 32768 * 2);
  unsigned short* Bm = (unsigned short*)alloc((size_t)10 * 32768 * 2);
  unsigned short* Bl = (unsigned short*)alloc((size_t)10 * 32768 * 2);

  const int EG = (E0 + 255) / 256;

  auto scan_np1 = [&](const unsigned* in, unsigned* outp, int n, int nch) {
    k_psum<<<nch, 256, 0, stream>>>(in, n, spart);
    k_scoff<<<1, 64, 0, stream>>>(spart, nch, soff, outp + n);
    k_sapply<<<nch, 256, 0, stream>>>(in, soff, n, outp);
  };

  // ---- CSR build (rank-from-count, atomic-free fill) ----
  hipMemsetAsync(cnt_src, 0, N0 * 4, stream);
  hipMemsetAsync(cnt_dst, 0, N0 * 4, stream);
  k_count<<<EG, 256, 0, stream>>>(src0, dst0, cnt_src, cnt_dst, rank_src, rank_dst);
  scan_np1(cnt_src, indptr_src, N0, NCH0);
  scan_np1(cnt_dst, indptr_dst, N0, NCH0);
  k_fill2<<<EG, 256, 0, stream>>>(src0, dst0, rank_src, rank_dst, indptr_src, indptr_dst,
                                  adj0_src, adj0_dst);
  k_wt_pk3<<<(10 * 8 * 8 * 64 + 255) / 256, 256, 0, stream>>>(Wl, Wr, Bh, Bm, Bl);

  auto gemm6 = [&](const float* meanb, const float* xin, float* yout, int n, int cidx) {
    size_t o = (size_t)cidx * 32768;
    k_gemm_mfma6<<<(n + 63) / 64, 256, 0, stream>>>(meanb, xin, Bh + o, Bm + o, Bl + o,
                                                    bl + cidx * 128, yout, n);
  };
  auto gemm_mx = [&](const float* meanb, const float* xin, float* yout, unsigned short* ybf,
                     const float* skip, int n, int cidx) {
    size_t o = (size_t)cidx * 32768;
    k_gemm_mfma<<<(n + 63) / 64, 256, 0, stream>>>(meanb, xin, Bh + o, Bm + o,
                                                   bl + cidx * 128, skip, yout, ybf, n);
  };

  auto pool_sel = [&](const float* xpool, int n, int kk, int level, const int* orig,
                      int* perm, float* w_next, int* orig_next,
                      float* xout, unsigned* xout_bf) {
    int nch = (n + 1023) / 1024;
    k_score<<<(n + 3) / 4, 256, 0, stream>>>(xpool, pool_p + level * D, n, score, keys);
    k_sel_init<<<1, 256, 0, stream>>>(bins, state, kk);
    for (int byte = 3; byte >= 0; --byte) {
      k_hist<<<256, 256, 0, stream>>>(keys, n, state, bins, byte);
      k_pick<<<1, 256, 0, stream>>>(bins, state, byte);
    }
    k_flags<<<nch, 256, 0, stream>>>(keys, state, n, ppart);
    k_choff<<<1, 64, 0, stream>>>(ppart, nch, poff);
    k_pack2<<<nch, 256, 0, stream>>>(keys, state, poff, aggrw, orig, n, perm, new_id, w_next, orig_next);
    k_gate<<<(kk + 3) / 4, 256, 0, stream>>>(xpool, perm, score, kk, xout, xout_bf);
  };

  const int G0 = (n0 + 3) / 4, G1 = (n1 + 3) / 4, G2 = (n2 + 3) / 4;

  // ======== down level 0 (f32, selection-exact) ========
  k_gf32<true, false, false><<<G0, 256, 0, stream>>>(x_in, adj0_dst, nullptr, indptr_dst, nullptr, n0, B1);
  gemm6(B1, x_in, B2, n0, 0);
  k_gf32<true, false, false><<<G0, 256, 0, stream>>>(B2, adj0_dst, nullptr, indptr_dst, nullptr, n0, B1);
  gemm6(B1, B2, down0, n0, 1);
  k_ew_dst<false><<<(n0 + 255) / 256, 256, 0, stream>>>(adj0_dst, indptr_dst, indptr_src, nullptr,
                                                        nullptr, nullptr, n0, ws_slot, aggrw, ec_dst);
  k_ew_src<false><<<(n0 + 255) / 256, 256, 0, stream>>>(adj0_src, indptr_src, nullptr, nullptr,
                                                        nullptr, aggrw, n0, ec0_src);
  k_gf32<false, false, true><<<G0, 256, 0, stream>>>(down0, adj0_dst, ec_dst, indptr_dst, nullptr, n0, B1);
  pool_sel(B1, n0, k0, 0, nullptr, perm0, w1, orig1, B2, nullptr);
  k_adj_next2<<<EG, 256, 0, stream>>>(adj0_dst, adj0_src, new_id, adj1_dst, adj1_src);

  // ======== down level 1 (f32) ========
  k_gf32<true, true, false><<<G1, 256, 0, stream>>>(B2, adj1_dst, nullptr, indptr_dst, orig1, n1, B1);
  gemm6(B1, B2, B0, n1, 2);
  k_gf32<true, true, false><<<G1, 256, 0, stream>>>(B0, adj1_dst, nullptr, indptr_dst, orig1, n1, B1);
  gemm6(B1, B0, down1, n1, 3);
  k_deg_mask<<<(n1 + 255) / 256, 256, 0, stream>>>(adj1_src, indptr_src, orig1, n1, deg);
  k_ew_dst<true><<<(n1 + 255) / 256, 256, 0, stream>>>(adj1_dst, indptr_dst, nullptr, orig1, w1,
                                                       deg, n1, ws_slot, aggrw, ec_dst);
  k_ew_src<true><<<(n1 + 255) / 256, 256, 0, stream>>>(adj1_src, indptr_src, orig1, w1, deg, aggrw,
                                                       n1, ec1_src);
  k_gf32<false, true, true><<<G1, 256, 0, stream>>>(down1, adj1_dst, ec_dst, indptr_dst, orig1, n1, B1);
  pool_sel(B1, n1, k1, 1, orig1, perm1, w2, orig2, B2, MA);
  k_adj_next<<<EG, 256, 0, stream>>>(adj1_dst, new_id, adj2_dst);   // aliases ws_slot (dead)

  // ======== bottom (bf16 gathers, MFMA convs) ========
  k_gbf<true, true, false><<<G2, 256, 0, stream>>>(MA, adj2_dst, nullptr, indptr_dst, orig2, n2, B1, nullptr);
  gemm_mx(B1, B2, B0, (unsigned short*)MB, nullptr, n2, 4);
  k_gbf<true, true, false><<<G2, 256, 0, stream>>>(MB, adj2_dst, nullptr, indptr_dst, orig2, n2, B1, nullptr);
  gemm_mx(B1, B0, B2, nullptr, nullptr, n2, 5);

  // ======== up u=1 (bf16 gathers, MFMA convs; skip fused into conv 7) ========
  hipMemsetAsync(MA, 0, (size_t)n1 * D * 2, stream);
  k_scatter_bf<<<G2, 256, 0, stream>>>(B2, perm1, n2, MA);
  k_gbf<false, true, true><<<G1, 256, 0, stream>>>(MA, adj1_src, ec1_src, indptr_src, orig1, n1, B1, MB);
  k_gbf<true, true, false><<<G1, 256, 0, stream>>>(MB, adj1_dst, nullptr, indptr_dst, orig1, n1, B0, nullptr);
  gemm_mx(B0, B1, B2, (unsigned short*)MA, nullptr, n1, 6);
  k_gbf<true, true, false><<<G1, 256, 0, stream>>>(MA, adj1_dst, nullptr, indptr_dst, orig1, n1, B0, nullptr);
  gemm_mx(B0, B2, B1, nullptr, down1, n1, 7);

  // ======== up u=0 (bf16 gathers, MFMA convs; skip fused into conv 9) ========
  hipMemsetAsync(MA, 0, (size_t)n0 * D * 2, stream);
  k_scatter_bf<<<G1, 256, 0, stream>>>(B1, perm0, n1, MA);
  k_gbf<false, false, true><<<G0, 256, 0, stream>>>(MA, adj0_src, ec0_src, indptr_src, nullptr, n0, B2, MB);
  k_gbf<true, false, false><<<G0, 256, 0, stream>>>(MB, adj0_dst, nullptr, indptr_dst, nullptr, n0, B1, nullptr);
  gemm_mx(B1, B2, B0, (unsigned short*)MA, nullptr, n0, 8);
  k_gbf<true, false, false><<<G0, 256, 0, stream>>>(MA, adj0_dst, nullptr, indptr_dst, nullptr, n0, B1, nullptr);
  gemm_mx(B1, B0, out, nullptr, down0, n0, 9);
}